// Round 1
// baseline (1321.290 us; speedup 1.0000x reference)
//
#include <hip/hip_runtime.h>
#include <math.h>

#define DM   1024
#define DI   2048
#define DS   16
#define DTR  64
#define NB   2
#define SEQL 1024
#define NTOK (NB*SEQL)
#define XND  96   /* DTR + 2*DS */

// ---------------- generic fp32 tiled GEMM: C[M,N] = A[M,K] @ B[K,N] ----------
// BM=BN=64, BK=16, 256 threads, 4x4 micro-tile per thread.
__global__ __launch_bounds__(256) void gemm_f32(
    const float* __restrict__ A, const float* __restrict__ B,
    float* __restrict__ C, int M, int N, int K, int lda, int ldb, int ldc)
{
    __shared__ float As[16][64 + 4];
    __shared__ float Bs[16][64 + 4];
    const int row0 = blockIdx.y * 64;
    const int col0 = blockIdx.x * 64;
    const int tid = threadIdx.x;
    const int tx = tid & 15, ty = tid >> 4;

    float acc[4][4] = {};

    for (int k0 = 0; k0 < K; k0 += 16) {
        // A tile: 64 rows x 16 k ; one float4 per thread
        {
            const int m  = tid >> 2;        // 0..63
            const int kk = (tid & 3) * 4;   // 0,4,8,12
            const float4 v = *reinterpret_cast<const float4*>(
                &A[(size_t)(row0 + m) * lda + k0 + kk]);
            As[kk + 0][m] = v.x; As[kk + 1][m] = v.y;
            As[kk + 2][m] = v.z; As[kk + 3][m] = v.w;
        }
        // B tile: 16 k x 64 cols ; one float4 per thread
        {
            const int kk = tid >> 4;        // 0..15
            const int n  = (tid & 15) * 4;  // 0..60
            const float4 v = *reinterpret_cast<const float4*>(
                &B[(size_t)(k0 + kk) * ldb + col0 + n]);
            Bs[kk][n + 0] = v.x; Bs[kk][n + 1] = v.y;
            Bs[kk][n + 2] = v.z; Bs[kk][n + 3] = v.w;
        }
        __syncthreads();
        #pragma unroll
        for (int kk = 0; kk < 16; kk++) {
            float a[4], b[4];
            #pragma unroll
            for (int i = 0; i < 4; i++) a[i] = As[kk][ty * 4 + i];
            #pragma unroll
            for (int j = 0; j < 4; j++) b[j] = Bs[kk][tx * 4 + j];
            #pragma unroll
            for (int i = 0; i < 4; i++)
                #pragma unroll
                for (int j = 0; j < 4; j++) acc[i][j] += a[i] * b[j];
        }
        __syncthreads();
    }
    #pragma unroll
    for (int i = 0; i < 4; i++)
        #pragma unroll
        for (int j = 0; j < 4; j++)
            C[(size_t)(row0 + ty * 4 + i) * ldc + col0 + tx * 4 + j] = acc[i][j];
}

// -------- depthwise causal conv (k=4) + bias + SiLU:  xc from xi half of xz --
__global__ __launch_bounds__(256) void conv_silu(
    const float* __restrict__ xz, const float* __restrict__ conv_w,
    const float* __restrict__ conv_b, float* __restrict__ xc)
{
    const int g = blockIdx.x * 256 + threadIdx.x;   // over NTOK*DI
    const int d   = g & (DI - 1);
    const int tok = g >> 11;
    const int t   = tok & (SEQL - 1);
    const float4 w = *reinterpret_cast<const float4*>(&conv_w[d * 4]);
    const float wk[4] = { w.x, w.y, w.z, w.w };
    float acc = conv_b[d];
    #pragma unroll
    for (int k = 0; k < 4; k++) {
        const int tt = t + k - 3;
        if (tt >= 0)
            acc += xz[(size_t)(tok + k - 3) * (2 * DI) + d] * wk[k];
    }
    xc[g] = acc / (1.f + __expf(-acc));   // silu
}

// -------- x_dbl = xc @ W_xproj   (M=NTOK, K=DI, N=96); one token per block ---
__global__ __launch_bounds__(128) void xproj(
    const float* __restrict__ xc, const float* __restrict__ W,
    float* __restrict__ xdbl)
{
    const int tok = blockIdx.x;
    const int n = threadIdx.x;
    if (n >= XND) return;
    const float* __restrict__ xr = &xc[(size_t)tok * DI];
    float acc = 0.f;
    #pragma unroll 4
    for (int k = 0; k < DI; k++) acc += xr[k] * W[(size_t)k * XND + n];
    xdbl[(size_t)tok * XND + n] = acc;
}

// -------- dt = softplus(dt_r @ W_dt + b_dt)  (M=NTOK, K=64, N=DI) ------------
__global__ __launch_bounds__(256) void dt_softplus(
    const float* __restrict__ xdbl, const float* __restrict__ Wdt,
    const float* __restrict__ bdt, float* __restrict__ dt)
{
    const int g = blockIdx.x * 256 + threadIdx.x;   // over NTOK*DI
    const int d   = g & (DI - 1);
    const int tok = g >> 11;
    const float* __restrict__ r = &xdbl[(size_t)tok * XND];
    float acc = bdt[d];
    #pragma unroll 8
    for (int k = 0; k < DTR; k++) acc += r[k] * Wdt[(size_t)k * DI + d];
    dt[g] = fmaxf(acc, 0.f) + log1pf(__expf(-fabsf(acc)));
}

// -------- selective scan + D-skip + z-gating ---------------------------------
// block: 256 thr = 16 channels x 16 states.  grid: (DI/16, NB).
// writes y into the xi half of xz (stride 2*DI), which gemm_out then reads.
__global__ __launch_bounds__(256) void scan_kernel(
    float* __restrict__ xz, const float* __restrict__ xc,
    const float* __restrict__ xdbl, const float* __restrict__ dtbuf,
    const float* __restrict__ A_log, const float* __restrict__ Dp)
{
    const int b   = blockIdx.y;
    const int tid = threadIdx.x;
    const int dl  = tid >> 4;     // 0..15
    const int n   = tid & 15;
    const int d   = blockIdx.x * 16 + dl;
    const float A  = -__expf(A_log[d * DS + n]);
    const float Dv = Dp[d];
    float h = 0.f;
    for (int t = 0; t < SEQL; t++) {
        const size_t tok = (size_t)b * SEQL + t;
        const float dtv = dtbuf[tok * DI + d];
        const float xcv = xc[tok * DI + d];
        const float Bv  = xdbl[tok * XND + DTR + n];
        const float Cv  = xdbl[tok * XND + DTR + DS + n];
        const float a = __expf(dtv * A);
        h = a * h + dtv * Bv * xcv;
        float p = h * Cv;
        p += __shfl_xor(p, 8, 16);
        p += __shfl_xor(p, 4, 16);
        p += __shfl_xor(p, 2, 16);
        p += __shfl_xor(p, 1, 16);
        if (n == 0) {
            const float zv = xz[tok * (2 * DI) + DI + d];
            const float yv = (p + xcv * Dv) * (zv / (1.f + __expf(-zv)));
            xz[tok * (2 * DI) + d] = yv;
        }
    }
}

// -------- out = x + LayerNorm(m) ---------------------------------------------
__global__ __launch_bounds__(256) void ln_add(
    const float* __restrict__ x, const float* __restrict__ m,
    const float* __restrict__ gamma, const float* __restrict__ beta,
    float* __restrict__ out)
{
    const int tok = blockIdx.x;
    const int tid = threadIdx.x;
    const int lane = tid & 63, wave = tid >> 6;
    __shared__ float red[4];
    __shared__ float stats[2];

    const float4 v = reinterpret_cast<const float4*>(&m[(size_t)tok * DM])[tid];
    float s = v.x + v.y + v.z + v.w;
    #pragma unroll
    for (int o = 32; o > 0; o >>= 1) s += __shfl_down(s, o, 64);
    if (lane == 0) red[wave] = s;
    __syncthreads();
    if (tid == 0) stats[0] = (red[0] + red[1] + red[2] + red[3]) * (1.f / DM);
    __syncthreads();
    const float mu = stats[0];
    const float dx = v.x - mu, dy = v.y - mu, dz = v.z - mu, dw = v.w - mu;
    float q = dx * dx + dy * dy + dz * dz + dw * dw;
    #pragma unroll
    for (int o = 32; o > 0; o >>= 1) q += __shfl_down(q, o, 64);
    if (lane == 0) red[wave] = q;
    __syncthreads();
    if (tid == 0)
        stats[1] = rsqrtf((red[0] + red[1] + red[2] + red[3]) * (1.f / DM) + 1e-6f);
    __syncthreads();
    const float rs = stats[1];

    const float4 g  = reinterpret_cast<const float4*>(gamma)[tid];
    const float4 bb = reinterpret_cast<const float4*>(beta)[tid];
    const float4 xv = reinterpret_cast<const float4*>(&x[(size_t)tok * DM])[tid];
    float4 o;
    o.x = xv.x + dx * rs * g.x + bb.x;
    o.y = xv.y + dy * rs * g.y + bb.y;
    o.z = xv.z + dz * rs * g.z + bb.z;
    o.w = xv.w + dw * rs * g.w + bb.w;
    reinterpret_cast<float4*>(&out[(size_t)tok * DM])[tid] = o;
}

extern "C" void kernel_launch(void* const* d_in, const int* in_sizes, int n_in,
                              void* d_out, int out_size, void* d_ws, size_t ws_size,
                              hipStream_t stream)
{
    const float* x      = (const float*)d_in[0];
    const float* W_in   = (const float*)d_in[1];
    const float* conv_w = (const float*)d_in[2];
    const float* conv_b = (const float*)d_in[3];
    const float* W_xprj = (const float*)d_in[4];
    const float* W_dt   = (const float*)d_in[5];
    const float* b_dt   = (const float*)d_in[6];
    const float* A_log  = (const float*)d_in[7];
    const float* D_par  = (const float*)d_in[8];
    const float* W_out  = (const float*)d_in[9];
    const float* gamma  = (const float*)d_in[10];
    const float* beta   = (const float*)d_in[11];
    float* out = (float*)d_out;

    // workspace layout (floats)
    float* ws   = (float*)d_ws;
    float* xz   = ws;                                  // NTOK*4096  (xi | z), y overwrites xi
    float* xc   = xz   + (size_t)NTOK * 2 * DI;        // NTOK*2048
    float* xdbl = xc   + (size_t)NTOK * DI;            // NTOK*96
    float* dt   = xdbl + (size_t)NTOK * XND;           // NTOK*2048
    float* mbuf = dt   + (size_t)NTOK * DI;            // NTOK*1024

    // 1. xz = x @ W_in           (M=2048, N=4096, K=1024)
    gemm_f32<<<dim3(4096 / 64, NTOK / 64), 256, 0, stream>>>(
        x, W_in, xz, NTOK, 2 * DI, DM, DM, 2 * DI, 2 * DI);
    // 2. xc = silu(conv(xi)+b)
    conv_silu<<<(NTOK * DI) / 256, 256, 0, stream>>>(xz, conv_w, conv_b, xc);
    // 3. x_dbl = xc @ W_xproj    (N=96)
    xproj<<<NTOK, 128, 0, stream>>>(xc, W_xprj, xdbl);
    // 4. dt = softplus(dt_r @ W_dt + b_dt)
    dt_softplus<<<(NTOK * DI) / 256, 256, 0, stream>>>(xdbl, W_dt, b_dt, dt);
    // 5. selective scan (+D skip, +z gate) -> y into xi half of xz
    scan_kernel<<<dim3(DI / 16, NB), 256, 0, stream>>>(
        xz, xc, xdbl, dt, A_log, D_par);
    // 6. m = y @ W_out           (M=2048, N=1024, K=2048, lda=4096)
    gemm_f32<<<dim3(DM / 64, NTOK / 64), 256, 0, stream>>>(
        xz, W_out, mbuf, NTOK, DM, DI, 2 * DI, DM, DM);
    // 7. out = x + LN(m)
    ln_add<<<NTOK, 256, 0, stream>>>(x, mbuf, gamma, beta, out);
}

// Round 2
// 825.932 us; speedup vs baseline: 1.5998x; 1.5998x over previous
//
#include <hip/hip_runtime.h>
#include <math.h>

#define DM   1024
#define DI   2048
#define DS   16
#define DTR  64
#define NB   2
#define SEQL 1024
#define NTOK (NB*SEQL)
#define XND  96   /* DTR + 2*DS */

// ---------------- generic fp32 tiled GEMM: C[M,N] = A[M,K] @ B[K,N] ----------
// BM=BN=64, BK=16, 256 threads, 4x4 micro-tile per thread.
__global__ __launch_bounds__(256) void gemm_f32(
    const float* __restrict__ A, const float* __restrict__ B,
    float* __restrict__ C, int M, int N, int K, int lda, int ldb, int ldc)
{
    __shared__ float As[16][64 + 4];
    __shared__ float Bs[16][64 + 4];
    const int row0 = blockIdx.y * 64;
    const int col0 = blockIdx.x * 64;
    const int tid = threadIdx.x;
    const int tx = tid & 15, ty = tid >> 4;

    float acc[4][4] = {};

    for (int k0 = 0; k0 < K; k0 += 16) {
        {
            const int m  = tid >> 2;
            const int kk = (tid & 3) * 4;
            const float4 v = *reinterpret_cast<const float4*>(
                &A[(size_t)(row0 + m) * lda + k0 + kk]);
            As[kk + 0][m] = v.x; As[kk + 1][m] = v.y;
            As[kk + 2][m] = v.z; As[kk + 3][m] = v.w;
        }
        {
            const int kk = tid >> 4;
            const int n  = (tid & 15) * 4;
            const float4 v = *reinterpret_cast<const float4*>(
                &B[(size_t)(k0 + kk) * ldb + col0 + n]);
            Bs[kk][n + 0] = v.x; Bs[kk][n + 1] = v.y;
            Bs[kk][n + 2] = v.z; Bs[kk][n + 3] = v.w;
        }
        __syncthreads();
        #pragma unroll
        for (int kk = 0; kk < 16; kk++) {
            float a[4], b[4];
            #pragma unroll
            for (int i = 0; i < 4; i++) a[i] = As[kk][ty * 4 + i];
            #pragma unroll
            for (int j = 0; j < 4; j++) b[j] = Bs[kk][tx * 4 + j];
            #pragma unroll
            for (int i = 0; i < 4; i++)
                #pragma unroll
                for (int j = 0; j < 4; j++) acc[i][j] += a[i] * b[j];
        }
        __syncthreads();
    }
    #pragma unroll
    for (int i = 0; i < 4; i++)
        #pragma unroll
        for (int j = 0; j < 4; j++)
            C[(size_t)(row0 + ty * 4 + i) * ldc + col0 + tx * 4 + j] = acc[i][j];
}

// -------- depthwise causal conv (k=4) + bias + SiLU:  xc from xi half of xz --
__global__ __launch_bounds__(256) void conv_silu(
    const float* __restrict__ xz, const float* __restrict__ conv_w,
    const float* __restrict__ conv_b, float* __restrict__ xc)
{
    const int g = blockIdx.x * 256 + threadIdx.x;
    const int d   = g & (DI - 1);
    const int tok = g >> 11;
    const int t   = tok & (SEQL - 1);
    const float4 w = *reinterpret_cast<const float4*>(&conv_w[d * 4]);
    const float wk[4] = { w.x, w.y, w.z, w.w };
    float acc = conv_b[d];
    #pragma unroll
    for (int k = 0; k < 4; k++) {
        const int tt = t + k - 3;
        if (tt >= 0)
            acc += xz[(size_t)(tok + k - 3) * (2 * DI) + d] * wk[k];
    }
    xc[g] = acc / (1.f + __expf(-acc));
}

// -------- x_dbl = xc @ W_xproj   (M=NTOK, K=DI, N=96); one token per block ---
__global__ __launch_bounds__(128) void xproj(
    const float* __restrict__ xc, const float* __restrict__ W,
    float* __restrict__ xdbl)
{
    const int tok = blockIdx.x;
    const int n = threadIdx.x;
    if (n >= XND) return;
    const float* __restrict__ xr = &xc[(size_t)tok * DI];
    float acc = 0.f;
    #pragma unroll 4
    for (int k = 0; k < DI; k++) acc += xr[k] * W[(size_t)k * XND + n];
    xdbl[(size_t)tok * XND + n] = acc;
}

// -------- dt = softplus(dt_r @ W_dt + b_dt)  (M=NTOK, K=64, N=DI) ------------
__global__ __launch_bounds__(256) void dt_softplus(
    const float* __restrict__ xdbl, const float* __restrict__ Wdt,
    const float* __restrict__ bdt, float* __restrict__ dt)
{
    const int g = blockIdx.x * 256 + threadIdx.x;
    const int d   = g & (DI - 1);
    const int tok = g >> 11;
    const float* __restrict__ r = &xdbl[(size_t)tok * XND];
    float acc = bdt[d];
    #pragma unroll 8
    for (int k = 0; k < DTR; k++) acc += r[k] * Wdt[(size_t)k * DI + d];
    dt[g] = fmaxf(acc, 0.f) + log1pf(__expf(-fabsf(acc)));
}

// -------- selective scan + D-skip + z-gating, LDS chunk-staged ---------------
// block: 256 thr = 16 channels x 16 states.  grid: (DI/16, NB).
// Chunks of TCH=64 timesteps are bulk-staged into LDS with coalesced float4
// loads (latency pipelined), recurrence then runs from LDS; y staged in LDS
// and written back coalesced into the xi half of xz.
#define TCH 64
__global__ __launch_bounds__(256) void scan_kernel(
    float* __restrict__ xz, const float* __restrict__ xc,
    const float* __restrict__ xdbl, const float* __restrict__ dtbuf,
    const float* __restrict__ A_log, const float* __restrict__ Dp)
{
    __shared__ float dt_s[TCH][16];
    __shared__ float xc_s[TCH][16];
    __shared__ float z_s [TCH][16];
    __shared__ float B_s [TCH][16];
    __shared__ float C_s [TCH][16];
    __shared__ float y_s [TCH][16];

    const int b   = blockIdx.y;
    const int tid = threadIdx.x;
    const int dl  = tid >> 4;     // 0..15 channel within block
    const int n   = tid & 15;     // state
    const int d   = blockIdx.x * 16 + dl;
    const float A  = -__expf(A_log[d * DS + n]);
    const float Dv = Dp[d];
    const int d0 = blockIdx.x * 16;

    // staging coords: one float4 per thread per buffer
    const int st  = tid >> 2;     // 0..63 timestep within chunk
    const int sg  = (tid & 3) * 4;// 0,4,8,12 channel/state offset

    float h = 0.f;
    for (int c0 = 0; c0 < SEQL; c0 += TCH) {
        const size_t tokb = (size_t)b * SEQL + c0;
        // ---- stage chunk (independent float4 loads, pipelined by vmcnt) ----
        {
            const size_t tk = tokb + st;
            const float4 vdt = *reinterpret_cast<const float4*>(&dtbuf[tk * DI + d0 + sg]);
            const float4 vxc = *reinterpret_cast<const float4*>(&xc   [tk * DI + d0 + sg]);
            const float4 vz  = *reinterpret_cast<const float4*>(&xz   [tk * (2*DI) + DI + d0 + sg]);
            const float4 vB  = *reinterpret_cast<const float4*>(&xdbl [tk * XND + DTR + sg]);
            const float4 vC  = *reinterpret_cast<const float4*>(&xdbl [tk * XND + DTR + DS + sg]);
            *reinterpret_cast<float4*>(&dt_s[st][sg]) = vdt;
            *reinterpret_cast<float4*>(&xc_s[st][sg]) = vxc;
            *reinterpret_cast<float4*>(&z_s [st][sg]) = vz;
            *reinterpret_cast<float4*>(&B_s [st][sg]) = vB;
            *reinterpret_cast<float4*>(&C_s [st][sg]) = vC;
        }
        __syncthreads();
        // ---- recurrence from LDS ----
        #pragma unroll 8
        for (int t = 0; t < TCH; t++) {
            const float dtv = dt_s[t][dl];
            const float xcv = xc_s[t][dl];
            const float Bv  = B_s[t][n];
            const float Cv  = C_s[t][n];
            const float a   = __expf(dtv * A);
            h = a * h + dtv * Bv * xcv;
            float p = h * Cv;
            p += __shfl_xor(p, 8, 16);
            p += __shfl_xor(p, 4, 16);
            p += __shfl_xor(p, 2, 16);
            p += __shfl_xor(p, 1, 16);
            if (n == 0) {
                const float zv = z_s[t][dl];
                y_s[t][dl] = (p + xcv * Dv) * (zv / (1.f + __expf(-zv)));
            }
        }
        __syncthreads();
        // ---- coalesced writeback of y into xi half of xz ----
        {
            const size_t tk = tokb + st;
            *reinterpret_cast<float4*>(&xz[tk * (2*DI) + d0 + sg]) =
                *reinterpret_cast<const float4*>(&y_s[st][sg]);
        }
        // next stage writes other buffers; sync at loop top (after stage)
        // protects y_s via the __syncthreads() before the next compute phase
    }
}

// -------- out = x + LayerNorm(m) ---------------------------------------------
__global__ __launch_bounds__(256) void ln_add(
    const float* __restrict__ x, const float* __restrict__ m,
    const float* __restrict__ gamma, const float* __restrict__ beta,
    float* __restrict__ out)
{
    const int tok = blockIdx.x;
    const int tid = threadIdx.x;
    const int lane = tid & 63, wave = tid >> 6;
    __shared__ float red[4];
    __shared__ float stats[2];

    const float4 v = reinterpret_cast<const float4*>(&m[(size_t)tok * DM])[tid];
    float s = v.x + v.y + v.z + v.w;
    #pragma unroll
    for (int o = 32; o > 0; o >>= 1) s += __shfl_down(s, o, 64);
    if (lane == 0) red[wave] = s;
    __syncthreads();
    if (tid == 0) stats[0] = (red[0] + red[1] + red[2] + red[3]) * (1.f / DM);
    __syncthreads();
    const float mu = stats[0];
    const float dx = v.x - mu, dy = v.y - mu, dz = v.z - mu, dw = v.w - mu;
    float q = dx * dx + dy * dy + dz * dz + dw * dw;
    #pragma unroll
    for (int o = 32; o > 0; o >>= 1) q += __shfl_down(q, o, 64);
    if (lane == 0) red[wave] = q;
    __syncthreads();
    if (tid == 0)
        stats[1] = rsqrtf((red[0] + red[1] + red[2] + red[3]) * (1.f / DM) + 1e-6f);
    __syncthreads();
    const float rs = stats[1];

    const float4 g  = reinterpret_cast<const float4*>(gamma)[tid];
    const float4 bb = reinterpret_cast<const float4*>(beta)[tid];
    const float4 xv = reinterpret_cast<const float4*>(&x[(size_t)tok * DM])[tid];
    float4 o;
    o.x = xv.x + dx * rs * g.x + bb.x;
    o.y = xv.y + dy * rs * g.y + bb.y;
    o.z = xv.z + dz * rs * g.z + bb.z;
    o.w = xv.w + dw * rs * g.w + bb.w;
    reinterpret_cast<float4*>(&out[(size_t)tok * DM])[tid] = o;
}

extern "C" void kernel_launch(void* const* d_in, const int* in_sizes, int n_in,
                              void* d_out, int out_size, void* d_ws, size_t ws_size,
                              hipStream_t stream)
{
    const float* x      = (const float*)d_in[0];
    const float* W_in   = (const float*)d_in[1];
    const float* conv_w = (const float*)d_in[2];
    const float* conv_b = (const float*)d_in[3];
    const float* W_xprj = (const float*)d_in[4];
    const float* W_dt   = (const float*)d_in[5];
    const float* b_dt   = (const float*)d_in[6];
    const float* A_log  = (const float*)d_in[7];
    const float* D_par  = (const float*)d_in[8];
    const float* W_out  = (const float*)d_in[9];
    const float* gamma  = (const float*)d_in[10];
    const float* beta   = (const float*)d_in[11];
    float* out = (float*)d_out;

    float* ws   = (float*)d_ws;
    float* xz   = ws;                                  // NTOK*4096  (xi | z)
    float* xc   = xz   + (size_t)NTOK * 2 * DI;        // NTOK*2048
    float* xdbl = xc   + (size_t)NTOK * DI;            // NTOK*96
    float* dt   = xdbl + (size_t)NTOK * XND;           // NTOK*2048
    float* mbuf = dt   + (size_t)NTOK * DI;            // NTOK*1024

    gemm_f32<<<dim3(4096 / 64, NTOK / 64), 256, 0, stream>>>(
        x, W_in, xz, NTOK, 2 * DI, DM, DM, 2 * DI, 2 * DI);
    conv_silu<<<(NTOK * DI) / 256, 256, 0, stream>>>(xz, conv_w, conv_b, xc);
    xproj<<<NTOK, 128, 0, stream>>>(xc, W_xprj, xdbl);
    dt_softplus<<<(NTOK * DI) / 256, 256, 0, stream>>>(xdbl, W_dt, b_dt, dt);
    scan_kernel<<<dim3(DI / 16, NB), 256, 0, stream>>>(
        xz, xc, xdbl, dt, A_log, D_par);
    gemm_f32<<<dim3(DM / 64, NTOK / 64), 256, 0, stream>>>(
        xz, W_out, mbuf, NTOK, DM, DI, 2 * DI, DM, DM);
    ln_add<<<NTOK, 256, 0, stream>>>(x, mbuf, gamma, beta, out);
}

// Round 3
// 583.798 us; speedup vs baseline: 2.2633x; 1.4148x over previous
//
#include <hip/hip_runtime.h>
#include <math.h>

#define DM   1024
#define DI   2048
#define DS   16
#define DTR  64
#define NB   2
#define SEQL 1024
#define NTOK (NB*SEQL)
#define XND  96   /* DTR + 2*DS */

typedef __bf16 bf16x8 __attribute__((ext_vector_type(8)));
typedef float  f32x4  __attribute__((ext_vector_type(4)));

// -------- fp32 -> bf16 row-major convert (strided source) --------------------
__global__ __launch_bounds__(256) void cvt_bf16(
    const float* __restrict__ src, __bf16* __restrict__ dst,
    int logW, int srcld, int total8)
{
    const int g = blockIdx.x * 256 + threadIdx.x;
    if (g >= total8) return;
    const int e = g * 8;
    const int row = e >> logW;
    const int col = e & ((1 << logW) - 1);
    const float4 v0 = *reinterpret_cast<const float4*>(&src[(size_t)row * srcld + col]);
    const float4 v1 = *reinterpret_cast<const float4*>(&src[(size_t)row * srcld + col + 4]);
    bf16x8 o;
    o[0] = (__bf16)v0.x; o[1] = (__bf16)v0.y; o[2] = (__bf16)v0.z; o[3] = (__bf16)v0.w;
    o[4] = (__bf16)v1.x; o[5] = (__bf16)v1.y; o[6] = (__bf16)v1.z; o[7] = (__bf16)v1.w;
    *reinterpret_cast<bf16x8*>(&dst[e]) = o;
}

// -------- W[K][N] fp32 -> WT[N][K] bf16 (tiled transpose) --------------------
__global__ __launch_bounds__(256) void transpose_cvt(
    const float* __restrict__ W, __bf16* __restrict__ WT, int K, int N)
{
    __shared__ __bf16 t[32][33];
    const int n0 = blockIdx.x * 32, k0 = blockIdx.y * 32;
    const int tx = threadIdx.x & 31, ty = threadIdx.x >> 5;  // ty 0..7
    #pragma unroll
    for (int i = 0; i < 4; i++)
        t[ty * 4 + i][tx] = (__bf16)W[(size_t)(k0 + ty * 4 + i) * N + n0 + tx];
    __syncthreads();
    #pragma unroll
    for (int i = 0; i < 4; i++)
        WT[(size_t)(n0 + ty * 4 + i) * K + k0 + tx] = t[tx][ty * 4 + i];
}

// -------- bf16 MFMA GEMM: C[M][N] = A[M][K] * B[K][N], B given as Bt[N][K] ---
// 128x128 tile, BK=32, 256 thr = 4 waves in 2x2 (64x64 each), 16x16x32 MFMA.
__global__ __launch_bounds__(256) void gemm_bf16(
    const __bf16* __restrict__ A, const __bf16* __restrict__ Bt,
    float* __restrict__ C, int M, int N, int K, int ldc)
{
    __shared__ __bf16 As[128 * 32];
    __shared__ __bf16 Bs[128 * 32];
    const int tid  = threadIdx.x;
    const int lane = tid & 63;
    const int wid  = tid >> 6;
    const int wr   = wid >> 1, wc = wid & 1;
    const int brow = blockIdx.y * 128, bcol = blockIdx.x * 128;

    f32x4 acc[4][4] = {};

    const int r0 = tid >> 2;            // staging row (pass 0: 0..63)
    const int k8 = (tid & 3) * 8;       // bf16 offset in row

    for (int k0 = 0; k0 < K; k0 += 32) {
        __syncthreads();
        {
            const __bf16* g0 = A  + (size_t)(brow + r0)      * K + k0 + k8;
            const __bf16* g1 = A  + (size_t)(brow + 64 + r0) * K + k0 + k8;
            const __bf16* h0 = Bt + (size_t)(bcol + r0)      * K + k0 + k8;
            const __bf16* h1 = Bt + (size_t)(bcol + 64 + r0) * K + k0 + k8;
            __builtin_amdgcn_global_load_lds(
                (const __attribute__((address_space(1))) void*)g0,
                (__attribute__((address_space(3))) void*)(As + tid * 8), 16, 0, 0);
            __builtin_amdgcn_global_load_lds(
                (const __attribute__((address_space(1))) void*)g1,
                (__attribute__((address_space(3))) void*)(As + 2048 + tid * 8), 16, 0, 0);
            __builtin_amdgcn_global_load_lds(
                (const __attribute__((address_space(1))) void*)h0,
                (__attribute__((address_space(3))) void*)(Bs + tid * 8), 16, 0, 0);
            __builtin_amdgcn_global_load_lds(
                (const __attribute__((address_space(1))) void*)h1,
                (__attribute__((address_space(3))) void*)(Bs + 2048 + tid * 8), 16, 0, 0);
        }
        __syncthreads();
        bf16x8 a[4], b[4];
        const int rA = wr * 64 + (lane & 15);
        const int rB = wc * 64 + (lane & 15);
        const int kf = (lane >> 4) * 8;
        #pragma unroll
        for (int m = 0; m < 4; m++)
            a[m] = *reinterpret_cast<const bf16x8*>(&As[(rA + m * 16) * 32 + kf]);
        #pragma unroll
        for (int n = 0; n < 4; n++)
            b[n] = *reinterpret_cast<const bf16x8*>(&Bs[(rB + n * 16) * 32 + kf]);
        #pragma unroll
        for (int m = 0; m < 4; m++)
            #pragma unroll
            for (int n = 0; n < 4; n++)
                acc[m][n] = __builtin_amdgcn_mfma_f32_16x16x32_bf16(
                    a[m], b[n], acc[m][n], 0, 0, 0);
    }
    const int crow = brow + wr * 64 + (lane >> 4) * 4;
    const int ccol = bcol + wc * 64 + (lane & 15);
    #pragma unroll
    for (int m = 0; m < 4; m++)
        #pragma unroll
        for (int n = 0; n < 4; n++)
            #pragma unroll
            for (int j = 0; j < 4; j++)
                C[(size_t)(crow + m * 16 + j) * ldc + ccol + n * 16] = acc[m][n][j];
}

// -------- depthwise causal conv (k=4) + bias + SiLU --------------------------
__global__ __launch_bounds__(256) void conv_silu(
    const float* __restrict__ xz, const float* __restrict__ conv_w,
    const float* __restrict__ conv_b, float* __restrict__ xc)
{
    const int g = blockIdx.x * 256 + threadIdx.x;
    const int d   = g & (DI - 1);
    const int tok = g >> 11;
    const int t   = tok & (SEQL - 1);
    const float4 w = *reinterpret_cast<const float4*>(&conv_w[d * 4]);
    const float wk[4] = { w.x, w.y, w.z, w.w };
    float acc = conv_b[d];
    #pragma unroll
    for (int k = 0; k < 4; k++) {
        const int tt = t + k - 3;
        if (tt >= 0)
            acc += xz[(size_t)(tok + k - 3) * (2 * DI) + d] * wk[k];
    }
    xc[g] = acc / (1.f + __expf(-acc));
}

// -------- x_dbl = xc @ W_xproj   (N=96); one token per block -----------------
__global__ __launch_bounds__(128) void xproj(
    const float* __restrict__ xc, const float* __restrict__ W,
    float* __restrict__ xdbl)
{
    const int tok = blockIdx.x;
    const int n = threadIdx.x;
    if (n >= XND) return;
    const float* __restrict__ xr = &xc[(size_t)tok * DI];
    float acc = 0.f;
    #pragma unroll 4
    for (int k = 0; k < DI; k++) acc += xr[k] * W[(size_t)k * XND + n];
    xdbl[(size_t)tok * XND + n] = acc;
}

// -------- dt = softplus(dt_r @ W_dt + b_dt) ----------------------------------
__global__ __launch_bounds__(256) void dt_softplus(
    const float* __restrict__ xdbl, const float* __restrict__ Wdt,
    const float* __restrict__ bdt, float* __restrict__ dt)
{
    const int g = blockIdx.x * 256 + threadIdx.x;
    const int d   = g & (DI - 1);
    const int tok = g >> 11;
    const float* __restrict__ r = &xdbl[(size_t)tok * XND];
    float acc = bdt[d];
    #pragma unroll 8
    for (int k = 0; k < DTR; k++) acc += r[k] * Wdt[(size_t)k * DI + d];
    dt[g] = fmaxf(acc, 0.f) + log1pf(__expf(-fabsf(acc)));
}

// -------- selective scan + D-skip + z-gating, LDS chunk-staged ---------------
#define TCH 64
__global__ __launch_bounds__(256) void scan_kernel(
    float* __restrict__ xz, const float* __restrict__ xc,
    const float* __restrict__ xdbl, const float* __restrict__ dtbuf,
    const float* __restrict__ A_log, const float* __restrict__ Dp)
{
    __shared__ float dt_s[TCH][16];
    __shared__ float xc_s[TCH][16];
    __shared__ float z_s [TCH][16];
    __shared__ float B_s [TCH][16];
    __shared__ float C_s [TCH][16];
    __shared__ float y_s [TCH][16];

    const int b   = blockIdx.y;
    const int tid = threadIdx.x;
    const int dl  = tid >> 4;
    const int n   = tid & 15;
    const int d   = blockIdx.x * 16 + dl;
    const float A  = -__expf(A_log[d * DS + n]);
    const float Dv = Dp[d];
    const int d0 = blockIdx.x * 16;

    const int st  = tid >> 2;
    const int sg  = (tid & 3) * 4;

    float h = 0.f;
    for (int c0 = 0; c0 < SEQL; c0 += TCH) {
        const size_t tokb = (size_t)b * SEQL + c0;
        {
            const size_t tk = tokb + st;
            const float4 vdt = *reinterpret_cast<const float4*>(&dtbuf[tk * DI + d0 + sg]);
            const float4 vxc = *reinterpret_cast<const float4*>(&xc   [tk * DI + d0 + sg]);
            const float4 vz  = *reinterpret_cast<const float4*>(&xz   [tk * (2*DI) + DI + d0 + sg]);
            const float4 vB  = *reinterpret_cast<const float4*>(&xdbl [tk * XND + DTR + sg]);
            const float4 vC  = *reinterpret_cast<const float4*>(&xdbl [tk * XND + DTR + DS + sg]);
            *reinterpret_cast<float4*>(&dt_s[st][sg]) = vdt;
            *reinterpret_cast<float4*>(&xc_s[st][sg]) = vxc;
            *reinterpret_cast<float4*>(&z_s [st][sg]) = vz;
            *reinterpret_cast<float4*>(&B_s [st][sg]) = vB;
            *reinterpret_cast<float4*>(&C_s [st][sg]) = vC;
        }
        __syncthreads();
        #pragma unroll 8
        for (int t = 0; t < TCH; t++) {
            const float dtv = dt_s[t][dl];
            const float xcv = xc_s[t][dl];
            const float Bv  = B_s[t][n];
            const float Cv  = C_s[t][n];
            const float a   = __expf(dtv * A);
            h = a * h + dtv * Bv * xcv;
            float p = h * Cv;
            p += __shfl_xor(p, 8, 16);
            p += __shfl_xor(p, 4, 16);
            p += __shfl_xor(p, 2, 16);
            p += __shfl_xor(p, 1, 16);
            if (n == 0) {
                const float zv = z_s[t][dl];
                y_s[t][dl] = (p + xcv * Dv) * (zv / (1.f + __expf(-zv)));
            }
        }
        __syncthreads();
        {
            const size_t tk = tokb + st;
            *reinterpret_cast<float4*>(&xz[tk * (2*DI) + d0 + sg]) =
                *reinterpret_cast<const float4*>(&y_s[st][sg]);
        }
    }
}

// -------- out = x + LayerNorm(m) ---------------------------------------------
__global__ __launch_bounds__(256) void ln_add(
    const float* __restrict__ x, const float* __restrict__ m,
    const float* __restrict__ gamma, const float* __restrict__ beta,
    float* __restrict__ out)
{
    const int tok = blockIdx.x;
    const int tid = threadIdx.x;
    const int lane = tid & 63, wave = tid >> 6;
    __shared__ float red[4];
    __shared__ float stats[2];

    const float4 v = reinterpret_cast<const float4*>(&m[(size_t)tok * DM])[tid];
    float s = v.x + v.y + v.z + v.w;
    #pragma unroll
    for (int o = 32; o > 0; o >>= 1) s += __shfl_down(s, o, 64);
    if (lane == 0) red[wave] = s;
    __syncthreads();
    if (tid == 0) stats[0] = (red[0] + red[1] + red[2] + red[3]) * (1.f / DM);
    __syncthreads();
    const float mu = stats[0];
    const float dx = v.x - mu, dy = v.y - mu, dz = v.z - mu, dw = v.w - mu;
    float q = dx * dx + dy * dy + dz * dz + dw * dw;
    #pragma unroll
    for (int o = 32; o > 0; o >>= 1) q += __shfl_down(q, o, 64);
    if (lane == 0) red[wave] = q;
    __syncthreads();
    if (tid == 0)
        stats[1] = rsqrtf((red[0] + red[1] + red[2] + red[3]) * (1.f / DM) + 1e-6f);
    __syncthreads();
    const float rs = stats[1];

    const float4 g  = reinterpret_cast<const float4*>(gamma)[tid];
    const float4 bb = reinterpret_cast<const float4*>(beta)[tid];
    const float4 xv = reinterpret_cast<const float4*>(&x[(size_t)tok * DM])[tid];
    float4 o;
    o.x = xv.x + dx * rs * g.x + bb.x;
    o.y = xv.y + dy * rs * g.y + bb.y;
    o.z = xv.z + dz * rs * g.z + bb.z;
    o.w = xv.w + dw * rs * g.w + bb.w;
    reinterpret_cast<float4*>(&out[(size_t)tok * DM])[tid] = o;
}

extern "C" void kernel_launch(void* const* d_in, const int* in_sizes, int n_in,
                              void* d_out, int out_size, void* d_ws, size_t ws_size,
                              hipStream_t stream)
{
    const float* x      = (const float*)d_in[0];
    const float* W_in   = (const float*)d_in[1];
    const float* conv_w = (const float*)d_in[2];
    const float* conv_b = (const float*)d_in[3];
    const float* W_xprj = (const float*)d_in[4];
    const float* W_dt   = (const float*)d_in[5];
    const float* b_dt   = (const float*)d_in[6];
    const float* A_log  = (const float*)d_in[7];
    const float* D_par  = (const float*)d_in[8];
    const float* W_out  = (const float*)d_in[9];
    const float* gamma  = (const float*)d_in[10];
    const float* beta   = (const float*)d_in[11];
    float* out = (float*)d_out;

    // workspace layout (bytes)
    char* w = (char*)d_ws;
    float*  xz    = (float*) (w + 0);           // 33,554,432
    float*  xc    = (float*) (w + 33554432);    // 16,777,216
    float*  xdbl  = (float*) (w + 50331648);    //    786,432
    float*  dt    = (float*) (w + 51118080);    // 16,777,216
    float*  mbuf  = (float*) (w + 67895296);    //  8,388,608
    // bf16 region (reused): phase-in: xb | W_inT ; phase-out: yb | W_outT
    __bf16* xb    = (__bf16*)(w + 76283904);                 // 4,194,304 B
    __bf16* W_inT = (__bf16*)(w + 76283904 + 4194304);       // 8,388,608 B
    __bf16* yb    = (__bf16*)(w + 76283904);                 // 8,388,608 B
    __bf16* W_outT= (__bf16*)(w + 76283904 + 8388608);       // 4,194,304 B

    // --- convert inputs for in-proj GEMM ---
    cvt_bf16<<<(NTOK * DM / 8 + 255) / 256, 256, 0, stream>>>(
        x, xb, 10, DM, NTOK * DM / 8);
    transpose_cvt<<<dim3(2 * DI / 32, DM / 32), 256, 0, stream>>>(
        W_in, W_inT, DM, 2 * DI);
    // 1. xz = x @ W_in  (M=2048, N=4096, K=1024)
    gemm_bf16<<<dim3(2 * DI / 128, NTOK / 128), 256, 0, stream>>>(
        xb, W_inT, xz, NTOK, 2 * DI, DM, 2 * DI);
    // 2. conv + silu
    conv_silu<<<(NTOK * DI) / 256, 256, 0, stream>>>(xz, conv_w, conv_b, xc);
    // 3. x_dbl
    xproj<<<NTOK, 128, 0, stream>>>(xc, W_xprj, xdbl);
    // 4. dt
    dt_softplus<<<(NTOK * DI) / 256, 256, 0, stream>>>(xdbl, W_dt, b_dt, dt);
    // 5. scan -> y into xi half of xz
    scan_kernel<<<dim3(DI / 16, NB), 256, 0, stream>>>(
        xz, xc, xdbl, dt, A_log, D_par);
    // --- convert for out-proj GEMM ---
    cvt_bf16<<<(NTOK * DI / 8 + 255) / 256, 256, 0, stream>>>(
        xz, yb, 11, 2 * DI, NTOK * DI / 8);
    transpose_cvt<<<dim3(DM / 32, DI / 32), 256, 0, stream>>>(
        W_out, W_outT, DI, DM);
    // 6. m = y @ W_out  (M=2048, N=1024, K=2048)
    gemm_bf16<<<dim3(DM / 128, NTOK / 128), 256, 0, stream>>>(
        yb, W_outT, mbuf, NTOK, DM, DI, DM);
    // 7. out = x + LN(m)
    ln_add<<<NTOK, 256, 0, stream>>>(x, mbuf, gamma, beta, out);
}

// Round 4
// 274.515 us; speedup vs baseline: 4.8132x; 2.1267x over previous
//
#include <hip/hip_runtime.h>
#include <math.h>

#define DM   1024
#define DI   2048
#define DS   16
#define DTR  64
#define NB   2
#define SEQL 1024
#define NTOK (NB*SEQL)
#define XND  96   /* DTR + 2*DS */
#define XNP  128  /* padded xproj width */
#define CK   16   /* scan chunks */
#define CL   64   /* chunk length */

typedef __bf16 bf16x8 __attribute__((ext_vector_type(8)));
typedef float  f32x4  __attribute__((ext_vector_type(4)));

// -------- fp32 -> bf16 row-major convert (strided source) --------------------
__global__ __launch_bounds__(256) void cvt_bf16(
    const float* __restrict__ src, __bf16* __restrict__ dst,
    int logW, int srcld, int total8)
{
    const int g = blockIdx.x * 256 + threadIdx.x;
    if (g >= total8) return;
    const int e = g * 8;
    const int row = e >> logW;
    const int col = e & ((1 << logW) - 1);
    const float4 v0 = *reinterpret_cast<const float4*>(&src[(size_t)row * srcld + col]);
    const float4 v1 = *reinterpret_cast<const float4*>(&src[(size_t)row * srcld + col + 4]);
    bf16x8 o;
    o[0] = (__bf16)v0.x; o[1] = (__bf16)v0.y; o[2] = (__bf16)v0.z; o[3] = (__bf16)v0.w;
    o[4] = (__bf16)v1.x; o[5] = (__bf16)v1.y; o[6] = (__bf16)v1.z; o[7] = (__bf16)v1.w;
    *reinterpret_cast<bf16x8*>(&dst[e]) = o;
}

// -------- W[K][N] fp32 -> WT[N][K] bf16 (tiled transpose) --------------------
__global__ __launch_bounds__(256) void transpose_cvt(
    const float* __restrict__ W, __bf16* __restrict__ WT, int K, int N)
{
    __shared__ __bf16 t[32][33];
    const int n0 = blockIdx.x * 32, k0 = blockIdx.y * 32;
    const int tx = threadIdx.x & 31, ty = threadIdx.x >> 5;
    #pragma unroll
    for (int i = 0; i < 4; i++)
        t[ty * 4 + i][tx] = (__bf16)W[(size_t)(k0 + ty * 4 + i) * N + n0 + tx];
    __syncthreads();
    #pragma unroll
    for (int i = 0; i < 4; i++)
        WT[(size_t)(n0 + ty * 4 + i) * K + k0 + tx] = t[tx][ty * 4 + i];
}

// -------- W_xproj[DI][96] -> WT[128][DI] bf16, rows 96..127 zero -------------
__global__ __launch_bounds__(256) void xprojT_pad(
    const float* __restrict__ W, __bf16* __restrict__ WT)
{
    const int idx = blockIdx.x * 256 + threadIdx.x;   // over 128*DI
    const int k = idx & (DI - 1);
    const int n = idx >> 11;
    WT[(size_t)n * DI + k] = (n < XND) ? (__bf16)W[(size_t)k * XND + n] : (__bf16)0.f;
}

// -------- bf16 MFMA GEMM: C[M][N] = A[M][K] * B[K][N], B given as Bt[N][K] ---
// 128x128 tile, BK=32, 256 thr = 4 waves 2x2. lda = ldb = K.
// gridDim.z = split-K count. mode: 0 = store f32, 1 = atomicAdd f32,
// 2 = softplus(acc + bias[col]) store f32.
__global__ __launch_bounds__(256) void gemm_bf16(
    const __bf16* __restrict__ A, const __bf16* __restrict__ Bt,
    float* __restrict__ C, int M, int N, int K, int ldc,
    int mode, const float* __restrict__ bias)
{
    __shared__ __bf16 As[128 * 32];
    __shared__ __bf16 Bs[128 * 32];
    const int tid  = threadIdx.x;
    const int lane = tid & 63;
    const int wid  = tid >> 6;
    const int wr   = wid >> 1, wc = wid & 1;
    const int brow = blockIdx.y * 128, bcol = blockIdx.x * 128;
    const int kper = K / gridDim.z;
    const int kbeg = blockIdx.z * kper, kend = kbeg + kper;

    f32x4 acc[4][4] = {};

    const int r0 = tid >> 2;
    const int k8 = (tid & 3) * 8;

    for (int k0 = kbeg; k0 < kend; k0 += 32) {
        __syncthreads();
        {
            const __bf16* g0 = A  + (size_t)(brow + r0)      * K + k0 + k8;
            const __bf16* g1 = A  + (size_t)(brow + 64 + r0) * K + k0 + k8;
            const __bf16* h0 = Bt + (size_t)(bcol + r0)      * K + k0 + k8;
            const __bf16* h1 = Bt + (size_t)(bcol + 64 + r0) * K + k0 + k8;
            __builtin_amdgcn_global_load_lds(
                (const __attribute__((address_space(1))) void*)g0,
                (__attribute__((address_space(3))) void*)(As + tid * 8), 16, 0, 0);
            __builtin_amdgcn_global_load_lds(
                (const __attribute__((address_space(1))) void*)g1,
                (__attribute__((address_space(3))) void*)(As + 2048 + tid * 8), 16, 0, 0);
            __builtin_amdgcn_global_load_lds(
                (const __attribute__((address_space(1))) void*)h0,
                (__attribute__((address_space(3))) void*)(Bs + tid * 8), 16, 0, 0);
            __builtin_amdgcn_global_load_lds(
                (const __attribute__((address_space(1))) void*)h1,
                (__attribute__((address_space(3))) void*)(Bs + 2048 + tid * 8), 16, 0, 0);
        }
        __syncthreads();
        bf16x8 a[4], b[4];
        const int rA = wr * 64 + (lane & 15);
        const int rB = wc * 64 + (lane & 15);
        const int kf = (lane >> 4) * 8;
        #pragma unroll
        for (int m = 0; m < 4; m++)
            a[m] = *reinterpret_cast<const bf16x8*>(&As[(rA + m * 16) * 32 + kf]);
        #pragma unroll
        for (int n = 0; n < 4; n++)
            b[n] = *reinterpret_cast<const bf16x8*>(&Bs[(rB + n * 16) * 32 + kf]);
        #pragma unroll
        for (int m = 0; m < 4; m++)
            #pragma unroll
            for (int n = 0; n < 4; n++)
                acc[m][n] = __builtin_amdgcn_mfma_f32_16x16x32_bf16(
                    a[m], b[n], acc[m][n], 0, 0, 0);
    }
    const int crow = brow + wr * 64 + (lane >> 4) * 4;
    const int ccol = bcol + wc * 64 + (lane & 15);
    #pragma unroll
    for (int m = 0; m < 4; m++)
        #pragma unroll
        for (int n = 0; n < 4; n++) {
            const int col = ccol + n * 16;
            #pragma unroll
            for (int j = 0; j < 4; j++) {
                const size_t idx = (size_t)(crow + m * 16 + j) * ldc + col;
                if (mode == 0) {
                    C[idx] = acc[m][n][j];
                } else if (mode == 1) {
                    atomicAdd(&C[idx], acc[m][n][j]);
                } else {
                    const float v = acc[m][n][j] + bias[col];
                    C[idx] = fmaxf(v, 0.f) + log1pf(__expf(-fabsf(v)));
                }
            }
        }
}

// -------- depthwise causal conv (k=4) + bias + SiLU -> bf16 ------------------
__global__ __launch_bounds__(256) void conv_silu(
    const float* __restrict__ xz, const float* __restrict__ conv_w,
    const float* __restrict__ conv_b, __bf16* __restrict__ xcb)
{
    const int g = blockIdx.x * 256 + threadIdx.x;
    const int d   = g & (DI - 1);
    const int tok = g >> 11;
    const int t   = tok & (SEQL - 1);
    const float4 w = *reinterpret_cast<const float4*>(&conv_w[d * 4]);
    const float wk[4] = { w.x, w.y, w.z, w.w };
    float acc = conv_b[d];
    #pragma unroll
    for (int k = 0; k < 4; k++) {
        const int tt = t + k - 3;
        if (tt >= 0)
            acc += xz[(size_t)(tok + k - 3) * (2 * DI) + d] * wk[k];
    }
    xcb[g] = (__bf16)(acc / (1.f + __expf(-acc)));
}

// -------- scan pass A: per-chunk local scan from h=0 -------------------------
// grid (DI/256, CK, NB), 256 thr, thread-per-channel, 16 states in regs.
__global__ __launch_bounds__(256) void scan_partial(
    const __bf16* __restrict__ xcb, const float* __restrict__ xdbl,
    const float* __restrict__ dtb, const float* __restrict__ A_log,
    float* __restrict__ hfin, float* __restrict__ sdtb)
{
    __shared__ float Bsh[CL][16];
    const int tid = threadIdx.x;
    const int d = blockIdx.x * 256 + tid;
    const int c = blockIdx.y, b = blockIdx.z;
    const size_t base = (size_t)b * SEQL + c * CL;
    {
        const int st = tid >> 2, sg = (tid & 3) * 4;
        *reinterpret_cast<float4*>(&Bsh[st][sg]) =
            *reinterpret_cast<const float4*>(&xdbl[(base + st) * XNP + DTR + sg]);
    }
    float Av[16];
    #pragma unroll
    for (int i = 0; i < 4; i++) {
        const float4 v = *reinterpret_cast<const float4*>(&A_log[(size_t)d * 16 + i * 4]);
        Av[i*4+0] = -__expf(v.x); Av[i*4+1] = -__expf(v.y);
        Av[i*4+2] = -__expf(v.z); Av[i*4+3] = -__expf(v.w);
    }
    __syncthreads();
    float h[16] = {};
    float sdt = 0.f;
    #pragma unroll 4
    for (int t = 0; t < CL; t++) {
        const float dtv = dtb[(base + t) * DI + d];
        const float xcv = (float)xcb[(base + t) * DI + d];
        sdt += dtv;
        const float dx = dtv * xcv;
        #pragma unroll
        for (int n = 0; n < 16; n++)
            h[n] = __expf(dtv * Av[n]) * h[n] + dx * Bsh[t][n];
    }
    const size_t ob = ((size_t)(b * CK + c) * DI + d) * 16;
    #pragma unroll
    for (int i = 0; i < 4; i++) {
        float4 v; v.x = h[i*4]; v.y = h[i*4+1]; v.z = h[i*4+2]; v.w = h[i*4+3];
        *reinterpret_cast<float4*>(&hfin[ob + i * 4]) = v;
    }
    sdtb[(size_t)(b * CK + c) * DI + d] = sdt;
}

// -------- scan pass B: sequential chunk combine; hfin -> entry states --------
__global__ __launch_bounds__(256) void scan_combine(
    const float* __restrict__ A_log, const float* __restrict__ sdtb,
    float* __restrict__ hfin)
{
    const int idx = blockIdx.x * 256 + threadIdx.x;   // over NB*DI*16
    const int n = idx & 15;
    const int d = (idx >> 4) & (DI - 1);
    const int b = idx >> 15;
    const float A = -__expf(A_log[(size_t)d * 16 + n]);
    float h = 0.f;
    for (int c = 0; c < CK; c++) {
        const size_t hb = ((size_t)(b * CK + c) * DI + d) * 16 + n;
        const float hl = hfin[hb];
        const float s  = sdtb[(size_t)(b * CK + c) * DI + d];
        hfin[hb] = h;
        h = __expf(A * s) * h + hl;
    }
}

// -------- scan pass C: seeded re-scan, emit y (D-skip + z-gate) as bf16 ------
__global__ __launch_bounds__(256) void scan_final(
    const float* __restrict__ xz, const __bf16* __restrict__ xcb,
    const float* __restrict__ xdbl, const float* __restrict__ dtb,
    const float* __restrict__ A_log, const float* __restrict__ Dp,
    const float* __restrict__ hfin, __bf16* __restrict__ yb)
{
    __shared__ float Bsh[CL][16];
    __shared__ float Csh[CL][16];
    const int tid = threadIdx.x;
    const int d = blockIdx.x * 256 + tid;
    const int c = blockIdx.y, b = blockIdx.z;
    const size_t base = (size_t)b * SEQL + c * CL;
    {
        const int st = tid >> 2, sg = (tid & 3) * 4;
        *reinterpret_cast<float4*>(&Bsh[st][sg]) =
            *reinterpret_cast<const float4*>(&xdbl[(base + st) * XNP + DTR + sg]);
        *reinterpret_cast<float4*>(&Csh[st][sg]) =
            *reinterpret_cast<const float4*>(&xdbl[(base + st) * XNP + DTR + DS + sg]);
    }
    float Av[16];
    #pragma unroll
    for (int i = 0; i < 4; i++) {
        const float4 v = *reinterpret_cast<const float4*>(&A_log[(size_t)d * 16 + i * 4]);
        Av[i*4+0] = -__expf(v.x); Av[i*4+1] = -__expf(v.y);
        Av[i*4+2] = -__expf(v.z); Av[i*4+3] = -__expf(v.w);
    }
    float h[16];
    const size_t ob = ((size_t)(b * CK + c) * DI + d) * 16;
    #pragma unroll
    for (int i = 0; i < 4; i++) {
        const float4 v = *reinterpret_cast<const float4*>(&hfin[ob + i * 4]);
        h[i*4] = v.x; h[i*4+1] = v.y; h[i*4+2] = v.z; h[i*4+3] = v.w;
    }
    const float Dv = Dp[d];
    __syncthreads();
    #pragma unroll 4
    for (int t = 0; t < CL; t++) {
        const size_t tok = base + t;
        const float dtv = dtb[tok * DI + d];
        const float xcv = (float)xcb[tok * DI + d];
        const float zv  = xz[tok * (2 * DI) + DI + d];
        const float dx = dtv * xcv;
        float y = 0.f;
        #pragma unroll
        for (int n = 0; n < 16; n++) {
            h[n] = __expf(dtv * Av[n]) * h[n] + dx * Bsh[t][n];
            y += h[n] * Csh[t][n];
        }
        y += xcv * Dv;
        y *= zv / (1.f + __expf(-zv));
        yb[tok * DI + d] = (__bf16)y;
    }
}

// -------- out = x + LayerNorm(m) ---------------------------------------------
__global__ __launch_bounds__(256) void ln_add(
    const float* __restrict__ x, const float* __restrict__ m,
    const float* __restrict__ gamma, const float* __restrict__ beta,
    float* __restrict__ out)
{
    const int tok = blockIdx.x;
    const int tid = threadIdx.x;
    const int lane = tid & 63, wave = tid >> 6;
    __shared__ float red[4];
    __shared__ float stats[2];

    const float4 v = reinterpret_cast<const float4*>(&m[(size_t)tok * DM])[tid];
    float s = v.x + v.y + v.z + v.w;
    #pragma unroll
    for (int o = 32; o > 0; o >>= 1) s += __shfl_down(s, o, 64);
    if (lane == 0) red[wave] = s;
    __syncthreads();
    if (tid == 0) stats[0] = (red[0] + red[1] + red[2] + red[3]) * (1.f / DM);
    __syncthreads();
    const float mu = stats[0];
    const float dx = v.x - mu, dy = v.y - mu, dz = v.z - mu, dw = v.w - mu;
    float q = dx * dx + dy * dy + dz * dz + dw * dw;
    #pragma unroll
    for (int o = 32; o > 0; o >>= 1) q += __shfl_down(q, o, 64);
    if (lane == 0) red[wave] = q;
    __syncthreads();
    if (tid == 0)
        stats[1] = rsqrtf((red[0] + red[1] + red[2] + red[3]) * (1.f / DM) + 1e-6f);
    __syncthreads();
    const float rs = stats[1];

    const float4 g  = reinterpret_cast<const float4*>(gamma)[tid];
    const float4 bb = reinterpret_cast<const float4*>(beta)[tid];
    const float4 xv = reinterpret_cast<const float4*>(&x[(size_t)tok * DM])[tid];
    float4 o;
    o.x = xv.x + dx * rs * g.x + bb.x;
    o.y = xv.y + dy * rs * g.y + bb.y;
    o.z = xv.z + dz * rs * g.z + bb.z;
    o.w = xv.w + dw * rs * g.w + bb.w;
    reinterpret_cast<float4*>(&out[(size_t)tok * DM])[tid] = o;
}

extern "C" void kernel_launch(void* const* d_in, const int* in_sizes, int n_in,
                              void* d_out, int out_size, void* d_ws, size_t ws_size,
                              hipStream_t stream)
{
    const float* x      = (const float*)d_in[0];
    const float* W_in   = (const float*)d_in[1];
    const float* conv_w = (const float*)d_in[2];
    const float* conv_b = (const float*)d_in[3];
    const float* W_xprj = (const float*)d_in[4];
    const float* W_dt   = (const float*)d_in[5];
    const float* b_dt   = (const float*)d_in[6];
    const float* A_log  = (const float*)d_in[7];
    const float* D_par  = (const float*)d_in[8];
    const float* W_out  = (const float*)d_in[9];
    const float* gamma  = (const float*)d_in[10];
    const float* beta   = (const float*)d_in[11];
    float* out = (float*)d_out;

    // workspace layout (byte offsets); aliases are safe by stream ordering
    char* w = (char*)d_ws;
    float*  xz     = (float*) (w + 0);          // 32 MB  [NTOK][4096]
    __bf16* xcb    = (__bf16*)(w + 33554432);   //  8 MB  [NTOK][DI]
    float*  xdbl   = (float*) (w + 41943040);   //  1 MB  [NTOK][128]
    __bf16* rb     = (__bf16*)(w + 42991616);   // .25 MB [NTOK][64]
    float*  dtbuf  = (float*) (w + 43253760);   // 16 MB  [NTOK][DI]
    float*  mbuf   = (float*) (w + 60030976);   //  8 MB  [NTOK][DM]   (alias: hfin)
    float*  hfin   = (float*) (w + 60030976);   //  8 MB  [NB*CK][DI][16]
    float*  sdtb   = (float*) (w + 68419584);   // .25 MB [NB*CK][DI]
    __bf16* xb     = (__bf16*)(w + 68681728);   //  4 MB  (alias: W_outT)
    __bf16* W_outT = (__bf16*)(w + 68681728);
    __bf16* W_inT  = (__bf16*)(w + 72876032);   //  8 MB  (alias: yb)
    __bf16* yb     = (__bf16*)(w + 72876032);
    __bf16* W_xprT = (__bf16*)(w + 81264640);   // .5 MB  [128][DI]
    __bf16* WdtT   = (__bf16*)(w + 81788928);   // .25 MB [DI][64]

    // --- conversions for in-proj ---
    cvt_bf16<<<NTOK * DM / 8 / 256, 256, 0, stream>>>(x, xb, 10, DM, NTOK * DM / 8);
    transpose_cvt<<<dim3(2 * DI / 32, DM / 32), 256, 0, stream>>>(W_in, W_inT, DM, 2 * DI);
    xprojT_pad<<<XNP * DI / 256, 256, 0, stream>>>(W_xprj, W_xprT);
    transpose_cvt<<<dim3(DI / 32, DTR / 32), 256, 0, stream>>>(W_dt, WdtT, DTR, DI);

    // 1. xz = x @ W_in   (M=2048, N=4096, K=1024)
    gemm_bf16<<<dim3(2 * DI / 128, NTOK / 128, 1), 256, 0, stream>>>(
        xb, W_inT, xz, NTOK, 2 * DI, DM, 2 * DI, 0, nullptr);
    // W_out transpose (after in-proj: aliases xb)
    transpose_cvt<<<dim3(DM / 32, DI / 32), 256, 0, stream>>>(W_out, W_outT, DI, DM);

    // 2. conv + silu -> bf16
    conv_silu<<<(NTOK * DI) / 256, 256, 0, stream>>>(xz, conv_w, conv_b, xcb);

    // 3. x_dbl = xc @ W_xproj  (M=2048, N=128pad, K=2048), split-K=4, atomic
    hipMemsetAsync(xdbl, 0, (size_t)NTOK * XNP * 4, stream);
    gemm_bf16<<<dim3(1, NTOK / 128, 4), 256, 0, stream>>>(
        xcb, W_xprT, xdbl, NTOK, XNP, DI, XNP, 1, nullptr);

    // 4. dt = softplus(dt_r @ W_dt + b_dt)  (M=2048, N=2048, K=64)
    cvt_bf16<<<NTOK * DTR / 8 / 256, 256, 0, stream>>>(xdbl, rb, 6, XNP, NTOK * DTR / 8);
    gemm_bf16<<<dim3(DI / 128, NTOK / 128, 1), 256, 0, stream>>>(
        rb, WdtT, dtbuf, NTOK, DI, DTR, DI, 2, b_dt);

    // 5. chunked selective scan
    scan_partial<<<dim3(DI / 256, CK, NB), 256, 0, stream>>>(
        xcb, xdbl, dtbuf, A_log, hfin, sdtb);
    scan_combine<<<NB * DI * DS / 256, 256, 0, stream>>>(A_log, sdtb, hfin);
    scan_final<<<dim3(DI / 256, CK, NB), 256, 0, stream>>>(
        xz, xcb, xdbl, dtbuf, A_log, D_par, hfin, yb);

    // 6. m = y @ W_out   (M=2048, N=1024, K=2048)
    gemm_bf16<<<dim3(DM / 128, NTOK / 128, 1), 256, 0, stream>>>(
        yb, W_outT, mbuf, NTOK, DM, DI, DM, 0, nullptr);

    // 7. out = x + LN(m)
    ln_add<<<NTOK, 256, 0, stream>>>(x, mbuf, gamma, beta, out);
}

// Round 5
// 261.534 us; speedup vs baseline: 5.0521x; 1.0496x over previous
//
#include <hip/hip_runtime.h>
#include <math.h>

#define DM   1024
#define DI   2048
#define DS   16
#define DTR  64
#define NB   2
#define SEQL 1024
#define NTOK (NB*SEQL)
#define XND  96   /* DTR + 2*DS */
#define XNP  128  /* padded xproj width */
#define CK   16   /* scan chunks */
#define CL   64   /* chunk length */

typedef __bf16 bf16x8 __attribute__((ext_vector_type(8)));
typedef float  f32x4  __attribute__((ext_vector_type(4)));

// -------- fp32 -> bf16 row-major convert (strided source) --------------------
__global__ __launch_bounds__(256) void cvt_bf16(
    const float* __restrict__ src, __bf16* __restrict__ dst,
    int logW, int srcld, int total8)
{
    const int g = blockIdx.x * 256 + threadIdx.x;
    if (g >= total8) return;
    const int e = g * 8;
    const int row = e >> logW;
    const int col = e & ((1 << logW) - 1);
    const float4 v0 = *reinterpret_cast<const float4*>(&src[(size_t)row * srcld + col]);
    const float4 v1 = *reinterpret_cast<const float4*>(&src[(size_t)row * srcld + col + 4]);
    bf16x8 o;
    o[0] = (__bf16)v0.x; o[1] = (__bf16)v0.y; o[2] = (__bf16)v0.z; o[3] = (__bf16)v0.w;
    o[4] = (__bf16)v1.x; o[5] = (__bf16)v1.y; o[6] = (__bf16)v1.z; o[7] = (__bf16)v1.w;
    *reinterpret_cast<bf16x8*>(&dst[e]) = o;
}

// -------- W[K][N] fp32 -> WT[N][K] bf16 (tiled transpose) --------------------
__global__ __launch_bounds__(256) void transpose_cvt(
    const float* __restrict__ W, __bf16* __restrict__ WT, int K, int N)
{
    __shared__ __bf16 t[32][33];
    const int n0 = blockIdx.x * 32, k0 = blockIdx.y * 32;
    const int tx = threadIdx.x & 31, ty = threadIdx.x >> 5;
    #pragma unroll
    for (int i = 0; i < 4; i++)
        t[ty * 4 + i][tx] = (__bf16)W[(size_t)(k0 + ty * 4 + i) * N + n0 + tx];
    __syncthreads();
    #pragma unroll
    for (int i = 0; i < 4; i++)
        WT[(size_t)(n0 + ty * 4 + i) * K + k0 + tx] = t[tx][ty * 4 + i];
}

// -------- W_xproj[DI][96] -> WT[128][DI] bf16, rows 96..127 zero -------------
__global__ __launch_bounds__(256) void xprojT_pad(
    const float* __restrict__ W, __bf16* __restrict__ WT)
{
    const int idx = blockIdx.x * 256 + threadIdx.x;
    const int k = idx & (DI - 1);
    const int n = idx >> 11;
    WT[(size_t)n * DI + k] = (n < XND) ? (__bf16)W[(size_t)k * XND + n] : (__bf16)0.f;
}

// -------- bf16 MFMA GEMM, 128x128 tile, BK=64, XOR-swizzled LDS --------------
// MODE 0: store f32 | 1: atomicAdd f32 | 2: softplus(acc+bias)->bf16 | 3: bf16
// Bt is [N][K] (B transposed). gridDim.z = split-K factor (kper % 64 == 0).
template<int MODE>
__global__ __launch_bounds__(256) void gemm_bf16(
    const __bf16* __restrict__ A, const __bf16* __restrict__ Bt,
    void* __restrict__ Cp, int M, int N, int K, int ldc,
    const float* __restrict__ bias)
{
    __shared__ __bf16 As[128 * 64];
    __shared__ __bf16 Bs[128 * 64];
    const int tid  = threadIdx.x;
    const int lane = tid & 63;
    const int wid  = tid >> 6;
    const int wr   = wid >> 1, wc = wid & 1;
    const int brow = blockIdx.y * 128, bcol = blockIdx.x * 128;
    const int kper = K / gridDim.z;
    const int kbeg = blockIdx.z * kper, kend = kbeg + kper;

    f32x4 acc[4][4] = {};

    for (int k0 = kbeg; k0 < kend; k0 += 64) {
        __syncthreads();
        // stage: chunk i = p*256+tid; row=i>>3, slot=i&7; LDS linear (dest =
        // base+lane*16 per wave), global col-chunk = slot^(row&7)  [rule #21]
        #pragma unroll
        for (int p = 0; p < 4; p++) {
            const int i = p * 256 + tid;
            const int r = i >> 3;
            const int gc = ((i & 7) ^ (r & 7)) * 8;
            __builtin_amdgcn_global_load_lds(
                (const __attribute__((address_space(1))) void*)(A + (size_t)(brow + r) * K + k0 + gc),
                (__attribute__((address_space(3))) void*)(As + i * 8), 16, 0, 0);
            __builtin_amdgcn_global_load_lds(
                (const __attribute__((address_space(1))) void*)(Bt + (size_t)(bcol + r) * K + k0 + gc),
                (__attribute__((address_space(3))) void*)(Bs + i * 8), 16, 0, 0);
        }
        __syncthreads();
        bf16x8 a[2][4], b[2][4];
        const int rA = wr * 64 + (lane & 15);
        const int rB = wc * 64 + (lane & 15);
        const int cq = lane >> 4;            // 16B chunk within K-subtile
        const int rx = lane & 7;             // == R&7 for all fragment rows
        #pragma unroll
        for (int ks = 0; ks < 2; ks++) {
            const int sl = ((ks * 4 + cq) ^ rx) * 8;
            #pragma unroll
            for (int m = 0; m < 4; m++) {
                a[ks][m] = *reinterpret_cast<const bf16x8*>(&As[(rA + m * 16) * 64 + sl]);
                b[ks][m] = *reinterpret_cast<const bf16x8*>(&Bs[(rB + m * 16) * 64 + sl]);
            }
        }
        #pragma unroll
        for (int ks = 0; ks < 2; ks++)
            #pragma unroll
            for (int m = 0; m < 4; m++)
                #pragma unroll
                for (int n = 0; n < 4; n++)
                    acc[m][n] = __builtin_amdgcn_mfma_f32_16x16x32_bf16(
                        a[ks][m], b[ks][n], acc[m][n], 0, 0, 0);
    }
    const int crow = brow + wr * 64 + (lane >> 4) * 4;
    const int ccol = bcol + wc * 64 + (lane & 15);
    #pragma unroll
    for (int m = 0; m < 4; m++)
        #pragma unroll
        for (int n = 0; n < 4; n++) {
            const int col = ccol + n * 16;
            #pragma unroll
            for (int j = 0; j < 4; j++) {
                const size_t idx = (size_t)(crow + m * 16 + j) * ldc + col;
                if (MODE == 0) {
                    ((float*)Cp)[idx] = acc[m][n][j];
                } else if (MODE == 1) {
                    atomicAdd(&((float*)Cp)[idx], acc[m][n][j]);
                } else if (MODE == 2) {
                    const float v = acc[m][n][j] + bias[col];
                    ((__bf16*)Cp)[idx] =
                        (__bf16)(fmaxf(v, 0.f) + log1pf(__expf(-fabsf(v))));
                } else {
                    ((__bf16*)Cp)[idx] = (__bf16)acc[m][n][j];
                }
            }
        }
}

// -------- depthwise causal conv (k=4) + bias + SiLU (bf16 in/out) ------------
__global__ __launch_bounds__(256) void conv_silu(
    const __bf16* __restrict__ xzb, const float* __restrict__ conv_w,
    const float* __restrict__ conv_b, __bf16* __restrict__ xcb)
{
    const int g = blockIdx.x * 256 + threadIdx.x;
    const int d   = g & (DI - 1);
    const int tok = g >> 11;
    const int t   = tok & (SEQL - 1);
    const float4 w = *reinterpret_cast<const float4*>(&conv_w[d * 4]);
    const float wk[4] = { w.x, w.y, w.z, w.w };
    float acc = conv_b[d];
    #pragma unroll
    for (int k = 0; k < 4; k++) {
        const int tt = t + k - 3;
        if (tt >= 0)
            acc += (float)xzb[(size_t)(tok + k - 3) * (2 * DI) + d] * wk[k];
    }
    xcb[g] = (__bf16)(acc / (1.f + __expf(-acc)));
}

// -------- scan pass A: per-chunk local scan from h=0 -------------------------
__global__ __launch_bounds__(256) void scan_partial(
    const __bf16* __restrict__ xcb, const float* __restrict__ xdbl,
    const __bf16* __restrict__ dtb, const float* __restrict__ A_log,
    float* __restrict__ hfin, float* __restrict__ sdtb)
{
    __shared__ float Bsh[CL][16];
    const int tid = threadIdx.x;
    const int d = blockIdx.x * 256 + tid;
    const int c = blockIdx.y, b = blockIdx.z;
    const size_t base = (size_t)b * SEQL + c * CL;
    {
        const int st = tid >> 2, sg = (tid & 3) * 4;
        *reinterpret_cast<float4*>(&Bsh[st][sg]) =
            *reinterpret_cast<const float4*>(&xdbl[(base + st) * XNP + DTR + sg]);
    }
    float Av[16];
    #pragma unroll
    for (int i = 0; i < 4; i++) {
        const float4 v = *reinterpret_cast<const float4*>(&A_log[(size_t)d * 16 + i * 4]);
        Av[i*4+0] = -__expf(v.x); Av[i*4+1] = -__expf(v.y);
        Av[i*4+2] = -__expf(v.z); Av[i*4+3] = -__expf(v.w);
    }
    __syncthreads();
    float h[16] = {};
    float sdt = 0.f;
    #pragma unroll 4
    for (int t = 0; t < CL; t++) {
        const float dtv = (float)dtb[(base + t) * DI + d];
        const float xcv = (float)xcb[(base + t) * DI + d];
        sdt += dtv;
        const float dx = dtv * xcv;
        #pragma unroll
        for (int n = 0; n < 16; n++)
            h[n] = __expf(dtv * Av[n]) * h[n] + dx * Bsh[t][n];
    }
    const size_t ob = ((size_t)(b * CK + c) * DI + d) * 16;
    #pragma unroll
    for (int i = 0; i < 4; i++) {
        float4 v; v.x = h[i*4]; v.y = h[i*4+1]; v.z = h[i*4+2]; v.w = h[i*4+3];
        *reinterpret_cast<float4*>(&hfin[ob + i * 4]) = v;
    }
    sdtb[(size_t)(b * CK + c) * DI + d] = sdt;
}

// -------- scan pass B: sequential chunk combine; hfin -> entry states --------
__global__ __launch_bounds__(256) void scan_combine(
    const float* __restrict__ A_log, const float* __restrict__ sdtb,
    float* __restrict__ hfin)
{
    const int idx = blockIdx.x * 256 + threadIdx.x;
    const int n = idx & 15;
    const int d = (idx >> 4) & (DI - 1);
    const int b = idx >> 15;
    const float A = -__expf(A_log[(size_t)d * 16 + n]);
    float h = 0.f;
    for (int c = 0; c < CK; c++) {
        const size_t hb = ((size_t)(b * CK + c) * DI + d) * 16 + n;
        const float hl = hfin[hb];
        const float s  = sdtb[(size_t)(b * CK + c) * DI + d];
        hfin[hb] = h;
        h = __expf(A * s) * h + hl;
    }
}

// -------- scan pass C: seeded re-scan, emit y (D-skip + z-gate) as bf16 ------
__global__ __launch_bounds__(256) void scan_final(
    const __bf16* __restrict__ xzb, const __bf16* __restrict__ xcb,
    const float* __restrict__ xdbl, const __bf16* __restrict__ dtb,
    const float* __restrict__ A_log, const float* __restrict__ Dp,
    const float* __restrict__ hfin, __bf16* __restrict__ yb)
{
    __shared__ float Bsh[CL][16];
    __shared__ float Csh[CL][16];
    const int tid = threadIdx.x;
    const int d = blockIdx.x * 256 + tid;
    const int c = blockIdx.y, b = blockIdx.z;
    const size_t base = (size_t)b * SEQL + c * CL;
    {
        const int st = tid >> 2, sg = (tid & 3) * 4;
        *reinterpret_cast<float4*>(&Bsh[st][sg]) =
            *reinterpret_cast<const float4*>(&xdbl[(base + st) * XNP + DTR + sg]);
        *reinterpret_cast<float4*>(&Csh[st][sg]) =
            *reinterpret_cast<const float4*>(&xdbl[(base + st) * XNP + DTR + DS + sg]);
    }
    float Av[16];
    #pragma unroll
    for (int i = 0; i < 4; i++) {
        const float4 v = *reinterpret_cast<const float4*>(&A_log[(size_t)d * 16 + i * 4]);
        Av[i*4+0] = -__expf(v.x); Av[i*4+1] = -__expf(v.y);
        Av[i*4+2] = -__expf(v.z); Av[i*4+3] = -__expf(v.w);
    }
    float h[16];
    const size_t ob = ((size_t)(b * CK + c) * DI + d) * 16;
    #pragma unroll
    for (int i = 0; i < 4; i++) {
        const float4 v = *reinterpret_cast<const float4*>(&hfin[ob + i * 4]);
        h[i*4] = v.x; h[i*4+1] = v.y; h[i*4+2] = v.z; h[i*4+3] = v.w;
    }
    const float Dv = Dp[d];
    __syncthreads();
    #pragma unroll 4
    for (int t = 0; t < CL; t++) {
        const size_t tok = base + t;
        const float dtv = (float)dtb[tok * DI + d];
        const float xcv = (float)xcb[tok * DI + d];
        const float zv  = (float)xzb[tok * (2 * DI) + DI + d];
        const float dx = dtv * xcv;
        float y = 0.f;
        #pragma unroll
        for (int n = 0; n < 16; n++) {
            h[n] = __expf(dtv * Av[n]) * h[n] + dx * Bsh[t][n];
            y += h[n] * Csh[t][n];
        }
        y += xcv * Dv;
        y *= zv / (1.f + __expf(-zv));
        yb[tok * DI + d] = (__bf16)y;
    }
}

// -------- out = x + LayerNorm(m) ---------------------------------------------
__global__ __launch_bounds__(256) void ln_add(
    const float* __restrict__ x, const float* __restrict__ m,
    const float* __restrict__ gamma, const float* __restrict__ beta,
    float* __restrict__ out)
{
    const int tok = blockIdx.x;
    const int tid = threadIdx.x;
    const int lane = tid & 63, wave = tid >> 6;
    __shared__ float red[4];
    __shared__ float stats[2];

    const float4 v = reinterpret_cast<const float4*>(&m[(size_t)tok * DM])[tid];
    float s = v.x + v.y + v.z + v.w;
    #pragma unroll
    for (int o = 32; o > 0; o >>= 1) s += __shfl_down(s, o, 64);
    if (lane == 0) red[wave] = s;
    __syncthreads();
    if (tid == 0) stats[0] = (red[0] + red[1] + red[2] + red[3]) * (1.f / DM);
    __syncthreads();
    const float mu = stats[0];
    const float dx = v.x - mu, dy = v.y - mu, dz = v.z - mu, dw = v.w - mu;
    float q = dx * dx + dy * dy + dz * dz + dw * dw;
    #pragma unroll
    for (int o = 32; o > 0; o >>= 1) q += __shfl_down(q, o, 64);
    if (lane == 0) red[wave] = q;
    __syncthreads();
    if (tid == 0)
        stats[1] = rsqrtf((red[0] + red[1] + red[2] + red[3]) * (1.f / DM) + 1e-6f);
    __syncthreads();
    const float rs = stats[1];

    const float4 g  = reinterpret_cast<const float4*>(gamma)[tid];
    const float4 bb = reinterpret_cast<const float4*>(beta)[tid];
    const float4 xv = reinterpret_cast<const float4*>(&x[(size_t)tok * DM])[tid];
    float4 o;
    o.x = xv.x + dx * rs * g.x + bb.x;
    o.y = xv.y + dy * rs * g.y + bb.y;
    o.z = xv.z + dz * rs * g.z + bb.z;
    o.w = xv.w + dw * rs * g.w + bb.w;
    reinterpret_cast<float4*>(&out[(size_t)tok * DM])[tid] = o;
}

extern "C" void kernel_launch(void* const* d_in, const int* in_sizes, int n_in,
                              void* d_out, int out_size, void* d_ws, size_t ws_size,
                              hipStream_t stream)
{
    const float* x      = (const float*)d_in[0];
    const float* W_in   = (const float*)d_in[1];
    const float* conv_w = (const float*)d_in[2];
    const float* conv_b = (const float*)d_in[3];
    const float* W_xprj = (const float*)d_in[4];
    const float* W_dt   = (const float*)d_in[5];
    const float* b_dt   = (const float*)d_in[6];
    const float* A_log  = (const float*)d_in[7];
    const float* D_par  = (const float*)d_in[8];
    const float* W_out  = (const float*)d_in[9];
    const float* gamma  = (const float*)d_in[10];
    const float* beta   = (const float*)d_in[11];
    float* out = (float*)d_out;

    // workspace layout (byte offsets); aliases safe by stream ordering
    char* w = (char*)d_ws;
    __bf16* xzb    = (__bf16*)(w + 0);          // 16 MB [NTOK][4096] (xi|z)
    __bf16* xcb    = (__bf16*)(w + 16777216);   //  8 MB [NTOK][DI]
    float*  xdbl   = (float*) (w + 25165824);   //  1 MB [NTOK][128]
    __bf16* rb     = (__bf16*)(w + 26214400);   // .25MB [NTOK][64]
    __bf16* dtb    = (__bf16*)(w + 26476544);   //  8 MB [NTOK][DI]
    float*  mbuf   = (float*) (w + 34865152);   //  8 MB [NTOK][DM] (alias hfin)
    float*  hfin   = (float*) (w + 34865152);   //  4 MB [NB*CK][DI][16]
    float*  sdtb   = (float*) (w + 43253760);   // .25MB [NB*CK][DI]
    __bf16* xb     = (__bf16*)(w + 43515904);   //  4 MB (alias W_outT)
    __bf16* W_outT = (__bf16*)(w + 43515904);   //  4 MB [DM][DI]
    __bf16* W_inT  = (__bf16*)(w + 47710208);   //  8 MB [4096][DM] (alias yb)
    __bf16* yb     = (__bf16*)(w + 47710208);   //  8 MB [NTOK][DI]
    __bf16* W_xprT = (__bf16*)(w + 56098816);   // .5MB [128][DI]
    __bf16* WdtT   = (__bf16*)(w + 56623104);   // .25MB [DI][64]

    // --- weight/input prep ---
    cvt_bf16<<<NTOK * DM / 8 / 256, 256, 0, stream>>>(x, xb, 10, DM, NTOK * DM / 8);
    transpose_cvt<<<dim3(2 * DI / 32, DM / 32), 256, 0, stream>>>(W_in, W_inT, DM, 2 * DI);
    xprojT_pad<<<XNP * DI / 256, 256, 0, stream>>>(W_xprj, W_xprT);
    transpose_cvt<<<dim3(DI / 32, DTR / 32), 256, 0, stream>>>(W_dt, WdtT, DTR, DI);

    // 1. xz = x @ W_in  (M=2048, N=4096, K=1024) -> bf16
    gemm_bf16<3><<<dim3(32, 16, 1), 256, 0, stream>>>(
        xb, W_inT, xzb, NTOK, 2 * DI, DM, 2 * DI, nullptr);
    // W_out transpose (aliases xb; must follow in-proj)
    transpose_cvt<<<dim3(DM / 32, DI / 32), 256, 0, stream>>>(W_out, W_outT, DI, DM);

    // 2. conv + silu -> bf16
    conv_silu<<<(NTOK * DI) / 256, 256, 0, stream>>>(xzb, conv_w, conv_b, xcb);

    // 3. x_dbl = xc @ W_xproj  (N=128 pad, K=2048), split-K=16, atomic f32
    hipMemsetAsync(xdbl, 0, (size_t)NTOK * XNP * 4, stream);
    gemm_bf16<1><<<dim3(1, 16, 16), 256, 0, stream>>>(
        xcb, W_xprT, xdbl, NTOK, XNP, DI, XNP, nullptr);

    // 4. dt = softplus(dt_r @ W_dt + b_dt) -> bf16  (K=64)
    cvt_bf16<<<NTOK * DTR / 8 / 256, 256, 0, stream>>>(xdbl, rb, 6, XNP, NTOK * DTR / 8);
    gemm_bf16<2><<<dim3(16, 16, 1), 256, 0, stream>>>(
        rb, WdtT, dtb, NTOK, DI, DTR, DI, b_dt);

    // 5. chunked selective scan
    scan_partial<<<dim3(DI / 256, CK, NB), 256, 0, stream>>>(
        xcb, xdbl, dtb, A_log, hfin, sdtb);
    scan_combine<<<NB * DI * DS / 256, 256, 0, stream>>>(A_log, sdtb, hfin);
    scan_final<<<dim3(DI / 256, CK, NB), 256, 0, stream>>>(
        xzb, xcb, xdbl, dtb, A_log, D_par, hfin, yb);

    // 6. m = y @ W_out  (M=2048, N=1024, K=2048), split-K=4, atomic f32
    hipMemsetAsync(mbuf, 0, (size_t)NTOK * DM * 4, stream);
    gemm_bf16<1><<<dim3(8, 16, 4), 256, 0, stream>>>(
        yb, W_outT, mbuf, NTOK, DM, DI, DM, nullptr);

    // 7. out = x + LN(m)
    ln_add<<<NTOK, 256, 0, stream>>>(x, mbuf, gamma, beta, out);
}

// Round 6
// 209.651 us; speedup vs baseline: 6.3023x; 1.2475x over previous
//
#include <hip/hip_runtime.h>
#include <math.h>

#define DM   1024
#define DI   2048
#define DS   16
#define DTR  64
#define NB   2
#define SEQL 1024
#define NTOK (NB*SEQL)
#define XND  96   /* DTR + 2*DS */
#define XNP  128  /* padded xproj width */
#define CK   64   /* scan chunks */
#define CL   16   /* chunk length */

typedef __bf16 bf16x8 __attribute__((ext_vector_type(8)));
typedef float  f32x4  __attribute__((ext_vector_type(4)));

// -------- fp32 -> bf16 row-major convert (strided source) --------------------
__global__ __launch_bounds__(256) void cvt_bf16(
    const float* __restrict__ src, __bf16* __restrict__ dst,
    int logW, int srcld, int total8)
{
    const int g = blockIdx.x * 256 + threadIdx.x;
    if (g >= total8) return;
    const int e = g * 8;
    const int row = e >> logW;
    const int col = e & ((1 << logW) - 1);
    const float4 v0 = *reinterpret_cast<const float4*>(&src[(size_t)row * srcld + col]);
    const float4 v1 = *reinterpret_cast<const float4*>(&src[(size_t)row * srcld + col + 4]);
    bf16x8 o;
    o[0] = (__bf16)v0.x; o[1] = (__bf16)v0.y; o[2] = (__bf16)v0.z; o[3] = (__bf16)v0.w;
    o[4] = (__bf16)v1.x; o[5] = (__bf16)v1.y; o[6] = (__bf16)v1.z; o[7] = (__bf16)v1.w;
    *reinterpret_cast<bf16x8*>(&dst[e]) = o;
}

// -------- W[K][N] fp32 -> WT[N][K] bf16 (tiled transpose) --------------------
__global__ __launch_bounds__(256) void transpose_cvt(
    const float* __restrict__ W, __bf16* __restrict__ WT, int K, int N)
{
    __shared__ __bf16 t[32][33];
    const int n0 = blockIdx.x * 32, k0 = blockIdx.y * 32;
    const int tx = threadIdx.x & 31, ty = threadIdx.x >> 5;
    #pragma unroll
    for (int i = 0; i < 4; i++)
        t[ty * 4 + i][tx] = (__bf16)W[(size_t)(k0 + ty * 4 + i) * N + n0 + tx];
    __syncthreads();
    #pragma unroll
    for (int i = 0; i < 4; i++)
        WT[(size_t)(n0 + ty * 4 + i) * K + k0 + tx] = t[tx][ty * 4 + i];
}

// -------- W_xproj[DI][96] -> WT[128][DI] bf16, rows 96..127 zero -------------
__global__ __launch_bounds__(256) void xprojT_pad(
    const float* __restrict__ W, __bf16* __restrict__ WT)
{
    const int idx = blockIdx.x * 256 + threadIdx.x;
    const int k = idx & (DI - 1);
    const int n = idx >> 11;
    WT[(size_t)n * DI + k] = (n < XND) ? (__bf16)W[(size_t)k * XND + n] : (__bf16)0.f;
}

// -------- bf16 MFMA GEMM, 128x128 tile, BK=64, XOR-swizzled LDS --------------
// MODE 0: store f32 | 1: atomicAdd f32 | 2: softplus(acc+bias)->bf16 | 3: bf16
// Bt is [N][K] (B transposed). gridDim.z = split-K factor (kper % 64 == 0).
template<int MODE>
__global__ __launch_bounds__(256) void gemm_bf16(
    const __bf16* __restrict__ A, const __bf16* __restrict__ Bt,
    void* __restrict__ Cp, int M, int N, int K, int ldc,
    const float* __restrict__ bias)
{
    __shared__ __bf16 As[128 * 64];
    __shared__ __bf16 Bs[128 * 64];
    const int tid  = threadIdx.x;
    const int lane = tid & 63;
    const int wid  = tid >> 6;
    const int wr   = wid >> 1, wc = wid & 1;
    const int brow = blockIdx.y * 128, bcol = blockIdx.x * 128;
    const int kper = K / gridDim.z;
    const int kbeg = blockIdx.z * kper, kend = kbeg + kper;

    f32x4 acc[4][4] = {};

    for (int k0 = kbeg; k0 < kend; k0 += 64) {
        __syncthreads();
        #pragma unroll
        for (int p = 0; p < 4; p++) {
            const int i = p * 256 + tid;
            const int r = i >> 3;
            const int gc = ((i & 7) ^ (r & 7)) * 8;
            __builtin_amdgcn_global_load_lds(
                (const __attribute__((address_space(1))) void*)(A + (size_t)(brow + r) * K + k0 + gc),
                (__attribute__((address_space(3))) void*)(As + i * 8), 16, 0, 0);
            __builtin_amdgcn_global_load_lds(
                (const __attribute__((address_space(1))) void*)(Bt + (size_t)(bcol + r) * K + k0 + gc),
                (__attribute__((address_space(3))) void*)(Bs + i * 8), 16, 0, 0);
        }
        __syncthreads();
        bf16x8 a[2][4], b[2][4];
        const int rA = wr * 64 + (lane & 15);
        const int rB = wc * 64 + (lane & 15);
        const int cq = lane >> 4;
        const int rx = lane & 7;
        #pragma unroll
        for (int ks = 0; ks < 2; ks++) {
            const int sl = ((ks * 4 + cq) ^ rx) * 8;
            #pragma unroll
            for (int m = 0; m < 4; m++) {
                a[ks][m] = *reinterpret_cast<const bf16x8*>(&As[(rA + m * 16) * 64 + sl]);
                b[ks][m] = *reinterpret_cast<const bf16x8*>(&Bs[(rB + m * 16) * 64 + sl]);
            }
        }
        #pragma unroll
        for (int ks = 0; ks < 2; ks++)
            #pragma unroll
            for (int m = 0; m < 4; m++)
                #pragma unroll
                for (int n = 0; n < 4; n++)
                    acc[m][n] = __builtin_amdgcn_mfma_f32_16x16x32_bf16(
                        a[ks][m], b[ks][n], acc[m][n], 0, 0, 0);
    }
    const int crow = brow + wr * 64 + (lane >> 4) * 4;
    const int ccol = bcol + wc * 64 + (lane & 15);
    #pragma unroll
    for (int m = 0; m < 4; m++)
        #pragma unroll
        for (int n = 0; n < 4; n++) {
            const int col = ccol + n * 16;
            #pragma unroll
            for (int j = 0; j < 4; j++) {
                const size_t idx = (size_t)(crow + m * 16 + j) * ldc + col;
                if (MODE == 0) {
                    ((float*)Cp)[idx] = acc[m][n][j];
                } else if (MODE == 1) {
                    atomicAdd(&((float*)Cp)[idx], acc[m][n][j]);
                } else if (MODE == 2) {
                    const float v = acc[m][n][j] + bias[col];
                    ((__bf16*)Cp)[idx] =
                        (__bf16)(fmaxf(v, 0.f) + log1pf(__expf(-fabsf(v))));
                } else {
                    ((__bf16*)Cp)[idx] = (__bf16)acc[m][n][j];
                }
            }
        }
}

// -------- depthwise causal conv (k=4) + bias + SiLU (bf16 in/out) ------------
__global__ __launch_bounds__(256) void conv_silu(
    const __bf16* __restrict__ xzb, const float* __restrict__ conv_w,
    const float* __restrict__ conv_b, __bf16* __restrict__ xcb)
{
    const int g = blockIdx.x * 256 + threadIdx.x;
    const int d   = g & (DI - 1);
    const int tok = g >> 11;
    const int t   = tok & (SEQL - 1);
    const float4 w = *reinterpret_cast<const float4*>(&conv_w[d * 4]);
    const float wk[4] = { w.x, w.y, w.z, w.w };
    float acc = conv_b[d];
    #pragma unroll
    for (int k = 0; k < 4; k++) {
        const int tt = t + k - 3;
        if (tt >= 0)
            acc += (float)xzb[(size_t)(tok + k - 3) * (2 * DI) + d] * wk[k];
    }
    xcb[g] = (__bf16)(acc / (1.f + __expf(-acc)));
}

// -------- scan pass A: per-chunk local scan from h=0 -------------------------
// grid (DI/256, CK, NB); 256 thr = thread-per-channel; CL=16 steps.
__global__ __launch_bounds__(256) void scan_partial(
    const __bf16* __restrict__ xcb, const float* __restrict__ xdbl,
    const __bf16* __restrict__ dtb, const float* __restrict__ A_log,
    float* __restrict__ hfin, float* __restrict__ sdtb)
{
    __shared__ float Bsh[CL][16];
    const int tid = threadIdx.x;
    const int d = blockIdx.x * 256 + tid;
    const int c = blockIdx.y, b = blockIdx.z;
    const size_t base = (size_t)b * SEQL + c * CL;
    {
        const int st = tid >> 4, sg = tid & 15;   // 256 thr = 16x16
        Bsh[st][sg] = xdbl[(base + st) * XNP + DTR + sg];
    }
    float Av[16];
    #pragma unroll
    for (int i = 0; i < 4; i++) {
        const float4 v = *reinterpret_cast<const float4*>(&A_log[(size_t)d * 16 + i * 4]);
        Av[i*4+0] = -__expf(v.x); Av[i*4+1] = -__expf(v.y);
        Av[i*4+2] = -__expf(v.z); Av[i*4+3] = -__expf(v.w);
    }
    __syncthreads();
    float h[16] = {};
    float sdt = 0.f;
    #pragma unroll 8
    for (int t = 0; t < CL; t++) {
        const float dtv = (float)dtb[(base + t) * DI + d];
        const float xcv = (float)xcb[(base + t) * DI + d];
        sdt += dtv;
        const float dx = dtv * xcv;
        #pragma unroll
        for (int n = 0; n < 16; n++)
            h[n] = __expf(dtv * Av[n]) * h[n] + dx * Bsh[t][n];
    }
    const size_t ob = ((size_t)(b * CK + c) * DI + d) * 16;
    #pragma unroll
    for (int i = 0; i < 4; i++) {
        float4 v; v.x = h[i*4]; v.y = h[i*4+1]; v.z = h[i*4+2]; v.w = h[i*4+3];
        *reinterpret_cast<float4*>(&hfin[ob + i * 4]) = v;
    }
    sdtb[(size_t)(b * CK + c) * DI + d] = sdt;
}

// -------- scan pass B: sequential chunk combine; hfin -> entry states --------
__global__ __launch_bounds__(256) void scan_combine(
    const float* __restrict__ A_log, const float* __restrict__ sdtb,
    float* __restrict__ hfin)
{
    const int idx = blockIdx.x * 256 + threadIdx.x;
    const int n = idx & 15;
    const int d = (idx >> 4) & (DI - 1);
    const int b = idx >> 15;
    const float A = -__expf(A_log[(size_t)d * 16 + n]);
    float h = 0.f;
    for (int c = 0; c < CK; c++) {
        const size_t hb = ((size_t)(b * CK + c) * DI + d) * 16 + n;
        const float hl = hfin[hb];
        const float s  = sdtb[(size_t)(b * CK + c) * DI + d];
        hfin[hb] = h;
        h = __expf(A * s) * h + hl;
    }
}

// -------- scan pass C: seeded re-scan, emit y (D-skip + z-gate) as bf16 ------
__global__ __launch_bounds__(256) void scan_final(
    const __bf16* __restrict__ xzb, const __bf16* __restrict__ xcb,
    const float* __restrict__ xdbl, const __bf16* __restrict__ dtb,
    const float* __restrict__ A_log, const float* __restrict__ Dp,
    const float* __restrict__ hfin, __bf16* __restrict__ yb)
{
    __shared__ float Bsh[CL][16];
    __shared__ float Csh[CL][16];
    const int tid = threadIdx.x;
    const int d = blockIdx.x * 256 + tid;
    const int c = blockIdx.y, b = blockIdx.z;
    const size_t base = (size_t)b * SEQL + c * CL;
    {
        const int st = tid >> 4, sg = tid & 15;
        Bsh[st][sg] = xdbl[(base + st) * XNP + DTR + sg];
        Csh[st][sg] = xdbl[(base + st) * XNP + DTR + DS + sg];
    }
    float Av[16];
    #pragma unroll
    for (int i = 0; i < 4; i++) {
        const float4 v = *reinterpret_cast<const float4*>(&A_log[(size_t)d * 16 + i * 4]);
        Av[i*4+0] = -__expf(v.x); Av[i*4+1] = -__expf(v.y);
        Av[i*4+2] = -__expf(v.z); Av[i*4+3] = -__expf(v.w);
    }
    float h[16];
    const size_t ob = ((size_t)(b * CK + c) * DI + d) * 16;
    #pragma unroll
    for (int i = 0; i < 4; i++) {
        const float4 v = *reinterpret_cast<const float4*>(&hfin[ob + i * 4]);
        h[i*4] = v.x; h[i*4+1] = v.y; h[i*4+2] = v.z; h[i*4+3] = v.w;
    }
    const float Dv = Dp[d];
    __syncthreads();
    #pragma unroll 8
    for (int t = 0; t < CL; t++) {
        const size_t tok = base + t;
        const float dtv = (float)dtb[tok * DI + d];
        const float xcv = (float)xcb[tok * DI + d];
        const float zv  = (float)xzb[tok * (2 * DI) + DI + d];
        const float dx = dtv * xcv;
        float y = 0.f;
        #pragma unroll
        for (int n = 0; n < 16; n++) {
            h[n] = __expf(dtv * Av[n]) * h[n] + dx * Bsh[t][n];
            y += h[n] * Csh[t][n];
        }
        y += xcv * Dv;
        y *= zv / (1.f + __expf(-zv));
        yb[tok * DI + d] = (__bf16)y;
    }
}

// -------- out = x + LayerNorm(m) ---------------------------------------------
__global__ __launch_bounds__(256) void ln_add(
    const float* __restrict__ x, const float* __restrict__ m,
    const float* __restrict__ gamma, const float* __restrict__ beta,
    float* __restrict__ out)
{
    const int tok = blockIdx.x;
    const int tid = threadIdx.x;
    const int lane = tid & 63, wave = tid >> 6;
    __shared__ float red[4];
    __shared__ float stats[2];

    const float4 v = reinterpret_cast<const float4*>(&m[(size_t)tok * DM])[tid];
    float s = v.x + v.y + v.z + v.w;
    #pragma unroll
    for (int o = 32; o > 0; o >>= 1) s += __shfl_down(s, o, 64);
    if (lane == 0) red[wave] = s;
    __syncthreads();
    if (tid == 0) stats[0] = (red[0] + red[1] + red[2] + red[3]) * (1.f / DM);
    __syncthreads();
    const float mu = stats[0];
    const float dx = v.x - mu, dy = v.y - mu, dz = v.z - mu, dw = v.w - mu;
    float q = dx * dx + dy * dy + dz * dz + dw * dw;
    #pragma unroll
    for (int o = 32; o > 0; o >>= 1) q += __shfl_down(q, o, 64);
    if (lane == 0) red[wave] = q;
    __syncthreads();
    if (tid == 0)
        stats[1] = rsqrtf((red[0] + red[1] + red[2] + red[3]) * (1.f / DM) + 1e-6f);
    __syncthreads();
    const float rs = stats[1];

    const float4 g  = reinterpret_cast<const float4*>(gamma)[tid];
    const float4 bb = reinterpret_cast<const float4*>(beta)[tid];
    const float4 xv = reinterpret_cast<const float4*>(&x[(size_t)tok * DM])[tid];
    float4 o;
    o.x = xv.x + dx * rs * g.x + bb.x;
    o.y = xv.y + dy * rs * g.y + bb.y;
    o.z = xv.z + dz * rs * g.z + bb.z;
    o.w = xv.w + dw * rs * g.w + bb.w;
    reinterpret_cast<float4*>(&out[(size_t)tok * DM])[tid] = o;
}

extern "C" void kernel_launch(void* const* d_in, const int* in_sizes, int n_in,
                              void* d_out, int out_size, void* d_ws, size_t ws_size,
                              hipStream_t stream)
{
    const float* x      = (const float*)d_in[0];
    const float* W_in   = (const float*)d_in[1];
    const float* conv_w = (const float*)d_in[2];
    const float* conv_b = (const float*)d_in[3];
    const float* W_xprj = (const float*)d_in[4];
    const float* W_dt   = (const float*)d_in[5];
    const float* b_dt   = (const float*)d_in[6];
    const float* A_log  = (const float*)d_in[7];
    const float* D_par  = (const float*)d_in[8];
    const float* W_out  = (const float*)d_in[9];
    const float* gamma  = (const float*)d_in[10];
    const float* beta   = (const float*)d_in[11];
    float* out = (float*)d_out;

    // workspace layout (byte offsets); aliases safe by stream ordering
    char* w = (char*)d_ws;
    __bf16* xzb    = (__bf16*)(w + 0);          // 16 MB [NTOK][4096] (xi|z)
    __bf16* xcb    = (__bf16*)(w + 16777216);   //  8 MB [NTOK][DI]
    float*  xdbl   = (float*) (w + 25165824);   //  1 MB [NTOK][128]
    __bf16* rb     = (__bf16*)(w + 26214400);   // .25MB [NTOK][64]
    __bf16* dtb    = (__bf16*)(w + 26476544);   //  8 MB [NTOK][DI]
    float*  mbuf   = (float*) (w + 34865152);   //  8 MB [NTOK][DM]
    float*  hfin   = (float*) (w + 43253760);   // 16.8MB [NB*CK][DI][16]
    float*  sdtb   = (float*) (w + 60030976);   //  1 MB [NB*CK][DI]
    __bf16* xb     = (__bf16*)(w + 61079552);   //  4 MB (alias W_outT)
    __bf16* W_outT = (__bf16*)(w + 61079552);   //  4 MB [DM][DI]
    __bf16* W_inT  = (__bf16*)(w + 65273856);   //  8 MB [4096][DM] (alias yb)
    __bf16* yb     = (__bf16*)(w + 65273856);   //  8 MB [NTOK][DI]
    __bf16* W_xprT = (__bf16*)(w + 73662464);   // .5MB [128][DI]
    __bf16* WdtT   = (__bf16*)(w + 74186752);   // .25MB [DI][64]

    // --- weight/input prep ---
    cvt_bf16<<<NTOK * DM / 8 / 256, 256, 0, stream>>>(x, xb, 10, DM, NTOK * DM / 8);
    transpose_cvt<<<dim3(2 * DI / 32, DM / 32), 256, 0, stream>>>(W_in, W_inT, DM, 2 * DI);
    xprojT_pad<<<XNP * DI / 256, 256, 0, stream>>>(W_xprj, W_xprT);
    transpose_cvt<<<dim3(DI / 32, DTR / 32), 256, 0, stream>>>(W_dt, WdtT, DTR, DI);

    // 1. xz = x @ W_in  (M=2048, N=4096, K=1024) -> bf16
    gemm_bf16<3><<<dim3(32, 16, 1), 256, 0, stream>>>(
        xb, W_inT, xzb, NTOK, 2 * DI, DM, 2 * DI, nullptr);
    // W_out transpose (aliases xb; must follow in-proj)
    transpose_cvt<<<dim3(DM / 32, DI / 32), 256, 0, stream>>>(W_out, W_outT, DI, DM);

    // 2. conv + silu -> bf16
    conv_silu<<<(NTOK * DI) / 256, 256, 0, stream>>>(xzb, conv_w, conv_b, xcb);

    // 3. x_dbl = xc @ W_xproj  (N=128 pad, K=2048), split-K=16, atomic f32
    hipMemsetAsync(xdbl, 0, (size_t)NTOK * XNP * 4, stream);
    gemm_bf16<1><<<dim3(1, 16, 16), 256, 0, stream>>>(
        xcb, W_xprT, xdbl, NTOK, XNP, DI, XNP, nullptr);

    // 4. dt = softplus(dt_r @ W_dt + b_dt) -> bf16  (K=64)
    cvt_bf16<<<NTOK * DTR / 8 / 256, 256, 0, stream>>>(xdbl, rb, 6, XNP, NTOK * DTR / 8);
    gemm_bf16<2><<<dim3(16, 16, 1), 256, 0, stream>>>(
        rb, WdtT, dtb, NTOK, DI, DTR, DI, b_dt);

    // 5. chunked selective scan (CK=64 chunks of CL=16 -> 1024 blocks/pass)
    scan_partial<<<dim3(DI / 256, CK, NB), 256, 0, stream>>>(
        xcb, xdbl, dtb, A_log, hfin, sdtb);
    scan_combine<<<NB * DI * DS / 256, 256, 0, stream>>>(A_log, sdtb, hfin);
    scan_final<<<dim3(DI / 256, CK, NB), 256, 0, stream>>>(
        xzb, xcb, xdbl, dtb, A_log, D_par, hfin, yb);

    // 6. m = y @ W_out  (M=2048, N=1024, K=2048), split-K=4, atomic f32
    hipMemsetAsync(mbuf, 0, (size_t)NTOK * DM * 4, stream);
    gemm_bf16<1><<<dim3(8, 16, 4), 256, 0, stream>>>(
        yb, W_outT, mbuf, NTOK, DM, DI, DM, nullptr);

    // 7. out = x + LN(m)
    ln_add<<<NTOK, 256, 0, stream>>>(x, mbuf, gamma, beta, out);
}

// Round 7
// 197.235 us; speedup vs baseline: 6.6991x; 1.0630x over previous
//
#include <hip/hip_runtime.h>
#include <math.h>

#define DM   1024
#define DI   2048
#define DS   16
#define DTR  64
#define NB   2
#define SEQL 1024
#define NTOK (NB*SEQL)
#define XND  96   /* DTR + 2*DS */
#define XNP  128  /* padded xproj width */
#define CK   64   /* scan chunks */
#define CL   16   /* chunk length */

typedef __bf16 bf16x8 __attribute__((ext_vector_type(8)));
typedef float  f32x4  __attribute__((ext_vector_type(4)));

// ------------- fused prep: zeroing + conversions + transposes ----------------
#define PREP_BLOCKS 10624

__device__ inline void trans_tile(const float* __restrict__ W,
                                  __bf16* __restrict__ WT, int K, int N,
                                  int n0, int k0, int tid, __bf16 (*t)[33])
{
    const int tx = tid & 31, ty = tid >> 5;
    #pragma unroll
    for (int i = 0; i < 4; i++)
        t[ty * 4 + i][tx] = (__bf16)W[(size_t)(k0 + ty * 4 + i) * N + n0 + tx];
    __syncthreads();
    #pragma unroll
    for (int i = 0; i < 4; i++)
        WT[(size_t)(n0 + ty * 4 + i) * K + k0 + tx] = t[tx][ty * 4 + i];
}

__global__ __launch_bounds__(256) void prep(
    const float* __restrict__ x, const float* __restrict__ W_in,
    const float* __restrict__ W_out, const float* __restrict__ W_dt,
    const float* __restrict__ W_xprj,
    __bf16* __restrict__ xb, __bf16* __restrict__ W_inT,
    __bf16* __restrict__ W_outT, __bf16* __restrict__ WdtT,
    __bf16* __restrict__ W_xprT, float* __restrict__ xdbl,
    float* __restrict__ mbuf)
{
    __shared__ __bf16 t[32][33];
    int bid = blockIdx.x;
    const int tid = threadIdx.x;

    if (bid < 2304) {                       // R0: zero xdbl + mbuf
        const int i = bid * 1024 + tid * 4;
        const float4 z = {0.f, 0.f, 0.f, 0.f};
        if (i < 262144) *reinterpret_cast<float4*>(&xdbl[i]) = z;
        else            *reinterpret_cast<float4*>(&mbuf[i - 262144]) = z;
        return;
    }
    bid -= 2304;
    if (bid < 1024) {                       // R1: cvt x -> xb
        const int e = (bid * 256 + tid) * 8;
        const float4 v0 = *reinterpret_cast<const float4*>(&x[e]);
        const float4 v1 = *reinterpret_cast<const float4*>(&x[e + 4]);
        bf16x8 o;
        o[0] = (__bf16)v0.x; o[1] = (__bf16)v0.y; o[2] = (__bf16)v0.z; o[3] = (__bf16)v0.w;
        o[4] = (__bf16)v1.x; o[5] = (__bf16)v1.y; o[6] = (__bf16)v1.z; o[7] = (__bf16)v1.w;
        *reinterpret_cast<bf16x8*>(&xb[e]) = o;
        return;
    }
    bid -= 1024;
    if (bid < 4096) {                       // R2: W_in [1024][4096] -> T
        trans_tile(W_in, W_inT, DM, 2 * DI, (bid & 127) * 32, (bid >> 7) * 32, tid, t);
        return;
    }
    bid -= 4096;
    if (bid < 2048) {                       // R3: W_out [2048][1024] -> T
        trans_tile(W_out, W_outT, DI, DM, (bid & 31) * 32, (bid >> 5) * 32, tid, t);
        return;
    }
    bid -= 2048;
    if (bid < 128) {                        // R4: W_dt [64][2048] -> T
        trans_tile(W_dt, WdtT, DTR, DI, (bid & 63) * 32, (bid >> 6) * 32, tid, t);
        return;
    }
    bid -= 128;
    {                                       // R5: xproj transpose+pad
        const int idx = bid * 256 + tid;
        const int k = idx & (DI - 1);
        const int n = idx >> 11;
        W_xprT[(size_t)n * DI + k] = (n < XND) ? (__bf16)W_xprj[(size_t)k * XND + n]
                                               : (__bf16)0.f;
    }
}

// -------- bf16 MFMA GEMM, 128x128 tile, BK=64, XOR-swizzled LDS --------------
// MODE 0: store f32 | 1: atomicAdd f32 | 2: A = f32[.][128] cols 0..63 reg-
// staged+cvt, epilogue softplus(acc+bias)->bf16 | 3: store bf16
template<int MODE>
__global__ __launch_bounds__(256) void gemm_bf16(
    const __bf16* __restrict__ A, const __bf16* __restrict__ Bt,
    void* __restrict__ Cp, int M, int N, int K, int ldc,
    const float* __restrict__ bias)
{
    __shared__ __bf16 As[128 * 64];
    __shared__ __bf16 Bs[128 * 64];
    const int tid  = threadIdx.x;
    const int lane = tid & 63;
    const int wid  = tid >> 6;
    const int wr   = wid >> 1, wc = wid & 1;
    const int brow = blockIdx.y * 128, bcol = blockIdx.x * 128;
    const int kper = K / gridDim.z;
    const int kbeg = blockIdx.z * kper, kend = kbeg + kper;

    f32x4 acc[4][4] = {};

    for (int k0 = kbeg; k0 < kend; k0 += 64) {
        __syncthreads();
        if (MODE == 2) {
            const float* Af = reinterpret_cast<const float*>(A);
            #pragma unroll
            for (int p = 0; p < 4; p++) {
                const int i = p * 256 + tid;
                const int r = i >> 3;
                const int j = i & 7;
                const float4 v0 = *reinterpret_cast<const float4*>(
                    &Af[(size_t)(brow + r) * XNP + j * 8]);
                const float4 v1 = *reinterpret_cast<const float4*>(
                    &Af[(size_t)(brow + r) * XNP + j * 8 + 4]);
                bf16x8 o;
                o[0] = (__bf16)v0.x; o[1] = (__bf16)v0.y; o[2] = (__bf16)v0.z; o[3] = (__bf16)v0.w;
                o[4] = (__bf16)v1.x; o[5] = (__bf16)v1.y; o[6] = (__bf16)v1.z; o[7] = (__bf16)v1.w;
                *reinterpret_cast<bf16x8*>(&As[r * 64 + ((j ^ (r & 7))) * 8]) = o;
            }
        } else {
            #pragma unroll
            for (int p = 0; p < 4; p++) {
                const int i = p * 256 + tid;
                const int r = i >> 3;
                const int gc = ((i & 7) ^ (r & 7)) * 8;
                __builtin_amdgcn_global_load_lds(
                    (const __attribute__((address_space(1))) void*)(A + (size_t)(brow + r) * K + k0 + gc),
                    (__attribute__((address_space(3))) void*)(As + i * 8), 16, 0, 0);
            }
        }
        #pragma unroll
        for (int p = 0; p < 4; p++) {
            const int i = p * 256 + tid;
            const int r = i >> 3;
            const int gc = ((i & 7) ^ (r & 7)) * 8;
            __builtin_amdgcn_global_load_lds(
                (const __attribute__((address_space(1))) void*)(Bt + (size_t)(bcol + r) * K + k0 + gc),
                (__attribute__((address_space(3))) void*)(Bs + i * 8), 16, 0, 0);
        }
        __syncthreads();
        bf16x8 a[2][4], b[2][4];
        const int rA = wr * 64 + (lane & 15);
        const int rB = wc * 64 + (lane & 15);
        const int cq = lane >> 4;
        const int rx = lane & 7;
        #pragma unroll
        for (int ks = 0; ks < 2; ks++) {
            const int sl = ((ks * 4 + cq) ^ rx) * 8;
            #pragma unroll
            for (int m = 0; m < 4; m++) {
                a[ks][m] = *reinterpret_cast<const bf16x8*>(&As[(rA + m * 16) * 64 + sl]);
                b[ks][m] = *reinterpret_cast<const bf16x8*>(&Bs[(rB + m * 16) * 64 + sl]);
            }
        }
        #pragma unroll
        for (int ks = 0; ks < 2; ks++)
            #pragma unroll
            for (int m = 0; m < 4; m++)
                #pragma unroll
                for (int n = 0; n < 4; n++)
                    acc[m][n] = __builtin_amdgcn_mfma_f32_16x16x32_bf16(
                        a[ks][m], b[ks][n], acc[m][n], 0, 0, 0);
    }
    const int crow = brow + wr * 64 + (lane >> 4) * 4;
    const int ccol = bcol + wc * 64 + (lane & 15);
    #pragma unroll
    for (int m = 0; m < 4; m++)
        #pragma unroll
        for (int n = 0; n < 4; n++) {
            const int col = ccol + n * 16;
            #pragma unroll
            for (int j = 0; j < 4; j++) {
                const size_t idx = (size_t)(crow + m * 16 + j) * ldc + col;
                if (MODE == 0) {
                    ((float*)Cp)[idx] = acc[m][n][j];
                } else if (MODE == 1) {
                    atomicAdd(&((float*)Cp)[idx], acc[m][n][j]);
                } else if (MODE == 2) {
                    const float v = acc[m][n][j] + bias[col];
                    ((__bf16*)Cp)[idx] =
                        (__bf16)(fmaxf(v, 0.f) + log1pf(__expf(-fabsf(v))));
                } else {
                    ((__bf16*)Cp)[idx] = (__bf16)acc[m][n][j];
                }
            }
        }
}

// -------- depthwise causal conv (k=4) + bias + SiLU, 8 ch/thread -------------
__global__ __launch_bounds__(256) void conv_silu(
    const __bf16* __restrict__ xzb, const float* __restrict__ conv_w,
    const float* __restrict__ conv_b, __bf16* __restrict__ xcb)
{
    const int g  = blockIdx.x * 256 + threadIdx.x;
    const int d0 = (g & 255) * 8;
    const int tok = g >> 8;
    const int t   = tok & (SEQL - 1);

    float4 wv[8];
    #pragma unroll
    for (int j = 0; j < 8; j++)
        wv[j] = *reinterpret_cast<const float4*>(&conv_w[(d0 + j) * 4]);
    float acc[8];
    {
        const float4 b0 = *reinterpret_cast<const float4*>(&conv_b[d0]);
        const float4 b1 = *reinterpret_cast<const float4*>(&conv_b[d0 + 4]);
        acc[0] = b0.x; acc[1] = b0.y; acc[2] = b0.z; acc[3] = b0.w;
        acc[4] = b1.x; acc[5] = b1.y; acc[6] = b1.z; acc[7] = b1.w;
    }
    #pragma unroll
    for (int k = 0; k < 4; k++) {
        const int tt = t + k - 3;
        if (tt >= 0) {
            const bf16x8 v = *reinterpret_cast<const bf16x8*>(
                &xzb[(size_t)(tok + k - 3) * (2 * DI) + d0]);
            #pragma unroll
            for (int j = 0; j < 8; j++) {
                const float wk = (k == 0) ? wv[j].x : (k == 1) ? wv[j].y
                               : (k == 2) ? wv[j].z : wv[j].w;
                acc[j] += (float)v[j] * wk;
            }
        }
    }
    bf16x8 o;
    #pragma unroll
    for (int j = 0; j < 8; j++) {
        const float a = acc[j];
        o[j] = (__bf16)(a / (1.f + __expf(-a)));
    }
    *reinterpret_cast<bf16x8*>(&xcb[(size_t)g * 8]) = o;
}

// -------- scan pass A --------------------------------------------------------
__global__ __launch_bounds__(256) void scan_partial(
    const __bf16* __restrict__ xcb, const float* __restrict__ xdbl,
    const __bf16* __restrict__ dtb, const float* __restrict__ A_log,
    float* __restrict__ hfin, float* __restrict__ sdtb)
{
    __shared__ float Bsh[CL][16];
    const int tid = threadIdx.x;
    const int d = blockIdx.x * 256 + tid;
    const int c = blockIdx.y, b = blockIdx.z;
    const size_t base = (size_t)b * SEQL + c * CL;
    {
        const int st = tid >> 4, sg = tid & 15;
        Bsh[st][sg] = xdbl[(base + st) * XNP + DTR + sg];
    }
    float Av[16];
    #pragma unroll
    for (int i = 0; i < 4; i++) {
        const float4 v = *reinterpret_cast<const float4*>(&A_log[(size_t)d * 16 + i * 4]);
        Av[i*4+0] = -__expf(v.x); Av[i*4+1] = -__expf(v.y);
        Av[i*4+2] = -__expf(v.z); Av[i*4+3] = -__expf(v.w);
    }
    __syncthreads();
    float h[16] = {};
    float sdt = 0.f;
    #pragma unroll 8
    for (int t = 0; t < CL; t++) {
        const float dtv = (float)dtb[(base + t) * DI + d];
        const float xcv = (float)xcb[(base + t) * DI + d];
        sdt += dtv;
        const float dx = dtv * xcv;
        #pragma unroll
        for (int n = 0; n < 16; n++)
            h[n] = __expf(dtv * Av[n]) * h[n] + dx * Bsh[t][n];
    }
    const size_t ob = ((size_t)(b * CK + c) * DI + d) * 16;
    #pragma unroll
    for (int i = 0; i < 4; i++) {
        float4 v; v.x = h[i*4]; v.y = h[i*4+1]; v.z = h[i*4+2]; v.w = h[i*4+3];
        *reinterpret_cast<float4*>(&hfin[ob + i * 4]) = v;
    }
    sdtb[(size_t)(b * CK + c) * DI + d] = sdt;
}

// -------- scan pass B --------------------------------------------------------
__global__ __launch_bounds__(256) void scan_combine(
    const float* __restrict__ A_log, const float* __restrict__ sdtb,
    float* __restrict__ hfin)
{
    const int idx = blockIdx.x * 256 + threadIdx.x;
    const int n = idx & 15;
    const int d = (idx >> 4) & (DI - 1);
    const int b = idx >> 15;
    const float A = -__expf(A_log[(size_t)d * 16 + n]);
    float h = 0.f;
    for (int c = 0; c < CK; c++) {
        const size_t hb = ((size_t)(b * CK + c) * DI + d) * 16 + n;
        const float hl = hfin[hb];
        const float s  = sdtb[(size_t)(b * CK + c) * DI + d];
        hfin[hb] = h;
        h = __expf(A * s) * h + hl;
    }
}

// -------- scan pass C --------------------------------------------------------
__global__ __launch_bounds__(256) void scan_final(
    const __bf16* __restrict__ xzb, const __bf16* __restrict__ xcb,
    const float* __restrict__ xdbl, const __bf16* __restrict__ dtb,
    const float* __restrict__ A_log, const float* __restrict__ Dp,
    const float* __restrict__ hfin, __bf16* __restrict__ yb)
{
    __shared__ float Bsh[CL][16];
    __shared__ float Csh[CL][16];
    const int tid = threadIdx.x;
    const int d = blockIdx.x * 256 + tid;
    const int c = blockIdx.y, b = blockIdx.z;
    const size_t base = (size_t)b * SEQL + c * CL;
    {
        const int st = tid >> 4, sg = tid & 15;
        Bsh[st][sg] = xdbl[(base + st) * XNP + DTR + sg];
        Csh[st][sg] = xdbl[(base + st) * XNP + DTR + DS + sg];
    }
    float Av[16];
    #pragma unroll
    for (int i = 0; i < 4; i++) {
        const float4 v = *reinterpret_cast<const float4*>(&A_log[(size_t)d * 16 + i * 4]);
        Av[i*4+0] = -__expf(v.x); Av[i*4+1] = -__expf(v.y);
        Av[i*4+2] = -__expf(v.z); Av[i*4+3] = -__expf(v.w);
    }
    float h[16];
    const size_t ob = ((size_t)(b * CK + c) * DI + d) * 16;
    #pragma unroll
    for (int i = 0; i < 4; i++) {
        const float4 v = *reinterpret_cast<const float4*>(&hfin[ob + i * 4]);
        h[i*4] = v.x; h[i*4+1] = v.y; h[i*4+2] = v.z; h[i*4+3] = v.w;
    }
    const float Dv = Dp[d];
    __syncthreads();
    #pragma unroll 8
    for (int t = 0; t < CL; t++) {
        const size_t tok = base + t;
        const float dtv = (float)dtb[tok * DI + d];
        const float xcv = (float)xcb[tok * DI + d];
        const float zv  = (float)xzb[tok * (2 * DI) + DI + d];
        const float dx = dtv * xcv;
        float y = 0.f;
        #pragma unroll
        for (int n = 0; n < 16; n++) {
            h[n] = __expf(dtv * Av[n]) * h[n] + dx * Bsh[t][n];
            y += h[n] * Csh[t][n];
        }
        y += xcv * Dv;
        y *= zv / (1.f + __expf(-zv));
        yb[tok * DI + d] = (__bf16)y;
    }
}

// -------- out = x + LayerNorm(m) ---------------------------------------------
__global__ __launch_bounds__(256) void ln_add(
    const float* __restrict__ x, const float* __restrict__ m,
    const float* __restrict__ gamma, const float* __restrict__ beta,
    float* __restrict__ out)
{
    const int tok = blockIdx.x;
    const int tid = threadIdx.x;
    const int lane = tid & 63, wave = tid >> 6;
    __shared__ float red[4];
    __shared__ float stats[2];

    const float4 v = reinterpret_cast<const float4*>(&m[(size_t)tok * DM])[tid];
    float s = v.x + v.y + v.z + v.w;
    #pragma unroll
    for (int o = 32; o > 0; o >>= 1) s += __shfl_down(s, o, 64);
    if (lane == 0) red[wave] = s;
    __syncthreads();
    if (tid == 0) stats[0] = (red[0] + red[1] + red[2] + red[3]) * (1.f / DM);
    __syncthreads();
    const float mu = stats[0];
    const float dx = v.x - mu, dy = v.y - mu, dz = v.z - mu, dw = v.w - mu;
    float q = dx * dx + dy * dy + dz * dz + dw * dw;
    #pragma unroll
    for (int o = 32; o > 0; o >>= 1) q += __shfl_down(q, o, 64);
    if (lane == 0) red[wave] = q;
    __syncthreads();
    if (tid == 0)
        stats[1] = rsqrtf((red[0] + red[1] + red[2] + red[3]) * (1.f / DM) + 1e-6f);
    __syncthreads();
    const float rs = stats[1];

    const float4 g  = reinterpret_cast<const float4*>(gamma)[tid];
    const float4 bb = reinterpret_cast<const float4*>(beta)[tid];
    const float4 xv = reinterpret_cast<const float4*>(&x[(size_t)tok * DM])[tid];
    float4 o;
    o.x = xv.x + dx * rs * g.x + bb.x;
    o.y = xv.y + dy * rs * g.y + bb.y;
    o.z = xv.z + dz * rs * g.z + bb.z;
    o.w = xv.w + dw * rs * g.w + bb.w;
    reinterpret_cast<float4*>(&out[(size_t)tok * DM])[tid] = o;
}

extern "C" void kernel_launch(void* const* d_in, const int* in_sizes, int n_in,
                              void* d_out, int out_size, void* d_ws, size_t ws_size,
                              hipStream_t stream)
{
    const float* x      = (const float*)d_in[0];
    const float* W_in   = (const float*)d_in[1];
    const float* conv_w = (const float*)d_in[2];
    const float* conv_b = (const float*)d_in[3];
    const float* W_xprj = (const float*)d_in[4];
    const float* W_dt   = (const float*)d_in[5];
    const float* b_dt   = (const float*)d_in[6];
    const float* A_log  = (const float*)d_in[7];
    const float* D_par  = (const float*)d_in[8];
    const float* W_out  = (const float*)d_in[9];
    const float* gamma  = (const float*)d_in[10];
    const float* beta   = (const float*)d_in[11];
    float* out = (float*)d_out;

    // workspace layout (byte offsets, non-aliasing, ~83 MB total)
    char* w = (char*)d_ws;
    __bf16* xzb    = (__bf16*)(w + 0);          // 16 MB [NTOK][4096] (xi|z)
    __bf16* xcb    = (__bf16*)(w + 16777216);   //  8 MB [NTOK][DI]
    float*  xdbl   = (float*) (w + 25165824);   //  1 MB [NTOK][128]
    __bf16* dtb    = (__bf16*)(w + 26214400);   //  8 MB [NTOK][DI]
    float*  mbuf   = (float*) (w + 34603008);   //  8 MB [NTOK][DM]
    float*  hfin   = (float*) (w + 42991616);   // 16 MB [NB*CK][DI][16]
    float*  sdtb   = (float*) (w + 59768832);   //  1 MB [NB*CK][DI]
    __bf16* xb     = (__bf16*)(w + 60817408);   //  4 MB [NTOK][DM]
    __bf16* W_inT  = (__bf16*)(w + 65011712);   //  8 MB [4096][DM]
    __bf16* W_outT = (__bf16*)(w + 73400320);   //  4 MB [DM][DI]
    __bf16* W_xprT = (__bf16*)(w + 77594624);   // .5 MB [128][DI]
    __bf16* WdtT   = (__bf16*)(w + 78118912);   // .25MB [DI][64]
    __bf16* yb     = (__bf16*)(w + 78381056);   //  8 MB [NTOK][DI]

    // 0. fused prep (zeroing + cvt + transposes)
    prep<<<PREP_BLOCKS, 256, 0, stream>>>(
        x, W_in, W_out, W_dt, W_xprj, xb, W_inT, W_outT, WdtT, W_xprT, xdbl, mbuf);

    // 1. xz = x @ W_in  (M=2048, N=4096, K=1024) -> bf16
    gemm_bf16<3><<<dim3(32, 16, 1), 256, 0, stream>>>(
        xb, W_inT, xzb, NTOK, 2 * DI, DM, 2 * DI, nullptr);

    // 2. conv + silu -> bf16
    conv_silu<<<(NTOK * DI / 8) / 256, 256, 0, stream>>>(xzb, conv_w, conv_b, xcb);

    // 3. x_dbl = xc @ W_xproj  (N=128 pad, K=2048), split-K=16, atomic f32
    gemm_bf16<1><<<dim3(1, 16, 16), 256, 0, stream>>>(
        xcb, W_xprT, xdbl, NTOK, XNP, DI, XNP, nullptr);

    // 4. dt = softplus(dt_r @ W_dt + b_dt) -> bf16 (A reg-staged from f32 xdbl)
    gemm_bf16<2><<<dim3(16, 16, 1), 256, 0, stream>>>(
        (const __bf16*)xdbl, WdtT, dtb, NTOK, DI, DTR, DI, b_dt);

    // 5. chunked selective scan (CK=64 chunks of CL=16)
    scan_partial<<<dim3(DI / 256, CK, NB), 256, 0, stream>>>(
        xcb, xdbl, dtb, A_log, hfin, sdtb);
    scan_combine<<<NB * DI * DS / 256, 256, 0, stream>>>(A_log, sdtb, hfin);
    scan_final<<<dim3(DI / 256, CK, NB), 256, 0, stream>>>(
        xzb, xcb, xdbl, dtb, A_log, D_par, hfin, yb);

    // 6. m = y @ W_out  (M=2048, N=1024, K=2048), split-K=4, atomic f32
    gemm_bf16<1><<<dim3(8, 16, 4), 256, 0, stream>>>(
        yb, W_outT, mbuf, NTOK, DM, DI, DM, nullptr);

    // 7. out = x + LN(m)
    ln_add<<<NTOK, 256, 0, stream>>>(x, mbuf, gamma, beta, out);
}

// Round 8
// 185.172 us; speedup vs baseline: 7.1355x; 1.0651x over previous
//
#include <hip/hip_runtime.h>
#include <math.h>

#define DM   1024
#define DI   2048
#define DS   16
#define DTR  64
#define NB   2
#define SEQL 1024
#define NTOK (NB*SEQL)
#define XND  96   /* DTR + 2*DS */
#define XNP  128  /* padded xproj width */
#define CK   64   /* scan chunks */
#define CL   16   /* chunk length */

typedef __bf16 bf16x8 __attribute__((ext_vector_type(8)));
typedef float  f32x4  __attribute__((ext_vector_type(4)));

// ------------- fused prep: zeroing + conversions + transposes ----------------
#define PREP_BLOCKS 10624

__device__ inline void trans_tile(const float* __restrict__ W,
                                  __bf16* __restrict__ WT, int K, int N,
                                  int n0, int k0, int tid, __bf16 (*t)[33])
{
    const int tx = tid & 31, ty = tid >> 5;
    #pragma unroll
    for (int i = 0; i < 4; i++)
        t[ty * 4 + i][tx] = (__bf16)W[(size_t)(k0 + ty * 4 + i) * N + n0 + tx];
    __syncthreads();
    #pragma unroll
    for (int i = 0; i < 4; i++)
        WT[(size_t)(n0 + ty * 4 + i) * K + k0 + tx] = t[tx][ty * 4 + i];
}

__global__ __launch_bounds__(256) void prep(
    const float* __restrict__ x, const float* __restrict__ W_in,
    const float* __restrict__ W_out, const float* __restrict__ W_dt,
    const float* __restrict__ W_xprj,
    __bf16* __restrict__ xb, __bf16* __restrict__ W_inT,
    __bf16* __restrict__ W_outT, __bf16* __restrict__ WdtT,
    __bf16* __restrict__ W_xprT, float* __restrict__ xdbl,
    float* __restrict__ mbuf)
{
    __shared__ __bf16 t[32][33];
    int bid = blockIdx.x;
    const int tid = threadIdx.x;

    if (bid < 2304) {                       // R0: zero xdbl + mbuf
        const int i = bid * 1024 + tid * 4;
        const float4 z = {0.f, 0.f, 0.f, 0.f};
        if (i < 262144) *reinterpret_cast<float4*>(&xdbl[i]) = z;
        else            *reinterpret_cast<float4*>(&mbuf[i - 262144]) = z;
        return;
    }
    bid -= 2304;
    if (bid < 1024) {                       // R1: cvt x -> xb
        const int e = (bid * 256 + tid) * 8;
        const float4 v0 = *reinterpret_cast<const float4*>(&x[e]);
        const float4 v1 = *reinterpret_cast<const float4*>(&x[e + 4]);
        bf16x8 o;
        o[0] = (__bf16)v0.x; o[1] = (__bf16)v0.y; o[2] = (__bf16)v0.z; o[3] = (__bf16)v0.w;
        o[4] = (__bf16)v1.x; o[5] = (__bf16)v1.y; o[6] = (__bf16)v1.z; o[7] = (__bf16)v1.w;
        *reinterpret_cast<bf16x8*>(&xb[e]) = o;
        return;
    }
    bid -= 1024;
    if (bid < 4096) {                       // R2: W_in [1024][4096] -> T
        trans_tile(W_in, W_inT, DM, 2 * DI, (bid & 127) * 32, (bid >> 7) * 32, tid, t);
        return;
    }
    bid -= 4096;
    if (bid < 2048) {                       // R3: W_out [2048][1024] -> T
        trans_tile(W_out, W_outT, DI, DM, (bid & 31) * 32, (bid >> 5) * 32, tid, t);
        return;
    }
    bid -= 2048;
    if (bid < 128) {                        // R4: W_dt [64][2048] -> T
        trans_tile(W_dt, WdtT, DTR, DI, (bid & 63) * 32, (bid >> 6) * 32, tid, t);
        return;
    }
    bid -= 128;
    {                                       // R5: xproj transpose+pad
        const int idx = bid * 256 + tid;
        const int k = idx & (DI - 1);
        const int n = idx >> 11;
        W_xprT[(size_t)n * DI + k] = (n < XND) ? (__bf16)W_xprj[(size_t)k * XND + n]
                                               : (__bf16)0.f;
    }
}

// -------- bf16 MFMA GEMM, 128x128 tile, BK=64, XOR-swizzled LDS --------------
// MODE 0: store f32 | 1: atomicAdd f32 | 2: A = f32[.][128] cols 0..63 reg-
// staged+cvt, epilogue softplus(acc+bias)->bf16 | 3: store bf16
template<int MODE>
__global__ __launch_bounds__(256) void gemm_bf16(
    const __bf16* __restrict__ A, const __bf16* __restrict__ Bt,
    void* __restrict__ Cp, int M, int N, int K, int ldc,
    const float* __restrict__ bias)
{
    __shared__ __bf16 As[128 * 64];
    __shared__ __bf16 Bs[128 * 64];
    const int tid  = threadIdx.x;
    const int lane = tid & 63;
    const int wid  = tid >> 6;
    const int wr   = wid >> 1, wc = wid & 1;
    const int brow = blockIdx.y * 128, bcol = blockIdx.x * 128;
    const int kper = K / gridDim.z;
    const int kbeg = blockIdx.z * kper, kend = kbeg + kper;

    f32x4 acc[4][4] = {};

    for (int k0 = kbeg; k0 < kend; k0 += 64) {
        __syncthreads();
        if (MODE == 2) {
            const float* Af = reinterpret_cast<const float*>(A);
            #pragma unroll
            for (int p = 0; p < 4; p++) {
                const int i = p * 256 + tid;
                const int r = i >> 3;
                const int j = i & 7;
                const float4 v0 = *reinterpret_cast<const float4*>(
                    &Af[(size_t)(brow + r) * XNP + j * 8]);
                const float4 v1 = *reinterpret_cast<const float4*>(
                    &Af[(size_t)(brow + r) * XNP + j * 8 + 4]);
                bf16x8 o;
                o[0] = (__bf16)v0.x; o[1] = (__bf16)v0.y; o[2] = (__bf16)v0.z; o[3] = (__bf16)v0.w;
                o[4] = (__bf16)v1.x; o[5] = (__bf16)v1.y; o[6] = (__bf16)v1.z; o[7] = (__bf16)v1.w;
                *reinterpret_cast<bf16x8*>(&As[r * 64 + ((j ^ (r & 7))) * 8]) = o;
            }
        } else {
            #pragma unroll
            for (int p = 0; p < 4; p++) {
                const int i = p * 256 + tid;
                const int r = i >> 3;
                const int gc = ((i & 7) ^ (r & 7)) * 8;
                __builtin_amdgcn_global_load_lds(
                    (const __attribute__((address_space(1))) void*)(A + (size_t)(brow + r) * K + k0 + gc),
                    (__attribute__((address_space(3))) void*)(As + i * 8), 16, 0, 0);
            }
        }
        #pragma unroll
        for (int p = 0; p < 4; p++) {
            const int i = p * 256 + tid;
            const int r = i >> 3;
            const int gc = ((i & 7) ^ (r & 7)) * 8;
            __builtin_amdgcn_global_load_lds(
                (const __attribute__((address_space(1))) void*)(Bt + (size_t)(bcol + r) * K + k0 + gc),
                (__attribute__((address_space(3))) void*)(Bs + i * 8), 16, 0, 0);
        }
        __syncthreads();
        bf16x8 a[2][4], b[2][4];
        const int rA = wr * 64 + (lane & 15);
        const int rB = wc * 64 + (lane & 15);
        const int cq = lane >> 4;
        const int rx = lane & 7;
        #pragma unroll
        for (int ks = 0; ks < 2; ks++) {
            const int sl = ((ks * 4 + cq) ^ rx) * 8;
            #pragma unroll
            for (int m = 0; m < 4; m++) {
                a[ks][m] = *reinterpret_cast<const bf16x8*>(&As[(rA + m * 16) * 64 + sl]);
                b[ks][m] = *reinterpret_cast<const bf16x8*>(&Bs[(rB + m * 16) * 64 + sl]);
            }
        }
        #pragma unroll
        for (int ks = 0; ks < 2; ks++)
            #pragma unroll
            for (int m = 0; m < 4; m++)
                #pragma unroll
                for (int n = 0; n < 4; n++)
                    acc[m][n] = __builtin_amdgcn_mfma_f32_16x16x32_bf16(
                        a[ks][m], b[ks][n], acc[m][n], 0, 0, 0);
    }
    const int crow = brow + wr * 64 + (lane >> 4) * 4;
    const int ccol = bcol + wc * 64 + (lane & 15);
    #pragma unroll
    for (int m = 0; m < 4; m++)
        #pragma unroll
        for (int n = 0; n < 4; n++) {
            const int col = ccol + n * 16;
            #pragma unroll
            for (int j = 0; j < 4; j++) {
                const size_t idx = (size_t)(crow + m * 16 + j) * ldc + col;
                if (MODE == 0) {
                    ((float*)Cp)[idx] = acc[m][n][j];
                } else if (MODE == 1) {
                    atomicAdd(&((float*)Cp)[idx], acc[m][n][j]);
                } else if (MODE == 2) {
                    const float v = acc[m][n][j] + bias[col];
                    ((__bf16*)Cp)[idx] =
                        (__bf16)(fmaxf(v, 0.f) + log1pf(__expf(-fabsf(v))));
                } else {
                    ((__bf16*)Cp)[idx] = (__bf16)acc[m][n][j];
                }
            }
        }
}

// -------- depthwise causal conv (k=4) + bias + SiLU, 8 ch/thread -------------
__global__ __launch_bounds__(256) void conv_silu(
    const __bf16* __restrict__ xzb, const float* __restrict__ conv_w,
    const float* __restrict__ conv_b, __bf16* __restrict__ xcb)
{
    const int g  = blockIdx.x * 256 + threadIdx.x;
    const int d0 = (g & 255) * 8;
    const int tok = g >> 8;
    const int t   = tok & (SEQL - 1);

    float4 wv[8];
    #pragma unroll
    for (int j = 0; j < 8; j++)
        wv[j] = *reinterpret_cast<const float4*>(&conv_w[(d0 + j) * 4]);
    float acc[8];
    {
        const float4 b0 = *reinterpret_cast<const float4*>(&conv_b[d0]);
        const float4 b1 = *reinterpret_cast<const float4*>(&conv_b[d0 + 4]);
        acc[0] = b0.x; acc[1] = b0.y; acc[2] = b0.z; acc[3] = b0.w;
        acc[4] = b1.x; acc[5] = b1.y; acc[6] = b1.z; acc[7] = b1.w;
    }
    #pragma unroll
    for (int k = 0; k < 4; k++) {
        const int tt = t + k - 3;
        if (tt >= 0) {
            const bf16x8 v = *reinterpret_cast<const bf16x8*>(
                &xzb[(size_t)(tok + k - 3) * (2 * DI) + d0]);
            #pragma unroll
            for (int j = 0; j < 8; j++) {
                const float wk = (k == 0) ? wv[j].x : (k == 1) ? wv[j].y
                               : (k == 2) ? wv[j].z : wv[j].w;
                acc[j] += (float)v[j] * wk;
            }
        }
    }
    bf16x8 o;
    #pragma unroll
    for (int j = 0; j < 8; j++) {
        const float a = acc[j];
        o[j] = (__bf16)(a / (1.f + __expf(-a)));
    }
    *reinterpret_cast<bf16x8*>(&xcb[(size_t)g * 8]) = o;
}

// -------- scan pass A: per-chunk local scan from h=0 -------------------------
// Loads for the whole chunk are issued up-front (independent), then the
// recurrence runs register-resident.
__global__ __launch_bounds__(256) void scan_partial(
    const __bf16* __restrict__ xcb, const float* __restrict__ xdbl,
    const __bf16* __restrict__ dtb, const float* __restrict__ A_log,
    float* __restrict__ hpart, float* __restrict__ sdtb)
{
    __shared__ float Bsh[CL][16];
    const int tid = threadIdx.x;
    const int d = blockIdx.x * 256 + tid;
    const int c = blockIdx.y, b = blockIdx.z;
    const size_t base = (size_t)b * SEQL + c * CL;
    {
        const int st = tid >> 4, sg = tid & 15;
        Bsh[st][sg] = xdbl[(base + st) * XNP + DTR + sg];
    }
    // ---- preload all per-step operands (independent loads) ----
    float dtv[CL], xcv[CL];
    #pragma unroll
    for (int t = 0; t < CL; t++) {
        dtv[t] = (float)dtb[(base + t) * DI + d];
        xcv[t] = (float)xcb[(base + t) * DI + d];
    }
    float Av[16];
    #pragma unroll
    for (int i = 0; i < 4; i++) {
        const float4 v = *reinterpret_cast<const float4*>(&A_log[(size_t)d * 16 + i * 4]);
        Av[i*4+0] = -__expf(v.x); Av[i*4+1] = -__expf(v.y);
        Av[i*4+2] = -__expf(v.z); Av[i*4+3] = -__expf(v.w);
    }
    __syncthreads();
    float h[16] = {};
    float sdt = 0.f;
    #pragma unroll
    for (int t = 0; t < CL; t++) {
        sdt += dtv[t];
        const float dx = dtv[t] * xcv[t];
        #pragma unroll
        for (int n = 0; n < 16; n++)
            h[n] = __expf(dtv[t] * Av[n]) * h[n] + dx * Bsh[t][n];
    }
    const size_t ob = ((size_t)(b * CK + c) * DI + d) * 16;
    #pragma unroll
    for (int i = 0; i < 4; i++) {
        float4 v; v.x = h[i*4]; v.y = h[i*4+1]; v.z = h[i*4+2]; v.w = h[i*4+3];
        *reinterpret_cast<float4*>(&hpart[ob + i * 4]) = v;
    }
    sdtb[(size_t)(b * CK + c) * DI + d] = sdt;
}

// -------- scan pass B: chunk combine, hpart -> hentry (separate buffers) -----
// Batched: 16 independent load pairs per batch, then 16 chain steps.
__global__ __launch_bounds__(256) void scan_combine(
    const float* __restrict__ A_log, const float* __restrict__ sdtb,
    const float* __restrict__ hpart, float* __restrict__ hentry)
{
    const int idx = blockIdx.x * 256 + threadIdx.x;
    const int n = idx & 15;
    const int d = (idx >> 4) & (DI - 1);
    const int b = idx >> 15;
    const float A = -__expf(A_log[(size_t)d * 16 + n]);
    float h = 0.f;
    #pragma unroll
    for (int cb = 0; cb < CK / 16; cb++) {
        float hl[16], sv[16];
        #pragma unroll
        for (int j = 0; j < 16; j++) {
            const int c = cb * 16 + j;
            hl[j] = hpart[((size_t)(b * CK + c) * DI + d) * 16 + n];
            sv[j] = sdtb[(size_t)(b * CK + c) * DI + d];
        }
        #pragma unroll
        for (int j = 0; j < 16; j++) {
            const int c = cb * 16 + j;
            hentry[((size_t)(b * CK + c) * DI + d) * 16 + n] = h;
            h = __expf(A * sv[j]) * h + hl[j];
        }
    }
}

// -------- scan pass C: seeded re-scan, emit y (D-skip + z-gate) as bf16 ------
__global__ __launch_bounds__(256) void scan_final(
    const __bf16* __restrict__ xzb, const __bf16* __restrict__ xcb,
    const float* __restrict__ xdbl, const __bf16* __restrict__ dtb,
    const float* __restrict__ A_log, const float* __restrict__ Dp,
    const float* __restrict__ hentry, __bf16* __restrict__ yb)
{
    __shared__ float Bsh[CL][16];
    __shared__ float Csh[CL][16];
    const int tid = threadIdx.x;
    const int d = blockIdx.x * 256 + tid;
    const int c = blockIdx.y, b = blockIdx.z;
    const size_t base = (size_t)b * SEQL + c * CL;
    {
        const int st = tid >> 4, sg = tid & 15;
        Bsh[st][sg] = xdbl[(base + st) * XNP + DTR + sg];
        Csh[st][sg] = xdbl[(base + st) * XNP + DTR + DS + sg];
    }
    // ---- preload all per-step operands (independent loads) ----
    float dtv[CL], xcv[CL], zv[CL];
    #pragma unroll
    for (int t = 0; t < CL; t++) {
        dtv[t] = (float)dtb[(base + t) * DI + d];
        xcv[t] = (float)xcb[(base + t) * DI + d];
        zv[t]  = (float)xzb[(base + t) * (2 * DI) + DI + d];
    }
    float Av[16];
    #pragma unroll
    for (int i = 0; i < 4; i++) {
        const float4 v = *reinterpret_cast<const float4*>(&A_log[(size_t)d * 16 + i * 4]);
        Av[i*4+0] = -__expf(v.x); Av[i*4+1] = -__expf(v.y);
        Av[i*4+2] = -__expf(v.z); Av[i*4+3] = -__expf(v.w);
    }
    float h[16];
    const size_t ob = ((size_t)(b * CK + c) * DI + d) * 16;
    #pragma unroll
    for (int i = 0; i < 4; i++) {
        const float4 v = *reinterpret_cast<const float4*>(&hentry[ob + i * 4]);
        h[i*4] = v.x; h[i*4+1] = v.y; h[i*4+2] = v.z; h[i*4+3] = v.w;
    }
    const float Dv = Dp[d];
    __syncthreads();
    #pragma unroll
    for (int t = 0; t < CL; t++) {
        const float dx = dtv[t] * xcv[t];
        float y = 0.f;
        #pragma unroll
        for (int n = 0; n < 16; n++) {
            h[n] = __expf(dtv[t] * Av[n]) * h[n] + dx * Bsh[t][n];
            y += h[n] * Csh[t][n];
        }
        y += xcv[t] * Dv;
        y *= zv[t] / (1.f + __expf(-zv[t]));
        yb[(base + t) * DI + d] = (__bf16)y;
    }
}

// -------- out = x + LayerNorm(m) ---------------------------------------------
__global__ __launch_bounds__(256) void ln_add(
    const float* __restrict__ x, const float* __restrict__ m,
    const float* __restrict__ gamma, const float* __restrict__ beta,
    float* __restrict__ out)
{
    const int tok = blockIdx.x;
    const int tid = threadIdx.x;
    const int lane = tid & 63, wave = tid >> 6;
    __shared__ float red[4];
    __shared__ float stats[2];

    const float4 v = reinterpret_cast<const float4*>(&m[(size_t)tok * DM])[tid];
    float s = v.x + v.y + v.z + v.w;
    #pragma unroll
    for (int o = 32; o > 0; o >>= 1) s += __shfl_down(s, o, 64);
    if (lane == 0) red[wave] = s;
    __syncthreads();
    if (tid == 0) stats[0] = (red[0] + red[1] + red[2] + red[3]) * (1.f / DM);
    __syncthreads();
    const float mu = stats[0];
    const float dx = v.x - mu, dy = v.y - mu, dz = v.z - mu, dw = v.w - mu;
    float q = dx * dx + dy * dy + dz * dz + dw * dw;
    #pragma unroll
    for (int o = 32; o > 0; o >>= 1) q += __shfl_down(q, o, 64);
    if (lane == 0) red[wave] = q;
    __syncthreads();
    if (tid == 0)
        stats[1] = rsqrtf((red[0] + red[1] + red[2] + red[3]) * (1.f / DM) + 1e-6f);
    __syncthreads();
    const float rs = stats[1];

    const float4 g  = reinterpret_cast<const float4*>(gamma)[tid];
    const float4 bb = reinterpret_cast<const float4*>(beta)[tid];
    const float4 xv = reinterpret_cast<const float4*>(&x[(size_t)tok * DM])[tid];
    float4 o;
    o.x = xv.x + dx * rs * g.x + bb.x;
    o.y = xv.y + dy * rs * g.y + bb.y;
    o.z = xv.z + dz * rs * g.z + bb.z;
    o.w = xv.w + dw * rs * g.w + bb.w;
    reinterpret_cast<float4*>(&out[(size_t)tok * DM])[tid] = o;
}

extern "C" void kernel_launch(void* const* d_in, const int* in_sizes, int n_in,
                              void* d_out, int out_size, void* d_ws, size_t ws_size,
                              hipStream_t stream)
{
    const float* x      = (const float*)d_in[0];
    const float* W_in   = (const float*)d_in[1];
    const float* conv_w = (const float*)d_in[2];
    const float* conv_b = (const float*)d_in[3];
    const float* W_xprj = (const float*)d_in[4];
    const float* W_dt   = (const float*)d_in[5];
    const float* b_dt   = (const float*)d_in[6];
    const float* A_log  = (const float*)d_in[7];
    const float* D_par  = (const float*)d_in[8];
    const float* W_out  = (const float*)d_in[9];
    const float* gamma  = (const float*)d_in[10];
    const float* beta   = (const float*)d_in[11];
    float* out = (float*)d_out;

    // workspace layout (byte offsets, non-aliasing, ~100 MB total)
    char* w = (char*)d_ws;
    __bf16* xzb    = (__bf16*)(w + 0);          // 16 MB [NTOK][4096] (xi|z)
    __bf16* xcb    = (__bf16*)(w + 16777216);   //  8 MB [NTOK][DI]
    float*  xdbl   = (float*) (w + 25165824);   //  1 MB [NTOK][128]
    __bf16* dtb    = (__bf16*)(w + 26214400);   //  8 MB [NTOK][DI]
    float*  mbuf   = (float*) (w + 34603008);   //  8 MB [NTOK][DM]
    float*  hpart  = (float*) (w + 42991616);   // 16 MB [NB*CK][DI][16]
    float*  sdtb   = (float*) (w + 59768832);   //  1 MB [NB*CK][DI]
    __bf16* xb     = (__bf16*)(w + 60817408);   //  4 MB [NTOK][DM]
    __bf16* W_inT  = (__bf16*)(w + 65011712);   //  8 MB [4096][DM]
    __bf16* W_outT = (__bf16*)(w + 73400320);   //  4 MB [DM][DI]
    __bf16* W_xprT = (__bf16*)(w + 77594624);   // .5 MB [128][DI]
    __bf16* WdtT   = (__bf16*)(w + 78118912);   // .25MB [DI][64]
    __bf16* yb     = (__bf16*)(w + 78381056);   //  8 MB [NTOK][DI]
    float*  hentry = (float*) (w + 86769664);   // 16 MB [NB*CK][DI][16]

    // 0. fused prep (zeroing + cvt + transposes)
    prep<<<PREP_BLOCKS, 256, 0, stream>>>(
        x, W_in, W_out, W_dt, W_xprj, xb, W_inT, W_outT, WdtT, W_xprT, xdbl, mbuf);

    // 1. xz = x @ W_in  (M=2048, N=4096, K=1024) -> bf16
    gemm_bf16<3><<<dim3(32, 16, 1), 256, 0, stream>>>(
        xb, W_inT, xzb, NTOK, 2 * DI, DM, 2 * DI, nullptr);

    // 2. conv + silu -> bf16
    conv_silu<<<(NTOK * DI / 8) / 256, 256, 0, stream>>>(xzb, conv_w, conv_b, xcb);

    // 3. x_dbl = xc @ W_xproj  (N=128 pad, K=2048), split-K=16, atomic f32
    gemm_bf16<1><<<dim3(1, 16, 16), 256, 0, stream>>>(
        xcb, W_xprT, xdbl, NTOK, XNP, DI, XNP, nullptr);

    // 4. dt = softplus(dt_r @ W_dt + b_dt) -> bf16 (A reg-staged from f32 xdbl)
    gemm_bf16<2><<<dim3(16, 16, 1), 256, 0, stream>>>(
        (const __bf16*)xdbl, WdtT, dtb, NTOK, DI, DTR, DI, b_dt);

    // 5. chunked selective scan (CK=64 chunks of CL=16)
    scan_partial<<<dim3(DI / 256, CK, NB), 256, 0, stream>>>(
        xcb, xdbl, dtb, A_log, hpart, sdtb);
    scan_combine<<<NB * DI * DS / 256, 256, 0, stream>>>(A_log, sdtb, hpart, hentry);
    scan_final<<<dim3(DI / 256, CK, NB), 256, 0, stream>>>(
        xzb, xcb, xdbl, dtb, A_log, D_par, hentry, yb);

    // 6. m = y @ W_out  (M=2048, N=1024, K=2048), split-K=4, atomic f32
    gemm_bf16<1><<<dim3(8, 16, 4), 256, 0, stream>>>(
        yb, W_outT, mbuf, NTOK, DM, DI, DM, nullptr);

    // 7. out = x + LN(m)
    ln_add<<<NTOK, 256, 0, stream>>>(x, mbuf, gamma, beta, out);
}

// Round 9
// 183.535 us; speedup vs baseline: 7.1991x; 1.0089x over previous
//
#include <hip/hip_runtime.h>
#include <math.h>

#define DM   1024
#define DI   2048
#define DS   16
#define DTR  64
#define NB   2
#define SEQL 1024
#define NTOK (NB*SEQL)
#define XND  96   /* DTR + 2*DS */
#define XNP  128  /* padded xproj width */
#define CK   64   /* scan chunks */
#define CL   16   /* chunk length */

typedef __bf16 bf16x8 __attribute__((ext_vector_type(8)));
typedef float  f32x4  __attribute__((ext_vector_type(4)));

// ------------- fused prep: zeroing + conversions + transposes ----------------
#define PREP_BLOCKS 10624

__device__ inline void trans_tile(const float* __restrict__ W,
                                  __bf16* __restrict__ WT, int K, int N,
                                  int n0, int k0, int tid, __bf16 (*t)[33])
{
    const int tx = tid & 31, ty = tid >> 5;
    #pragma unroll
    for (int i = 0; i < 4; i++)
        t[ty * 4 + i][tx] = (__bf16)W[(size_t)(k0 + ty * 4 + i) * N + n0 + tx];
    __syncthreads();
    #pragma unroll
    for (int i = 0; i < 4; i++)
        WT[(size_t)(n0 + ty * 4 + i) * K + k0 + tx] = t[tx][ty * 4 + i];
}

__global__ __launch_bounds__(256) void prep(
    const float* __restrict__ x, const float* __restrict__ W_in,
    const float* __restrict__ W_out, const float* __restrict__ W_dt,
    const float* __restrict__ W_xprj,
    __bf16* __restrict__ xb, __bf16* __restrict__ W_inT,
    __bf16* __restrict__ W_outT, __bf16* __restrict__ WdtT,
    __bf16* __restrict__ W_xprT, float* __restrict__ xdbl,
    float* __restrict__ mbuf)
{
    __shared__ __bf16 t[32][33];
    int bid = blockIdx.x;
    const int tid = threadIdx.x;

    if (bid < 2304) {                       // R0: zero xdbl + mbuf
        const int i = bid * 1024 + tid * 4;
        const float4 z = {0.f, 0.f, 0.f, 0.f};
        if (i < 262144) *reinterpret_cast<float4*>(&xdbl[i]) = z;
        else            *reinterpret_cast<float4*>(&mbuf[i - 262144]) = z;
        return;
    }
    bid -= 2304;
    if (bid < 1024) {                       // R1: cvt x -> xb
        const int e = (bid * 256 + tid) * 8;
        const float4 v0 = *reinterpret_cast<const float4*>(&x[e]);
        const float4 v1 = *reinterpret_cast<const float4*>(&x[e + 4]);
        bf16x8 o;
        o[0] = (__bf16)v0.x; o[1] = (__bf16)v0.y; o[2] = (__bf16)v0.z; o[3] = (__bf16)v0.w;
        o[4] = (__bf16)v1.x; o[5] = (__bf16)v1.y; o[6] = (__bf16)v1.z; o[7] = (__bf16)v1.w;
        *reinterpret_cast<bf16x8*>(&xb[e]) = o;
        return;
    }
    bid -= 1024;
    if (bid < 4096) {                       // R2: W_in [1024][4096] -> T
        trans_tile(W_in, W_inT, DM, 2 * DI, (bid & 127) * 32, (bid >> 7) * 32, tid, t);
        return;
    }
    bid -= 4096;
    if (bid < 2048) {                       // R3: W_out [2048][1024] -> T
        trans_tile(W_out, W_outT, DI, DM, (bid & 31) * 32, (bid >> 5) * 32, tid, t);
        return;
    }
    bid -= 2048;
    if (bid < 128) {                        // R4: W_dt [64][2048] -> T
        trans_tile(W_dt, WdtT, DTR, DI, (bid & 63) * 32, (bid >> 6) * 32, tid, t);
        return;
    }
    bid -= 128;
    {                                       // R5: xproj transpose+pad
        const int idx = bid * 256 + tid;
        const int k = idx & (DI - 1);
        const int n = idx >> 11;
        W_xprT[(size_t)n * DI + k] = (n < XND) ? (__bf16)W_xprj[(size_t)k * XND + n]
                                               : (__bf16)0.f;
    }
}

// -------- bf16 MFMA GEMM, 128x128 tile, BK=64, XOR-swizzled LDS --------------
// Double-buffered: next tile's global_load_lds issued BEFORE compute on the
// current tile, so HBM latency hides under the MFMA block; one barrier/iter.
// MODE 0: store f32 | 1: atomicAdd f32 | 2: A = f32[.][128] cols 0..63 reg-
// staged+cvt, epilogue softplus(acc+bias)->bf16 | 3: store bf16
// SWZ 0: none | 1: XCD swizzle, row-major tiles | 2: XCD swizzle, col-major.
template<int MODE, int SWZ>
__global__ __launch_bounds__(256) void gemm_bf16(
    const __bf16* __restrict__ A, const __bf16* __restrict__ Bt,
    void* __restrict__ Cp, int M, int N, int K, int ldc,
    const float* __restrict__ bias)
{
    __shared__ __bf16 As[2][128 * 64];
    __shared__ __bf16 Bs[2][128 * 64];
    const int tid  = threadIdx.x;
    const int lane = tid & 63;
    const int wid  = tid >> 6;
    const int wr   = wid >> 1, wc = wid & 1;

    int bx = blockIdx.x, by = blockIdx.y;
    if (SWZ != 0) {
        const int gx = gridDim.x, gy = gridDim.y;
        const int nxy = gx * gy;          // must be a multiple of 8
        const int q = nxy >> 3;
        int lin = by * gx + bx;
        lin = (lin & 7) * q + (lin >> 3); // XCD j -> contiguous tile chunk
        if (SWZ == 1) { by = lin / gx; bx = lin % gx; }
        else          { bx = lin / gy; by = lin % gy; }
    }
    const int brow = by * 128, bcol = bx * 128;
    const int kper = K / gridDim.z;
    const int kbeg = blockIdx.z * kper, kend = kbeg + kper;

    f32x4 acc[4][4] = {};

    auto stage = [&](int buf, int k0) {
        if (MODE == 2) {
            const float* Af = reinterpret_cast<const float*>(A);
            #pragma unroll
            for (int p = 0; p < 4; p++) {
                const int i = p * 256 + tid;
                const int r = i >> 3;
                const int j = i & 7;
                const float4 v0 = *reinterpret_cast<const float4*>(
                    &Af[(size_t)(brow + r) * XNP + j * 8]);
                const float4 v1 = *reinterpret_cast<const float4*>(
                    &Af[(size_t)(brow + r) * XNP + j * 8 + 4]);
                bf16x8 o;
                o[0] = (__bf16)v0.x; o[1] = (__bf16)v0.y; o[2] = (__bf16)v0.z; o[3] = (__bf16)v0.w;
                o[4] = (__bf16)v1.x; o[5] = (__bf16)v1.y; o[6] = (__bf16)v1.z; o[7] = (__bf16)v1.w;
                *reinterpret_cast<bf16x8*>(&As[buf][r * 64 + ((j ^ (r & 7))) * 8]) = o;
            }
        } else {
            #pragma unroll
            for (int p = 0; p < 4; p++) {
                const int i = p * 256 + tid;
                const int r = i >> 3;
                const int gc = ((i & 7) ^ (r & 7)) * 8;
                __builtin_amdgcn_global_load_lds(
                    (const __attribute__((address_space(1))) void*)(A + (size_t)(brow + r) * K + k0 + gc),
                    (__attribute__((address_space(3))) void*)(&As[buf][i * 8]), 16, 0, 0);
            }
        }
        #pragma unroll
        for (int p = 0; p < 4; p++) {
            const int i = p * 256 + tid;
            const int r = i >> 3;
            const int gc = ((i & 7) ^ (r & 7)) * 8;
            __builtin_amdgcn_global_load_lds(
                (const __attribute__((address_space(1))) void*)(Bt + (size_t)(bcol + r) * K + k0 + gc),
                (__attribute__((address_space(3))) void*)(&Bs[buf][i * 8]), 16, 0, 0);
        }
    };

    const int nt = (kend - kbeg) >> 6;
    stage(0, kbeg);
    __syncthreads();                       // drains vmcnt -> buf0 ready
    int cur = 0;
    for (int t = 0; t < nt; t++) {
        if (t + 1 < nt) stage(cur ^ 1, kbeg + ((t + 1) << 6));   // issue early
        const __bf16* Ab = &As[cur][0];
        const __bf16* Bb = &Bs[cur][0];
        bf16x8 a[2][4], b[2][4];
        const int rA = wr * 64 + (lane & 15);
        const int rB = wc * 64 + (lane & 15);
        const int cq = lane >> 4;
        const int rx = lane & 7;
        #pragma unroll
        for (int ks = 0; ks < 2; ks++) {
            const int sl = ((ks * 4 + cq) ^ rx) * 8;
            #pragma unroll
            for (int m = 0; m < 4; m++) {
                a[ks][m] = *reinterpret_cast<const bf16x8*>(&Ab[(rA + m * 16) * 64 + sl]);
                b[ks][m] = *reinterpret_cast<const bf16x8*>(&Bb[(rB + m * 16) * 64 + sl]);
            }
        }
        #pragma unroll
        for (int ks = 0; ks < 2; ks++)
            #pragma unroll
            for (int m = 0; m < 4; m++)
                #pragma unroll
                for (int n = 0; n < 4; n++)
                    acc[m][n] = __builtin_amdgcn_mfma_f32_16x16x32_bf16(
                        a[ks][m], b[ks][n], acc[m][n], 0, 0, 0);
        __syncthreads();                   // drains vmcnt -> next buf ready
        cur ^= 1;
    }
    const int crow = brow + wr * 64 + (lane >> 4) * 4;
    const int ccol = bcol + wc * 64 + (lane & 15);
    #pragma unroll
    for (int m = 0; m < 4; m++)
        #pragma unroll
        for (int n = 0; n < 4; n++) {
            const int col = ccol + n * 16;
            #pragma unroll
            for (int j = 0; j < 4; j++) {
                const size_t idx = (size_t)(crow + m * 16 + j) * ldc + col;
                if (MODE == 0) {
                    ((float*)Cp)[idx] = acc[m][n][j];
                } else if (MODE == 1) {
                    atomicAdd(&((float*)Cp)[idx], acc[m][n][j]);
                } else if (MODE == 2) {
                    const float v = acc[m][n][j] + bias[col];
                    ((__bf16*)Cp)[idx] =
                        (__bf16)(fmaxf(v, 0.f) + log1pf(__expf(-fabsf(v))));
                } else {
                    ((__bf16*)Cp)[idx] = (__bf16)acc[m][n][j];
                }
            }
        }
}

// -------- depthwise causal conv (k=4) + bias + SiLU, 8 ch/thread -------------
__global__ __launch_bounds__(256) void conv_silu(
    const __bf16* __restrict__ xzb, const float* __restrict__ conv_w,
    const float* __restrict__ conv_b, __bf16* __restrict__ xcb)
{
    const int g  = blockIdx.x * 256 + threadIdx.x;
    const int d0 = (g & 255) * 8;
    const int tok = g >> 8;
    const int t   = tok & (SEQL - 1);

    float4 wv[8];
    #pragma unroll
    for (int j = 0; j < 8; j++)
        wv[j] = *reinterpret_cast<const float4*>(&conv_w[(d0 + j) * 4]);
    float acc[8];
    {
        const float4 b0 = *reinterpret_cast<const float4*>(&conv_b[d0]);
        const float4 b1 = *reinterpret_cast<const float4*>(&conv_b[d0 + 4]);
        acc[0] = b0.x; acc[1] = b0.y; acc[2] = b0.z; acc[3] = b0.w;
        acc[4] = b1.x; acc[5] = b1.y; acc[6] = b1.z; acc[7] = b1.w;
    }
    #pragma unroll
    for (int k = 0; k < 4; k++) {
        const int tt = t + k - 3;
        if (tt >= 0) {
            const bf16x8 v = *reinterpret_cast<const bf16x8*>(
                &xzb[(size_t)(tok + k - 3) * (2 * DI) + d0]);
            #pragma unroll
            for (int j = 0; j < 8; j++) {
                const float wk = (k == 0) ? wv[j].x : (k == 1) ? wv[j].y
                               : (k == 2) ? wv[j].z : wv[j].w;
                acc[j] += (float)v[j] * wk;
            }
        }
    }
    bf16x8 o;
    #pragma unroll
    for (int j = 0; j < 8; j++) {
        const float a = acc[j];
        o[j] = (__bf16)(a / (1.f + __expf(-a)));
    }
    *reinterpret_cast<bf16x8*>(&xcb[(size_t)g * 8]) = o;
}

// -------- scan pass A: per-chunk local scan from h=0 -------------------------
__global__ __launch_bounds__(256) void scan_partial(
    const __bf16* __restrict__ xcb, const float* __restrict__ xdbl,
    const __bf16* __restrict__ dtb, const float* __restrict__ A_log,
    float* __restrict__ hpart, float* __restrict__ sdtb)
{
    __shared__ float Bsh[CL][16];
    const int tid = threadIdx.x;
    const int d = blockIdx.x * 256 + tid;
    const int c = blockIdx.y, b = blockIdx.z;
    const size_t base = (size_t)b * SEQL + c * CL;
    {
        const int st = tid >> 4, sg = tid & 15;
        Bsh[st][sg] = xdbl[(base + st) * XNP + DTR + sg];
    }
    float dtv[CL], xcv[CL];
    #pragma unroll
    for (int t = 0; t < CL; t++) {
        dtv[t] = (float)dtb[(base + t) * DI + d];
        xcv[t] = (float)xcb[(base + t) * DI + d];
    }
    float Av[16];
    #pragma unroll
    for (int i = 0; i < 4; i++) {
        const float4 v = *reinterpret_cast<const float4*>(&A_log[(size_t)d * 16 + i * 4]);
        Av[i*4+0] = -__expf(v.x); Av[i*4+1] = -__expf(v.y);
        Av[i*4+2] = -__expf(v.z); Av[i*4+3] = -__expf(v.w);
    }
    __syncthreads();
    float h[16] = {};
    float sdt = 0.f;
    #pragma unroll
    for (int t = 0; t < CL; t++) {
        sdt += dtv[t];
        const float dx = dtv[t] * xcv[t];
        #pragma unroll
        for (int n = 0; n < 16; n++)
            h[n] = __expf(dtv[t] * Av[n]) * h[n] + dx * Bsh[t][n];
    }
    const size_t ob = ((size_t)(b * CK + c) * DI + d) * 16;
    #pragma unroll
    for (int i = 0; i < 4; i++) {
        float4 v; v.x = h[i*4]; v.y = h[i*4+1]; v.z = h[i*4+2]; v.w = h[i*4+3];
        *reinterpret_cast<float4*>(&hpart[ob + i * 4]) = v;
    }
    sdtb[(size_t)(b * CK + c) * DI + d] = sdt;
}

// -------- scan pass B: chunk combine, hpart -> hentry ------------------------
__global__ __launch_bounds__(256) void scan_combine(
    const float* __restrict__ A_log, const float* __restrict__ sdtb,
    const float* __restrict__ hpart, float* __restrict__ hentry)
{
    const int idx = blockIdx.x * 256 + threadIdx.x;
    const int n = idx & 15;
    const int d = (idx >> 4) & (DI - 1);
    const int b = idx >> 15;
    const float A = -__expf(A_log[(size_t)d * 16 + n]);
    float h = 0.f;
    #pragma unroll
    for (int cb = 0; cb < CK / 16; cb++) {
        float hl[16], sv[16];
        #pragma unroll
        for (int j = 0; j < 16; j++) {
            const int c = cb * 16 + j;
            hl[j] = hpart[((size_t)(b * CK + c) * DI + d) * 16 + n];
            sv[j] = sdtb[(size_t)(b * CK + c) * DI + d];
        }
        #pragma unroll
        for (int j = 0; j < 16; j++) {
            const int c = cb * 16 + j;
            hentry[((size_t)(b * CK + c) * DI + d) * 16 + n] = h;
            h = __expf(A * sv[j]) * h + hl[j];
        }
    }
}

// -------- scan pass C: seeded re-scan, emit y (D-skip + z-gate) as bf16 ------
__global__ __launch_bounds__(256) void scan_final(
    const __bf16* __restrict__ xzb, const __bf16* __restrict__ xcb,
    const float* __restrict__ xdbl, const __bf16* __restrict__ dtb,
    const float* __restrict__ A_log, const float* __restrict__ Dp,
    const float* __restrict__ hentry, __bf16* __restrict__ yb)
{
    __shared__ float Bsh[CL][16];
    __shared__ float Csh[CL][16];
    const int tid = threadIdx.x;
    const int d = blockIdx.x * 256 + tid;
    const int c = blockIdx.y, b = blockIdx.z;
    const size_t base = (size_t)b * SEQL + c * CL;
    {
        const int st = tid >> 4, sg = tid & 15;
        Bsh[st][sg] = xdbl[(base + st) * XNP + DTR + sg];
        Csh[st][sg] = xdbl[(base + st) * XNP + DTR + DS + sg];
    }
    float dtv[CL], xcv[CL], zv[CL];
    #pragma unroll
    for (int t = 0; t < CL; t++) {
        dtv[t] = (float)dtb[(base + t) * DI + d];
        xcv[t] = (float)xcb[(base + t) * DI + d];
        zv[t]  = (float)xzb[(base + t) * (2 * DI) + DI + d];
    }
    float Av[16];
    #pragma unroll
    for (int i = 0; i < 4; i++) {
        const float4 v = *reinterpret_cast<const float4*>(&A_log[(size_t)d * 16 + i * 4]);
        Av[i*4+0] = -__expf(v.x); Av[i*4+1] = -__expf(v.y);
        Av[i*4+2] = -__expf(v.z); Av[i*4+3] = -__expf(v.w);
    }
    float h[16];
    const size_t ob = ((size_t)(b * CK + c) * DI + d) * 16;
    #pragma unroll
    for (int i = 0; i < 4; i++) {
        const float4 v = *reinterpret_cast<const float4*>(&hentry[ob + i * 4]);
        h[i*4] = v.x; h[i*4+1] = v.y; h[i*4+2] = v.z; h[i*4+3] = v.w;
    }
    const float Dv = Dp[d];
    __syncthreads();
    #pragma unroll
    for (int t = 0; t < CL; t++) {
        const float dx = dtv[t] * xcv[t];
        float y = 0.f;
        #pragma unroll
        for (int n = 0; n < 16; n++) {
            h[n] = __expf(dtv[t] * Av[n]) * h[n] + dx * Bsh[t][n];
            y += h[n] * Csh[t][n];
        }
        y += xcv[t] * Dv;
        y *= zv[t] / (1.f + __expf(-zv[t]));
        yb[(base + t) * DI + d] = (__bf16)y;
    }
}

// -------- out = x + LayerNorm(m) ---------------------------------------------
__global__ __launch_bounds__(256) void ln_add(
    const float* __restrict__ x, const float* __restrict__ m,
    const float* __restrict__ gamma, const float* __restrict__ beta,
    float* __restrict__ out)
{
    const int tok = blockIdx.x;
    const int tid = threadIdx.x;
    const int lane = tid & 63, wave = tid >> 6;
    __shared__ float red[4];
    __shared__ float stats[2];

    const float4 v = reinterpret_cast<const float4*>(&m[(size_t)tok * DM])[tid];
    float s = v.x + v.y + v.z + v.w;
    #pragma unroll
    for (int o = 32; o > 0; o >>= 1) s += __shfl_down(s, o, 64);
    if (lane == 0) red[wave] = s;
    __syncthreads();
    if (tid == 0) stats[0] = (red[0] + red[1] + red[2] + red[3]) * (1.f / DM);
    __syncthreads();
    const float mu = stats[0];
    const float dx = v.x - mu, dy = v.y - mu, dz = v.z - mu, dw = v.w - mu;
    float q = dx * dx + dy * dy + dz * dz + dw * dw;
    #pragma unroll
    for (int o = 32; o > 0; o >>= 1) q += __shfl_down(q, o, 64);
    if (lane == 0) red[wave] = q;
    __syncthreads();
    if (tid == 0)
        stats[1] = rsqrtf((red[0] + red[1] + red[2] + red[3]) * (1.f / DM) + 1e-6f);
    __syncthreads();
    const float rs = stats[1];

    const float4 g  = reinterpret_cast<const float4*>(gamma)[tid];
    const float4 bb = reinterpret_cast<const float4*>(beta)[tid];
    const float4 xv = reinterpret_cast<const float4*>(&x[(size_t)tok * DM])[tid];
    float4 o;
    o.x = xv.x + dx * rs * g.x + bb.x;
    o.y = xv.y + dy * rs * g.y + bb.y;
    o.z = xv.z + dz * rs * g.z + bb.z;
    o.w = xv.w + dw * rs * g.w + bb.w;
    reinterpret_cast<float4*>(&out[(size_t)tok * DM])[tid] = o;
}

extern "C" void kernel_launch(void* const* d_in, const int* in_sizes, int n_in,
                              void* d_out, int out_size, void* d_ws, size_t ws_size,
                              hipStream_t stream)
{
    const float* x      = (const float*)d_in[0];
    const float* W_in   = (const float*)d_in[1];
    const float* conv_w = (const float*)d_in[2];
    const float* conv_b = (const float*)d_in[3];
    const float* W_xprj = (const float*)d_in[4];
    const float* W_dt   = (const float*)d_in[5];
    const float* b_dt   = (const float*)d_in[6];
    const float* A_log  = (const float*)d_in[7];
    const float* D_par  = (const float*)d_in[8];
    const float* W_out  = (const float*)d_in[9];
    const float* gamma  = (const float*)d_in[10];
    const float* beta   = (const float*)d_in[11];
    float* out = (float*)d_out;

    // workspace layout (byte offsets, non-aliasing, ~100 MB total)
    char* w = (char*)d_ws;
    __bf16* xzb    = (__bf16*)(w + 0);          // 16 MB [NTOK][4096] (xi|z)
    __bf16* xcb    = (__bf16*)(w + 16777216);   //  8 MB [NTOK][DI]
    float*  xdbl   = (float*) (w + 25165824);   //  1 MB [NTOK][128]
    __bf16* dtb    = (__bf16*)(w + 26214400);   //  8 MB [NTOK][DI]
    float*  mbuf   = (float*) (w + 34603008);   //  8 MB [NTOK][DM]
    float*  hpart  = (float*) (w + 42991616);   // 16 MB [NB*CK][DI][16]
    float*  sdtb   = (float*) (w + 59768832);   //  1 MB [NB*CK][DI]
    __bf16* xb     = (__bf16*)(w + 60817408);   //  4 MB [NTOK][DM]
    __bf16* W_inT  = (__bf16*)(w + 65011712);   //  8 MB [4096][DM]
    __bf16* W_outT = (__bf16*)(w + 73400320);   //  4 MB [DM][DI]
    __bf16* W_xprT = (__bf16*)(w + 77594624);   // .5 MB [128][DI]
    __bf16* WdtT   = (__bf16*)(w + 78118912);   // .25MB [DI][64]
    __bf16* yb     = (__bf16*)(w + 78381056);   //  8 MB [NTOK][DI]
    float*  hentry = (float*) (w + 86769664);   // 16 MB [NB*CK][DI][16]

    // 0. fused prep (zeroing + cvt + transposes)
    prep<<<PREP_BLOCKS, 256, 0, stream>>>(
        x, W_in, W_out, W_dt, W_xprj, xb, W_inT, W_outT, WdtT, W_xprT, xdbl, mbuf);

    // 1. xz = x @ W_in  (M=2048, N=4096, K=1024) -> bf16, col-major XCD chunks
    gemm_bf16<3, 2><<<dim3(32, 16, 1), 256, 0, stream>>>(
        xb, W_inT, xzb, NTOK, 2 * DI, DM, 2 * DI, nullptr);

    // 2. conv + silu -> bf16
    conv_silu<<<(NTOK * DI / 8) / 256, 256, 0, stream>>>(xzb, conv_w, conv_b, xcb);

    // 3. x_dbl = xc @ W_xproj  (N=128 pad, K=2048), split-K=16, atomic f32
    gemm_bf16<1, 0><<<dim3(1, 16, 16), 256, 0, stream>>>(
        xcb, W_xprT, xdbl, NTOK, XNP, DI, XNP, nullptr);

    // 4. dt = softplus(dt_r @ W_dt + b_dt) -> bf16 (A reg-staged from f32 xdbl)
    gemm_bf16<2, 0><<<dim3(16, 16, 1), 256, 0, stream>>>(
        (const __bf16*)xdbl, WdtT, dtb, NTOK, DI, DTR, DI, b_dt);

    // 5. chunked selective scan (CK=64 chunks of CL=16)
    scan_partial<<<dim3(DI / 256, CK, NB), 256, 0, stream>>>(
        xcb, xdbl, dtb, A_log, hpart, sdtb);
    scan_combine<<<NB * DI * DS / 256, 256, 0, stream>>>(A_log, sdtb, hpart, hentry);
    scan_final<<<dim3(DI / 256, CK, NB), 256, 0, stream>>>(
        xzb, xcb, xdbl, dtb, A_log, D_par, hentry, yb);

    // 6. m = y @ W_out  (M=2048, N=1024, K=2048), split-K=4, row-major XCD chunks
    gemm_bf16<1, 1><<<dim3(8, 16, 4), 256, 0, stream>>>(
        yb, W_outT, mbuf, NTOK, DM, DI, DM, nullptr);

    // 7. out = x + LN(m)
    ln_add<<<NTOK, 256, 0, stream>>>(x, mbuf, gamma, beta, out);
}

// Round 10
// 171.219 us; speedup vs baseline: 7.7170x; 1.0719x over previous
//
#include <hip/hip_runtime.h>
#include <math.h>

#define DM   1024
#define DI   2048
#define DS   16
#define DTR  64
#define NB   2
#define SEQL 1024
#define NTOK (NB*SEQL)
#define XND  96   /* DTR + 2*DS */
#define XNP  128  /* padded xproj width */
#define CK   64   /* scan chunks */
#define CL   16   /* chunk length */

typedef __bf16 bf16x8 __attribute__((ext_vector_type(8)));
typedef __bf16 bf16x4 __attribute__((ext_vector_type(4)));
typedef float  f32x4  __attribute__((ext_vector_type(4)));

// ------------- fused prep: zeroing + conversions + transposes ----------------
// R0 [0,256):      zero xdbl (256K f32)
// R1 [256,1280):   cvt x -> xb bf16
// R2 [1280,2304):  W_in [1024][4096] -> W_inT bf16 (64x64 tiles)
// R3 [2304,2816):  W_out [2048][1024] -> W_outT bf16
// R4 [2816,2848):  W_dt [64][2048] -> WdtT bf16
// R5 [2848,3872):  W_xproj [2048][96] -> W_xprT[128][2048] bf16 (pad)
#define PREP_BLOCKS 3872

__device__ inline void trans_tile64(const float* __restrict__ W,
                                    __bf16* __restrict__ WT, int K, int N,
                                    int n0, int k0, int tid, __bf16 (*t)[65])
{
    const int tx = tid & 63, ty = tid >> 6;   // ty 0..3
    #pragma unroll
    for (int i = 0; i < 16; i++)
        t[ty * 16 + i][tx] = (__bf16)W[(size_t)(k0 + ty * 16 + i) * N + n0 + tx];
    __syncthreads();
    #pragma unroll
    for (int i = 0; i < 16; i++)
        WT[(size_t)(n0 + ty * 16 + i) * K + k0 + tx] = t[tx][ty * 16 + i];
}

__global__ __launch_bounds__(256) void prep(
    const float* __restrict__ x, const float* __restrict__ W_in,
    const float* __restrict__ W_out, const float* __restrict__ W_dt,
    const float* __restrict__ W_xprj,
    __bf16* __restrict__ xb, __bf16* __restrict__ W_inT,
    __bf16* __restrict__ W_outT, __bf16* __restrict__ WdtT,
    __bf16* __restrict__ W_xprT, float* __restrict__ xdbl)
{
    __shared__ __bf16 t[64][65];
    int bid = blockIdx.x;
    const int tid = threadIdx.x;

    if (bid < 256) {                        // R0: zero xdbl
        const int i = bid * 1024 + tid * 4;
        const float4 z = {0.f, 0.f, 0.f, 0.f};
        *reinterpret_cast<float4*>(&xdbl[i]) = z;
        return;
    }
    bid -= 256;
    if (bid < 1024) {                       // R1: cvt x -> xb
        const int e = (bid * 256 + tid) * 8;
        const float4 v0 = *reinterpret_cast<const float4*>(&x[e]);
        const float4 v1 = *reinterpret_cast<const float4*>(&x[e + 4]);
        bf16x8 o;
        o[0] = (__bf16)v0.x; o[1] = (__bf16)v0.y; o[2] = (__bf16)v0.z; o[3] = (__bf16)v0.w;
        o[4] = (__bf16)v1.x; o[5] = (__bf16)v1.y; o[6] = (__bf16)v1.z; o[7] = (__bf16)v1.w;
        *reinterpret_cast<bf16x8*>(&xb[e]) = o;
        return;
    }
    bid -= 1024;
    if (bid < 1024) {                       // R2: W_in (64 n-tiles x 16 k-tiles)
        trans_tile64(W_in, W_inT, DM, 2 * DI, (bid & 63) * 64, (bid >> 6) * 64, tid, t);
        return;
    }
    bid -= 1024;
    if (bid < 512) {                        // R3: W_out (16 n-tiles x 32 k-tiles)
        trans_tile64(W_out, W_outT, DI, DM, (bid & 15) * 64, (bid >> 4) * 64, tid, t);
        return;
    }
    bid -= 512;
    if (bid < 32) {                         // R4: W_dt (32 n-tiles x 1 k-tile)
        trans_tile64(W_dt, WdtT, DTR, DI, bid * 64, 0, tid, t);
        return;
    }
    bid -= 32;
    {                                       // R5: xproj transpose+pad
        const int idx = bid * 256 + tid;
        const int k = idx & (DI - 1);
        const int n = idx >> 11;
        W_xprT[(size_t)n * DI + k] = (n < XND) ? (__bf16)W_xprj[(size_t)k * XND + n]
                                               : (__bf16)0.f;
    }
}

// -------- bf16 MFMA GEMM, 128x128 tile, BK=64, XOR-swizzled LDS --------------
// Double-buffered, stage-early. MODE 0: store f32 | 1: atomicAdd f32 |
// 2: A from f32 [.][128] cols 0..63 reg-staged+cvt, softplus(acc+bias)->bf16 |
// 3: store bf16 (with per-z partial offset when gridDim.z>1).
// SWZ 0: none | 1: XCD swizzle row-major | 2: XCD swizzle col-major.
template<int MODE, int SWZ>
__global__ __launch_bounds__(256) void gemm_bf16(
    const __bf16* __restrict__ A, const __bf16* __restrict__ Bt,
    void* __restrict__ Cp, int M, int N, int K, int ldc,
    const float* __restrict__ bias)
{
    __shared__ __bf16 As[2][128 * 64];
    __shared__ __bf16 Bs[2][128 * 64];
    const int tid  = threadIdx.x;
    const int lane = tid & 63;
    const int wid  = tid >> 6;
    const int wr   = wid >> 1, wc = wid & 1;

    int bx = blockIdx.x, by = blockIdx.y;
    if (SWZ != 0) {
        const int gx = gridDim.x, gy = gridDim.y;
        const int nxy = gx * gy;          // multiple of 8
        const int q = nxy >> 3;
        int lin = by * gx + bx;
        lin = (lin & 7) * q + (lin >> 3);
        if (SWZ == 1) { by = lin / gx; bx = lin % gx; }
        else          { bx = lin / gy; by = lin % gy; }
    }
    const int brow = by * 128, bcol = bx * 128;
    const int kper = K / gridDim.z;
    const int kbeg = blockIdx.z * kper, kend = kbeg + kper;

    f32x4 acc[4][4] = {};

    auto stage = [&](int buf, int k0) {
        if (MODE == 2) {
            const float* Af = reinterpret_cast<const float*>(A);
            #pragma unroll
            for (int p = 0; p < 4; p++) {
                const int i = p * 256 + tid;
                const int r = i >> 3;
                const int j = i & 7;
                const float4 v0 = *reinterpret_cast<const float4*>(
                    &Af[(size_t)(brow + r) * XNP + j * 8]);
                const float4 v1 = *reinterpret_cast<const float4*>(
                    &Af[(size_t)(brow + r) * XNP + j * 8 + 4]);
                bf16x8 o;
                o[0] = (__bf16)v0.x; o[1] = (__bf16)v0.y; o[2] = (__bf16)v0.z; o[3] = (__bf16)v0.w;
                o[4] = (__bf16)v1.x; o[5] = (__bf16)v1.y; o[6] = (__bf16)v1.z; o[7] = (__bf16)v1.w;
                *reinterpret_cast<bf16x8*>(&As[buf][r * 64 + ((j ^ (r & 7))) * 8]) = o;
            }
        } else {
            #pragma unroll
            for (int p = 0; p < 4; p++) {
                const int i = p * 256 + tid;
                const int r = i >> 3;
                const int gc = ((i & 7) ^ (r & 7)) * 8;
                __builtin_amdgcn_global_load_lds(
                    (const __attribute__((address_space(1))) void*)(A + (size_t)(brow + r) * K + k0 + gc),
                    (__attribute__((address_space(3))) void*)(&As[buf][i * 8]), 16, 0, 0);
            }
        }
        #pragma unroll
        for (int p = 0; p < 4; p++) {
            const int i = p * 256 + tid;
            const int r = i >> 3;
            const int gc = ((i & 7) ^ (r & 7)) * 8;
            __builtin_amdgcn_global_load_lds(
                (const __attribute__((address_space(1))) void*)(Bt + (size_t)(bcol + r) * K + k0 + gc),
                (__attribute__((address_space(3))) void*)(&Bs[buf][i * 8]), 16, 0, 0);
        }
    };

    const int nt = (kend - kbeg) >> 6;
    stage(0, kbeg);
    __syncthreads();
    int cur = 0;
    for (int t = 0; t < nt; t++) {
        if (t + 1 < nt) stage(cur ^ 1, kbeg + ((t + 1) << 6));
        const __bf16* Ab = &As[cur][0];
        const __bf16* Bb = &Bs[cur][0];
        bf16x8 a[2][4], b[2][4];
        const int rA = wr * 64 + (lane & 15);
        const int rB = wc * 64 + (lane & 15);
        const int cq = lane >> 4;
        const int rx = lane & 7;
        #pragma unroll
        for (int ks = 0; ks < 2; ks++) {
            const int sl = ((ks * 4 + cq) ^ rx) * 8;
            #pragma unroll
            for (int m = 0; m < 4; m++) {
                a[ks][m] = *reinterpret_cast<const bf16x8*>(&Ab[(rA + m * 16) * 64 + sl]);
                b[ks][m] = *reinterpret_cast<const bf16x8*>(&Bb[(rB + m * 16) * 64 + sl]);
            }
        }
        #pragma unroll
        for (int ks = 0; ks < 2; ks++)
            #pragma unroll
            for (int m = 0; m < 4; m++)
                #pragma unroll
                for (int n = 0; n < 4; n++)
                    acc[m][n] = __builtin_amdgcn_mfma_f32_16x16x32_bf16(
                        a[ks][m], b[ks][n], acc[m][n], 0, 0, 0);
        __syncthreads();
        cur ^= 1;
    }
    const int crow = brow + wr * 64 + (lane >> 4) * 4;
    const int ccol = bcol + wc * 64 + (lane & 15);
    __bf16* Cb3 = (__bf16*)Cp + (size_t)blockIdx.z * ((MODE == 3) ? (size_t)M * ldc : 0);
    #pragma unroll
    for (int m = 0; m < 4; m++)
        #pragma unroll
        for (int n = 0; n < 4; n++) {
            const int col = ccol + n * 16;
            #pragma unroll
            for (int j = 0; j < 4; j++) {
                const size_t idx = (size_t)(crow + m * 16 + j) * ldc + col;
                if (MODE == 0) {
                    ((float*)Cp)[idx] = acc[m][n][j];
                } else if (MODE == 1) {
                    atomicAdd(&((float*)Cp)[idx], acc[m][n][j]);
                } else if (MODE == 2) {
                    const float v = acc[m][n][j] + bias[col];
                    ((__bf16*)Cp)[idx] =
                        (__bf16)(fmaxf(v, 0.f) + log1pf(__expf(-fabsf(v))));
                } else {
                    Cb3[idx] = (__bf16)acc[m][n][j];
                }
            }
        }
}

// -------- depthwise causal conv (k=4) + bias + SiLU, 8 ch/thread -------------
__global__ __launch_bounds__(256) void conv_silu(
    const __bf16* __restrict__ xzb, const float* __restrict__ conv_w,
    const float* __restrict__ conv_b, __bf16* __restrict__ xcb)
{
    const int g  = blockIdx.x * 256 + threadIdx.x;
    const int d0 = (g & 255) * 8;
    const int tok = g >> 8;
    const int t   = tok & (SEQL - 1);

    float4 wv[8];
    #pragma unroll
    for (int j = 0; j < 8; j++)
        wv[j] = *reinterpret_cast<const float4*>(&conv_w[(d0 + j) * 4]);
    float acc[8];
    {
        const float4 b0 = *reinterpret_cast<const float4*>(&conv_b[d0]);
        const float4 b1 = *reinterpret_cast<const float4*>(&conv_b[d0 + 4]);
        acc[0] = b0.x; acc[1] = b0.y; acc[2] = b0.z; acc[3] = b0.w;
        acc[4] = b1.x; acc[5] = b1.y; acc[6] = b1.z; acc[7] = b1.w;
    }
    #pragma unroll
    for (int k = 0; k < 4; k++) {
        const int tt = t + k - 3;
        if (tt >= 0) {
            const bf16x8 v = *reinterpret_cast<const bf16x8*>(
                &xzb[(size_t)(tok + k - 3) * (2 * DI) + d0]);
            #pragma unroll
            for (int j = 0; j < 8; j++) {
                const float wk = (k == 0) ? wv[j].x : (k == 1) ? wv[j].y
                               : (k == 2) ? wv[j].z : wv[j].w;
                acc[j] += (float)v[j] * wk;
            }
        }
    }
    bf16x8 o;
    #pragma unroll
    for (int j = 0; j < 8; j++) {
        const float a = acc[j];
        o[j] = (__bf16)(a / (1.f + __expf(-a)));
    }
    *reinterpret_cast<bf16x8*>(&xcb[(size_t)g * 8]) = o;
}

// -------- scan pass A: per-chunk local scan from h=0, bf16 h out -------------
__global__ __launch_bounds__(256) void scan_partial(
    const __bf16* __restrict__ xcb, const float* __restrict__ xdbl,
    const __bf16* __restrict__ dtb, const float* __restrict__ A_log,
    __bf16* __restrict__ hpart, float* __restrict__ sdtb)
{
    __shared__ float Bsh[CL][16];
    const int tid = threadIdx.x;
    const int d = blockIdx.x * 256 + tid;
    const int c = blockIdx.y, b = blockIdx.z;
    const size_t base = (size_t)b * SEQL + c * CL;
    {
        const int st = tid >> 4, sg = tid & 15;
        Bsh[st][sg] = xdbl[(base + st) * XNP + DTR + sg];
    }
    float dtv[CL], xcv[CL];
    #pragma unroll
    for (int t = 0; t < CL; t++) {
        dtv[t] = (float)dtb[(base + t) * DI + d];
        xcv[t] = (float)xcb[(base + t) * DI + d];
    }
    float Av[16];
    #pragma unroll
    for (int i = 0; i < 4; i++) {
        const float4 v = *reinterpret_cast<const float4*>(&A_log[(size_t)d * 16 + i * 4]);
        Av[i*4+0] = -__expf(v.x); Av[i*4+1] = -__expf(v.y);
        Av[i*4+2] = -__expf(v.z); Av[i*4+3] = -__expf(v.w);
    }
    __syncthreads();
    float h[16] = {};
    float sdt = 0.f;
    #pragma unroll
    for (int t = 0; t < CL; t++) {
        sdt += dtv[t];
        const float dx = dtv[t] * xcv[t];
        #pragma unroll
        for (int n = 0; n < 16; n++)
            h[n] = __expf(dtv[t] * Av[n]) * h[n] + dx * Bsh[t][n];
    }
    const size_t ob = ((size_t)(b * CK + c) * DI + d) * 16;
    bf16x8 o0, o1;
    #pragma unroll
    for (int i = 0; i < 8; i++) { o0[i] = (__bf16)h[i]; o1[i] = (__bf16)h[i + 8]; }
    *reinterpret_cast<bf16x8*>(&hpart[ob])     = o0;
    *reinterpret_cast<bf16x8*>(&hpart[ob + 8]) = o1;
    sdtb[(size_t)(b * CK + c) * DI + d] = sdt;
}

// -------- scan pass B: chunk combine, hpart -> hentry (bf16) -----------------
__global__ __launch_bounds__(256) void scan_combine(
    const float* __restrict__ A_log, const float* __restrict__ sdtb,
    const __bf16* __restrict__ hpart, __bf16* __restrict__ hentry)
{
    const int idx = blockIdx.x * 256 + threadIdx.x;
    const int n = idx & 15;
    const int d = (idx >> 4) & (DI - 1);
    const int b = idx >> 15;
    const float A = -__expf(A_log[(size_t)d * 16 + n]);
    float h = 0.f;
    #pragma unroll
    for (int cb = 0; cb < CK / 16; cb++) {
        float hl[16], sv[16];
        #pragma unroll
        for (int j = 0; j < 16; j++) {
            const int c = cb * 16 + j;
            hl[j] = (float)hpart[((size_t)(b * CK + c) * DI + d) * 16 + n];
            sv[j] = sdtb[(size_t)(b * CK + c) * DI + d];
        }
        #pragma unroll
        for (int j = 0; j < 16; j++) {
            const int c = cb * 16 + j;
            hentry[((size_t)(b * CK + c) * DI + d) * 16 + n] = (__bf16)h;
            h = __expf(A * sv[j]) * h + hl[j];
        }
    }
}

// -------- scan pass C: seeded re-scan, emit y (D-skip + z-gate) as bf16 ------
__global__ __launch_bounds__(256) void scan_final(
    const __bf16* __restrict__ xzb, const __bf16* __restrict__ xcb,
    const float* __restrict__ xdbl, const __bf16* __restrict__ dtb,
    const float* __restrict__ A_log, const float* __restrict__ Dp,
    const __bf16* __restrict__ hentry, __bf16* __restrict__ yb)
{
    __shared__ float Bsh[CL][16];
    __shared__ float Csh[CL][16];
    const int tid = threadIdx.x;
    const int d = blockIdx.x * 256 + tid;
    const int c = blockIdx.y, b = blockIdx.z;
    const size_t base = (size_t)b * SEQL + c * CL;
    {
        const int st = tid >> 4, sg = tid & 15;
        Bsh[st][sg] = xdbl[(base + st) * XNP + DTR + sg];
        Csh[st][sg] = xdbl[(base + st) * XNP + DTR + DS + sg];
    }
    float dtv[CL], xcv[CL], zv[CL];
    #pragma unroll
    for (int t = 0; t < CL; t++) {
        dtv[t] = (float)dtb[(base + t) * DI + d];
        xcv[t] = (float)xcb[(base + t) * DI + d];
        zv[t]  = (float)xzb[(base + t) * (2 * DI) + DI + d];
    }
    float Av[16];
    #pragma unroll
    for (int i = 0; i < 4; i++) {
        const float4 v = *reinterpret_cast<const float4*>(&A_log[(size_t)d * 16 + i * 4]);
        Av[i*4+0] = -__expf(v.x); Av[i*4+1] = -__expf(v.y);
        Av[i*4+2] = -__expf(v.z); Av[i*4+3] = -__expf(v.w);
    }
    float h[16];
    const size_t ob = ((size_t)(b * CK + c) * DI + d) * 16;
    {
        const bf16x8 v0 = *reinterpret_cast<const bf16x8*>(&hentry[ob]);
        const bf16x8 v1 = *reinterpret_cast<const bf16x8*>(&hentry[ob + 8]);
        #pragma unroll
        for (int i = 0; i < 8; i++) { h[i] = (float)v0[i]; h[i + 8] = (float)v1[i]; }
    }
    const float Dv = Dp[d];
    __syncthreads();
    #pragma unroll
    for (int t = 0; t < CL; t++) {
        const float dx = dtv[t] * xcv[t];
        float y = 0.f;
        #pragma unroll
        for (int n = 0; n < 16; n++) {
            h[n] = __expf(dtv[t] * Av[n]) * h[n] + dx * Bsh[t][n];
            y += h[n] * Csh[t][n];
        }
        y += xcv[t] * Dv;
        y *= zv[t] / (1.f + __expf(-zv[t]));
        yb[(base + t) * DI + d] = (__bf16)y;
    }
}

// -------- out = x + LayerNorm(sum of 4 bf16 partials) ------------------------
__global__ __launch_bounds__(256) void ln_add(
    const float* __restrict__ x, const __bf16* __restrict__ mpart,
    const float* __restrict__ gamma, const float* __restrict__ beta,
    float* __restrict__ out)
{
    const int tok = blockIdx.x;
    const int tid = threadIdx.x;
    const int lane = tid & 63, wave = tid >> 6;
    __shared__ float red[4];
    __shared__ float stats[2];

    float4 v = {0.f, 0.f, 0.f, 0.f};
    #pragma unroll
    for (int p = 0; p < 4; p++) {
        const bf16x4 mv = *reinterpret_cast<const bf16x4*>(
            &mpart[((size_t)p * NTOK + tok) * DM + tid * 4]);
        v.x += (float)mv[0]; v.y += (float)mv[1];
        v.z += (float)mv[2]; v.w += (float)mv[3];
    }
    float s = v.x + v.y + v.z + v.w;
    #pragma unroll
    for (int o = 32; o > 0; o >>= 1) s += __shfl_down(s, o, 64);
    if (lane == 0) red[wave] = s;
    __syncthreads();
    if (tid == 0) stats[0] = (red[0] + red[1] + red[2] + red[3]) * (1.f / DM);
    __syncthreads();
    const float mu = stats[0];
    const float dx = v.x - mu, dy = v.y - mu, dz = v.z - mu, dw = v.w - mu;
    float q = dx * dx + dy * dy + dz * dz + dw * dw;
    #pragma unroll
    for (int o = 32; o > 0; o >>= 1) q += __shfl_down(q, o, 64);
    if (lane == 0) red[wave] = q;
    __syncthreads();
    if (tid == 0)
        stats[1] = rsqrtf((red[0] + red[1] + red[2] + red[3]) * (1.f / DM) + 1e-6f);
    __syncthreads();
    const float rs = stats[1];

    const float4 g  = reinterpret_cast<const float4*>(gamma)[tid];
    const float4 bb = reinterpret_cast<const float4*>(beta)[tid];
    const float4 xv = reinterpret_cast<const float4*>(&x[(size_t)tok * DM])[tid];
    float4 o;
    o.x = xv.x + dx * rs * g.x + bb.x;
    o.y = xv.y + dy * rs * g.y + bb.y;
    o.z = xv.z + dz * rs * g.z + bb.z;
    o.w = xv.w + dw * rs * g.w + bb.w;
    reinterpret_cast<float4*>(&out[(size_t)tok * DM])[tid] = o;
}

extern "C" void kernel_launch(void* const* d_in, const int* in_sizes, int n_in,
                              void* d_out, int out_size, void* d_ws, size_t ws_size,
                              hipStream_t stream)
{
    const float* x      = (const float*)d_in[0];
    const float* W_in   = (const float*)d_in[1];
    const float* conv_w = (const float*)d_in[2];
    const float* conv_b = (const float*)d_in[3];
    const float* W_xprj = (const float*)d_in[4];
    const float* W_dt   = (const float*)d_in[5];
    const float* b_dt   = (const float*)d_in[6];
    const float* A_log  = (const float*)d_in[7];
    const float* D_par  = (const float*)d_in[8];
    const float* W_out  = (const float*)d_in[9];
    const float* gamma  = (const float*)d_in[10];
    const float* beta   = (const float*)d_in[11];
    float* out = (float*)d_out;

    // workspace layout (byte offsets, non-aliasing, ~95 MB)
    char* w = (char*)d_ws;
    __bf16* xzb    = (__bf16*)(w + 0);          // 16 MB [NTOK][4096] (xi|z)
    __bf16* xcb    = (__bf16*)(w + 16777216);   //  8 MB [NTOK][DI]
    float*  xdbl   = (float*) (w + 25165824);   //  1 MB [NTOK][128]
    __bf16* dtb    = (__bf16*)(w + 26214400);   //  8 MB [NTOK][DI]
    __bf16* mpart  = (__bf16*)(w + 34603008);   // 16 MB [4][NTOK][DM]
    __bf16* hpart  = (__bf16*)(w + 51380224);   //  8 MB [NB*CK][DI][16]
    __bf16* hentry = (__bf16*)(w + 59768832);   //  8 MB [NB*CK][DI][16]
    float*  sdtb   = (float*) (w + 68157440);   // .5 MB [NB*CK][DI]
    __bf16* xb     = (__bf16*)(w + 68681728);   //  4 MB [NTOK][DM]
    __bf16* W_inT  = (__bf16*)(w + 72876032);   //  8 MB [4096][DM]
    __bf16* W_outT = (__bf16*)(w + 81264640);   //  4 MB [DM][DI]
    __bf16* W_xprT = (__bf16*)(w + 85458944);   // .5 MB [128][DI]
    __bf16* WdtT   = (__bf16*)(w + 85983232);   // .25MB [DI][64]
    __bf16* yb     = (__bf16*)(w + 86245376);   //  8 MB [NTOK][DI]

    // 0. fused prep
    prep<<<PREP_BLOCKS, 256, 0, stream>>>(
        x, W_in, W_out, W_dt, W_xprj, xb, W_inT, W_outT, WdtT, W_xprT, xdbl);

    // 1. xz = x @ W_in  (M=2048, N=4096, K=1024) -> bf16
    gemm_bf16<3, 2><<<dim3(32, 16, 1), 256, 0, stream>>>(
        xb, W_inT, xzb, NTOK, 2 * DI, DM, 2 * DI, nullptr);

    // 2. conv + silu -> bf16
    conv_silu<<<(NTOK * DI / 8) / 256, 256, 0, stream>>>(xzb, conv_w, conv_b, xcb);

    // 3. x_dbl = xc @ W_xproj  (N=128 pad, K=2048), split-K=16, atomic f32
    gemm_bf16<1, 0><<<dim3(1, 16, 16), 256, 0, stream>>>(
        xcb, W_xprT, xdbl, NTOK, XNP, DI, XNP, nullptr);

    // 4. dt = softplus(dt_r @ W_dt + b_dt) -> bf16
    gemm_bf16<2, 0><<<dim3(16, 16, 1), 256, 0, stream>>>(
        (const __bf16*)xdbl, WdtT, dtb, NTOK, DI, DTR, DI, b_dt);

    // 5. chunked selective scan (CK=64 chunks of CL=16)
    scan_partial<<<dim3(DI / 256, CK, NB), 256, 0, stream>>>(
        xcb, xdbl, dtb, A_log, hpart, sdtb);
    scan_combine<<<NB * DI * DS / 256, 256, 0, stream>>>(A_log, sdtb, hpart, hentry);
    scan_final<<<dim3(DI / 256, CK, NB), 256, 0, stream>>>(
        xzb, xcb, xdbl, dtb, A_log, D_par, hentry, yb);

    // 6. m partials = y @ W_out  (split-K=4, bf16 partial stores, no atomics)
    gemm_bf16<3, 1><<<dim3(8, 16, 4), 256, 0, stream>>>(
        yb, W_outT, mpart, NTOK, DM, DI, DM, nullptr);

    // 7. out = x + LN(sum of partials)
    ln_add<<<NTOK, 256, 0, stream>>>(x, mpart, gamma, beta, out);
}

// Round 12
// 162.141 us; speedup vs baseline: 8.1490x; 1.0560x over previous
//
#include <hip/hip_runtime.h>
#include <math.h>

#define DM   1024
#define DI   2048
#define DS   16
#define DTR  64
#define NB   2
#define SEQL 1024
#define NTOK (NB*SEQL)
#define XND  96   /* DTR + 2*DS */
#define XNP  128  /* padded xproj width */
#define CK   128  /* scan chunks */
#define CL   8    /* chunk length */

typedef __bf16 bf16x8 __attribute__((ext_vector_type(8)));
typedef __bf16 bf16x4 __attribute__((ext_vector_type(4)));
typedef float  f32x4  __attribute__((ext_vector_type(4)));

// ------------- fused prep: zeroing + conversions + transposes ----------------
#define PREP_BLOCKS 3872

__device__ inline void trans_tile64(const float* __restrict__ W,
                                    __bf16* __restrict__ WT, int K, int N,
                                    int n0, int k0, int tid, __bf16 (*t)[65])
{
    const int tx = tid & 63, ty = tid >> 6;   // ty 0..3
    #pragma unroll
    for (int i = 0; i < 16; i++)
        t[ty * 16 + i][tx] = (__bf16)W[(size_t)(k0 + ty * 16 + i) * N + n0 + tx];
    __syncthreads();
    #pragma unroll
    for (int i = 0; i < 16; i++)
        WT[(size_t)(n0 + ty * 16 + i) * K + k0 + tx] = t[tx][ty * 16 + i];
}

__global__ __launch_bounds__(256) void prep(
    const float* __restrict__ x, const float* __restrict__ W_in,
    const float* __restrict__ W_out, const float* __restrict__ W_dt,
    const float* __restrict__ W_xprj,
    __bf16* __restrict__ xb, __bf16* __restrict__ W_inT,
    __bf16* __restrict__ W_outT, __bf16* __restrict__ WdtT,
    __bf16* __restrict__ W_xprT, float* __restrict__ xdbl)
{
    __shared__ __bf16 t[64][65];
    int bid = blockIdx.x;
    const int tid = threadIdx.x;

    if (bid < 256) {                        // R0: zero xdbl
        const int i = bid * 1024 + tid * 4;
        const float4 z = {0.f, 0.f, 0.f, 0.f};
        *reinterpret_cast<float4*>(&xdbl[i]) = z;
        return;
    }
    bid -= 256;
    if (bid < 1024) {                       // R1: cvt x -> xb
        const int e = (bid * 256 + tid) * 8;
        const float4 v0 = *reinterpret_cast<const float4*>(&x[e]);
        const float4 v1 = *reinterpret_cast<const float4*>(&x[e + 4]);
        bf16x8 o;
        o[0] = (__bf16)v0.x; o[1] = (__bf16)v0.y; o[2] = (__bf16)v0.z; o[3] = (__bf16)v0.w;
        o[4] = (__bf16)v1.x; o[5] = (__bf16)v1.y; o[6] = (__bf16)v1.z; o[7] = (__bf16)v1.w;
        *reinterpret_cast<bf16x8*>(&xb[e]) = o;
        return;
    }
    bid -= 1024;
    if (bid < 1024) {                       // R2: W_in [1024][4096] -> T
        trans_tile64(W_in, W_inT, DM, 2 * DI, (bid & 63) * 64, (bid >> 6) * 64, tid, t);
        return;
    }
    bid -= 1024;
    if (bid < 512) {                        // R3: W_out [2048][1024] -> T
        trans_tile64(W_out, W_outT, DI, DM, (bid & 15) * 64, (bid >> 4) * 64, tid, t);
        return;
    }
    bid -= 512;
    if (bid < 32) {                         // R4: W_dt [64][2048] -> T
        trans_tile64(W_dt, WdtT, DTR, DI, bid * 64, 0, tid, t);
        return;
    }
    bid -= 32;
    {                                       // R5: xproj transpose+pad
        const int idx = bid * 256 + tid;
        const int k = idx & (DI - 1);
        const int n = idx >> 11;
        W_xprT[(size_t)n * DI + k] = (n < XND) ? (__bf16)W_xprj[(size_t)k * XND + n]
                                               : (__bf16)0.f;
    }
}

// -------- bf16 MFMA GEMM, 128x128 tile, BK=64, XOR-swizzled LDS --------------
// Double-buffered, stage-early. MODE 0: store f32 | 1: atomicAdd f32 |
// 2: A from f32 [.][128] cols 0..63 reg-staged+cvt, softplus(acc+bias)->bf16 |
// 3: store bf16 (per-z partial offset when gridDim.z>1).
// SWZ 0: none | 1: XCD swizzle row-major | 2: XCD swizzle col-major.
template<int MODE, int SWZ>
__global__ __launch_bounds__(256) void gemm_bf16(
    const __bf16* __restrict__ A, const __bf16* __restrict__ Bt,
    void* __restrict__ Cp, int M, int N, int K, int ldc,
    const float* __restrict__ bias)
{
    __shared__ __bf16 As[2][128 * 64];
    __shared__ __bf16 Bs[2][128 * 64];
    const int tid  = threadIdx.x;
    const int lane = tid & 63;
    const int wid  = tid >> 6;
    const int wr   = wid >> 1, wc = wid & 1;

    int bx = blockIdx.x, by = blockIdx.y;
    if (SWZ != 0) {
        const int gx = gridDim.x, gy = gridDim.y;
        const int nxy = gx * gy;          // multiple of 8
        const int q = nxy >> 3;
        int lin = by * gx + bx;
        lin = (lin & 7) * q + (lin >> 3);
        if (SWZ == 1) { by = lin / gx; bx = lin % gx; }
        else          { bx = lin / gy; by = lin % gy; }
    }
    const int brow = by * 128, bcol = bx * 128;
    const int kper = K / gridDim.z;
    const int kbeg = blockIdx.z * kper, kend = kbeg + kper;

    f32x4 acc[4][4] = {};

    auto stage = [&](int buf, int k0) {
        if (MODE == 2) {
            const float* Af = reinterpret_cast<const float*>(A);
            #pragma unroll
            for (int p = 0; p < 4; p++) {
                const int i = p * 256 + tid;
                const int r = i >> 3;
                const int j = i & 7;
                const float4 v0 = *reinterpret_cast<const float4*>(
                    &Af[(size_t)(brow + r) * XNP + j * 8]);
                const float4 v1 = *reinterpret_cast<const float4*>(
                    &Af[(size_t)(brow + r) * XNP + j * 8 + 4]);
                bf16x8 o;
                o[0] = (__bf16)v0.x; o[1] = (__bf16)v0.y; o[2] = (__bf16)v0.z; o[3] = (__bf16)v0.w;
                o[4] = (__bf16)v1.x; o[5] = (__bf16)v1.y; o[6] = (__bf16)v1.z; o[7] = (__bf16)v1.w;
                *reinterpret_cast<bf16x8*>(&As[buf][r * 64 + ((j ^ (r & 7))) * 8]) = o;
            }
        } else {
            #pragma unroll
            for (int p = 0; p < 4; p++) {
                const int i = p * 256 + tid;
                const int r = i >> 3;
                const int gc = ((i & 7) ^ (r & 7)) * 8;
                __builtin_amdgcn_global_load_lds(
                    (const __attribute__((address_space(1))) void*)(A + (size_t)(brow + r) * K + k0 + gc),
                    (__attribute__((address_space(3))) void*)(&As[buf][i * 8]), 16, 0, 0);
            }
        }
        #pragma unroll
        for (int p = 0; p < 4; p++) {
            const int i = p * 256 + tid;
            const int r = i >> 3;
            const int gc = ((i & 7) ^ (r & 7)) * 8;
            __builtin_amdgcn_global_load_lds(
                (const __attribute__((address_space(1))) void*)(Bt + (size_t)(bcol + r) * K + k0 + gc),
                (__attribute__((address_space(3))) void*)(&Bs[buf][i * 8]), 16, 0, 0);
        }
    };

    const int nt = (kend - kbeg) >> 6;
    stage(0, kbeg);
    __syncthreads();
    int cur = 0;
    for (int t = 0; t < nt; t++) {
        if (t + 1 < nt) stage(cur ^ 1, kbeg + ((t + 1) << 6));
        const __bf16* Ab = &As[cur][0];
        const __bf16* Bb = &Bs[cur][0];
        bf16x8 a[2][4], b[2][4];
        const int rA = wr * 64 + (lane & 15);
        const int rB = wc * 64 + (lane & 15);
        const int cq = lane >> 4;
        const int rx = lane & 7;
        #pragma unroll
        for (int ks = 0; ks < 2; ks++) {
            const int sl = ((ks * 4 + cq) ^ rx) * 8;
            #pragma unroll
            for (int m = 0; m < 4; m++) {
                a[ks][m] = *reinterpret_cast<const bf16x8*>(&Ab[(rA + m * 16) * 64 + sl]);
                b[ks][m] = *reinterpret_cast<const bf16x8*>(&Bb[(rB + m * 16) * 64 + sl]);
            }
        }
        #pragma unroll
        for (int ks = 0; ks < 2; ks++)
            #pragma unroll
            for (int m = 0; m < 4; m++)
                #pragma unroll
                for (int n = 0; n < 4; n++)
                    acc[m][n] = __builtin_amdgcn_mfma_f32_16x16x32_bf16(
                        a[ks][m], b[ks][n], acc[m][n], 0, 0, 0);
        __syncthreads();
        cur ^= 1;
    }
    const int crow = brow + wr * 64 + (lane >> 4) * 4;
    const int ccol = bcol + wc * 64 + (lane & 15);
    __bf16* Cb3 = (__bf16*)Cp + (size_t)blockIdx.z * ((MODE == 3) ? (size_t)M * ldc : 0);
    #pragma unroll
    for (int m = 0; m < 4; m++)
        #pragma unroll
        for (int n = 0; n < 4; n++) {
            const int col = ccol + n * 16;
            #pragma unroll
            for (int j = 0; j < 4; j++) {
                const size_t idx = (size_t)(crow + m * 16 + j) * ldc + col;
                if (MODE == 0) {
                    ((float*)Cp)[idx] = acc[m][n][j];
                } else if (MODE == 1) {
                    atomicAdd(&((float*)Cp)[idx], acc[m][n][j]);
                } else if (MODE == 2) {
                    const float v = acc[m][n][j] + bias[col];
                    ((__bf16*)Cp)[idx] =
                        (__bf16)(fmaxf(v, 0.f) + log1pf(__expf(-fabsf(v))));
                } else {
                    Cb3[idx] = (__bf16)acc[m][n][j];
                }
            }
        }
}

// -------- depthwise causal conv (k=4) + bias + SiLU, 8 ch/thread -------------
__global__ __launch_bounds__(256) void conv_silu(
    const __bf16* __restrict__ xzb, const float* __restrict__ conv_w,
    const float* __restrict__ conv_b, __bf16* __restrict__ xcb)
{
    const int g  = blockIdx.x * 256 + threadIdx.x;
    const int d0 = (g & 255) * 8;
    const int tok = g >> 8;
    const int t   = tok & (SEQL - 1);

    float4 wv[8];
    #pragma unroll
    for (int j = 0; j < 8; j++)
        wv[j] = *reinterpret_cast<const float4*>(&conv_w[(d0 + j) * 4]);
    float acc[8];
    {
        const float4 b0 = *reinterpret_cast<const float4*>(&conv_b[d0]);
        const float4 b1 = *reinterpret_cast<const float4*>(&conv_b[d0 + 4]);
        acc[0] = b0.x; acc[1] = b0.y; acc[2] = b0.z; acc[3] = b0.w;
        acc[4] = b1.x; acc[5] = b1.y; acc[6] = b1.z; acc[7] = b1.w;
    }
    #pragma unroll
    for (int k = 0; k < 4; k++) {
        const int tt = t + k - 3;
        if (tt >= 0) {
            const bf16x8 v = *reinterpret_cast<const bf16x8*>(
                &xzb[(size_t)(tok + k - 3) * (2 * DI) + d0]);
            #pragma unroll
            for (int j = 0; j < 8; j++) {
                const float wk = (k == 0) ? wv[j].x : (k == 1) ? wv[j].y
                               : (k == 2) ? wv[j].z : wv[j].w;
                acc[j] += (float)v[j] * wk;
            }
        }
    }
    bf16x8 o;
    #pragma unroll
    for (int j = 0; j < 8; j++) {
        const float a = acc[j];
        o[j] = (__bf16)(a / (1.f + __expf(-a)));
    }
    *reinterpret_cast<bf16x8*>(&xcb[(size_t)g * 8]) = o;
}

// -------- scan pass A: per-chunk local scan from h=0, bf16 h out -------------
// grid (DI/256, CK, NB) = 2048 blocks (8 blocks/CU).
__global__ __launch_bounds__(256) void scan_partial(
    const __bf16* __restrict__ xcb, const float* __restrict__ xdbl,
    const __bf16* __restrict__ dtb, const float* __restrict__ A_log,
    __bf16* __restrict__ hpart, float* __restrict__ sdtb)
{
    __shared__ float Bsh[CL][16];
    const int tid = threadIdx.x;
    const int d = blockIdx.x * 256 + tid;
    const int c = blockIdx.y, b = blockIdx.z;
    const size_t base = (size_t)b * SEQL + c * CL;
    {
        const int st = tid >> 4, sg = tid & 15;
        if (st < CL) Bsh[st][sg] = xdbl[(base + st) * XNP + DTR + sg];
    }
    float dtv[CL], xcv[CL];
    #pragma unroll
    for (int t = 0; t < CL; t++) {
        dtv[t] = (float)dtb[(base + t) * DI + d];
        xcv[t] = (float)xcb[(base + t) * DI + d];
    }
    float Av[16];
    #pragma unroll
    for (int i = 0; i < 4; i++) {
        const float4 v = *reinterpret_cast<const float4*>(&A_log[(size_t)d * 16 + i * 4]);
        Av[i*4+0] = -__expf(v.x); Av[i*4+1] = -__expf(v.y);
        Av[i*4+2] = -__expf(v.z); Av[i*4+3] = -__expf(v.w);
    }
    __syncthreads();
    float h[16] = {};
    float sdt = 0.f;
    #pragma unroll
    for (int t = 0; t < CL; t++) {
        sdt += dtv[t];
        const float dx = dtv[t] * xcv[t];
        #pragma unroll
        for (int n = 0; n < 16; n++)
            h[n] = __expf(dtv[t] * Av[n]) * h[n] + dx * Bsh[t][n];
    }
    const size_t ob = ((size_t)(b * CK + c) * DI + d) * 16;
    bf16x8 o0, o1;
    #pragma unroll
    for (int i = 0; i < 8; i++) { o0[i] = (__bf16)h[i]; o1[i] = (__bf16)h[i + 8]; }
    *reinterpret_cast<bf16x8*>(&hpart[ob])     = o0;
    *reinterpret_cast<bf16x8*>(&hpart[ob + 8]) = o1;
    sdtb[(size_t)(b * CK + c) * DI + d] = sdt;
}

// -------- scan pass B: chunk combine, hpart -> hentry (bf16), batched --------
__global__ __launch_bounds__(256) void scan_combine(
    const float* __restrict__ A_log, const float* __restrict__ sdtb,
    const __bf16* __restrict__ hpart, __bf16* __restrict__ hentry)
{
    const int idx = blockIdx.x * 256 + threadIdx.x;
    const int n = idx & 15;
    const int d = (idx >> 4) & (DI - 1);
    const int b = idx >> 15;
    const float A = -__expf(A_log[(size_t)d * 16 + n]);
    float h = 0.f;
    for (int cb = 0; cb < CK / 16; cb++) {
        float hl[16], sv[16];
        #pragma unroll
        for (int j = 0; j < 16; j++) {
            const int c = cb * 16 + j;
            hl[j] = (float)hpart[((size_t)(b * CK + c) * DI + d) * 16 + n];
            sv[j] = sdtb[(size_t)(b * CK + c) * DI + d];
        }
        #pragma unroll
        for (int j = 0; j < 16; j++) {
            const int c = cb * 16 + j;
            hentry[((size_t)(b * CK + c) * DI + d) * 16 + n] = (__bf16)h;
            h = __expf(A * sv[j]) * h + hl[j];
        }
    }
}

// -------- scan pass C: seeded re-scan, emit y (D-skip + z-gate) as bf16 ------
__global__ __launch_bounds__(256) void scan_final(
    const __bf16* __restrict__ xzb, const __bf16* __restrict__ xcb,
    const float* __restrict__ xdbl, const __bf16* __restrict__ dtb,
    const float* __restrict__ A_log, const float* __restrict__ Dp,
    const __bf16* __restrict__ hentry, __bf16* __restrict__ yb)
{
    __shared__ float Bsh[CL][16];
    __shared__ float Csh[CL][16];
    const int tid = threadIdx.x;
    const int d = blockIdx.x * 256 + tid;
    const int c = blockIdx.y, b = blockIdx.z;
    const size_t base = (size_t)b * SEQL + c * CL;
    {
        const int st = tid >> 4, sg = tid & 15;
        if (st < CL)
            Bsh[st][sg] = xdbl[(base + st) * XNP + DTR + sg];
        else if (st < 2 * CL)
            Csh[st - CL][sg] = xdbl[(base + st - CL) * XNP + DTR + DS + sg];
    }
    float dtv[CL], xcv[CL], zv[CL];
    #pragma unroll
    for (int t = 0; t < CL; t++) {
        dtv[t] = (float)dtb[(base + t) * DI + d];
        xcv[t] = (float)xcb[(base + t) * DI + d];
        zv[t]  = (float)xzb[(base + t) * (2 * DI) + DI + d];
    }
    float Av[16];
    #pragma unroll
    for (int i = 0; i < 4; i++) {
        const float4 v = *reinterpret_cast<const float4*>(&A_log[(size_t)d * 16 + i * 4]);
        Av[i*4+0] = -__expf(v.x); Av[i*4+1] = -__expf(v.y);
        Av[i*4+2] = -__expf(v.z); Av[i*4+3] = -__expf(v.w);
    }
    float h[16];
    const size_t ob = ((size_t)(b * CK + c) * DI + d) * 16;
    {
        const bf16x8 v0 = *reinterpret_cast<const bf16x8*>(&hentry[ob]);
        const bf16x8 v1 = *reinterpret_cast<const bf16x8*>(&hentry[ob + 8]);
        #pragma unroll
        for (int i = 0; i < 8; i++) { h[i] = (float)v0[i]; h[i + 8] = (float)v1[i]; }
    }
    const float Dv = Dp[d];
    __syncthreads();
    #pragma unroll
    for (int t = 0; t < CL; t++) {
        const float dx = dtv[t] * xcv[t];
        float y = 0.f;
        #pragma unroll
        for (int n = 0; n < 16; n++) {
            h[n] = __expf(dtv[t] * Av[n]) * h[n] + dx * Bsh[t][n];
            y += h[n] * Csh[t][n];
        }
        y += xcv[t] * Dv;
        y *= zv[t] / (1.f + __expf(-zv[t]));
        yb[(base + t) * DI + d] = (__bf16)y;
    }
}

// -------- out = x + LayerNorm(sum of 4 bf16 partials) ------------------------
__global__ __launch_bounds__(256) void ln_add(
    const float* __restrict__ x, const __bf16* __restrict__ mpart,
    const float* __restrict__ gamma, const float* __restrict__ beta,
    float* __restrict__ out)
{
    const int tok = blockIdx.x;
    const int tid = threadIdx.x;
    const int lane = tid & 63, wave = tid >> 6;
    __shared__ float red[4];
    __shared__ float stats[2];

    float4 v = {0.f, 0.f, 0.f, 0.f};
    #pragma unroll
    for (int p = 0; p < 4; p++) {
        const bf16x4 mv = *reinterpret_cast<const bf16x4*>(
            &mpart[((size_t)p * NTOK + tok) * DM + tid * 4]);
        v.x += (float)mv[0]; v.y += (float)mv[1];
        v.z += (float)mv[2]; v.w += (float)mv[3];
    }
    float s = v.x + v.y + v.z + v.w;
    #pragma unroll
    for (int o = 32; o > 0; o >>= 1) s += __shfl_down(s, o, 64);
    if (lane == 0) red[wave] = s;
    __syncthreads();
    if (tid == 0) stats[0] = (red[0] + red[1] + red[2] + red[3]) * (1.f / DM);
    __syncthreads();
    const float mu = stats[0];
    const float dx = v.x - mu, dy = v.y - mu, dz = v.z - mu, dw = v.w - mu;
    float q = dx * dx + dy * dy + dz * dz + dw * dw;
    #pragma unroll
    for (int o = 32; o > 0; o >>= 1) q += __shfl_down(q, o, 64);
    if (lane == 0) red[wave] = q;
    __syncthreads();
    if (tid == 0)
        stats[1] = rsqrtf((red[0] + red[1] + red[2] + red[3]) * (1.f / DM) + 1e-6f);
    __syncthreads();
    const float rs = stats[1];

    const float4 g  = reinterpret_cast<const float4*>(gamma)[tid];
    const float4 bb = reinterpret_cast<const float4*>(beta)[tid];
    const float4 xv = reinterpret_cast<const float4*>(&x[(size_t)tok * DM])[tid];
    float4 o;
    o.x = xv.x + dx * rs * g.x + bb.x;
    o.y = xv.y + dy * rs * g.y + bb.y;
    o.z = xv.z + dz * rs * g.z + bb.z;
    o.w = xv.w + dw * rs * g.w + bb.w;
    reinterpret_cast<float4*>(&out[(size_t)tok * DM])[tid] = o;
}

extern "C" void kernel_launch(void* const* d_in, const int* in_sizes, int n_in,
                              void* d_out, int out_size, void* d_ws, size_t ws_size,
                              hipStream_t stream)
{
    const float* x      = (const float*)d_in[0];
    const float* W_in   = (const float*)d_in[1];
    const float* conv_w = (const float*)d_in[2];
    const float* conv_b = (const float*)d_in[3];
    const float* W_xprj = (const float*)d_in[4];
    const float* W_dt   = (const float*)d_in[5];
    const float* b_dt   = (const float*)d_in[6];
    const float* A_log  = (const float*)d_in[7];
    const float* D_par  = (const float*)d_in[8];
    const float* W_out  = (const float*)d_in[9];
    const float* gamma  = (const float*)d_in[10];
    const float* beta   = (const float*)d_in[11];
    float* out = (float*)d_out;

    // workspace layout (byte offsets, non-aliasing, ~113 MB)
    char* w = (char*)d_ws;
    __bf16* xzb    = (__bf16*)(w + 0);          // 16 MB [NTOK][4096] (xi|z)
    __bf16* xcb    = (__bf16*)(w + 16777216);   //  8 MB [NTOK][DI]
    float*  xdbl   = (float*) (w + 25165824);   //  1 MB [NTOK][128]
    __bf16* dtb    = (__bf16*)(w + 26214400);   //  8 MB [NTOK][DI]
    __bf16* mpart  = (__bf16*)(w + 34603008);   // 16 MB [4][NTOK][DM]
    __bf16* hpart  = (__bf16*)(w + 51380224);   // 16 MB [NB*CK][DI][16]
    __bf16* hentry = (__bf16*)(w + 68157440);   // 16 MB [NB*CK][DI][16]
    float*  sdtb   = (float*) (w + 84934656);   //  2 MB [NB*CK][DI]
    __bf16* xb     = (__bf16*)(w + 87031808);   //  4 MB [NTOK][DM]
    __bf16* W_inT  = (__bf16*)(w + 91226112);   //  8 MB [4096][DM]
    __bf16* W_outT = (__bf16*)(w + 99614720);   //  4 MB [DM][DI]
    __bf16* W_xprT = (__bf16*)(w + 103809024);  // .5 MB [128][DI]
    __bf16* WdtT   = (__bf16*)(w + 104333312);  // .25MB [DI][64]
    __bf16* yb     = (__bf16*)(w + 104595456);  //  8 MB [NTOK][DI]

    // 0. fused prep
    prep<<<PREP_BLOCKS, 256, 0, stream>>>(
        x, W_in, W_out, W_dt, W_xprj, xb, W_inT, W_outT, WdtT, W_xprT, xdbl);

    // 1. xz = x @ W_in  (M=2048, N=4096, K=1024) -> bf16
    gemm_bf16<3, 2><<<dim3(32, 16, 1), 256, 0, stream>>>(
        xb, W_inT, xzb, NTOK, 2 * DI, DM, 2 * DI, nullptr);

    // 2. conv + silu -> bf16
    conv_silu<<<(NTOK * DI / 8) / 256, 256, 0, stream>>>(xzb, conv_w, conv_b, xcb);

    // 3. x_dbl = xc @ W_xproj  (N=128 pad, K=2048), split-K=16, atomic f32
    gemm_bf16<1, 0><<<dim3(1, 16, 16), 256, 0, stream>>>(
        xcb, W_xprT, xdbl, NTOK, XNP, DI, XNP, nullptr);

    // 4. dt = softplus(dt_r @ W_dt + b_dt) -> bf16
    gemm_bf16<2, 0><<<dim3(16, 16, 1), 256, 0, stream>>>(
        (const __bf16*)xdbl, WdtT, dtb, NTOK, DI, DTR, DI, b_dt);

    // 5. chunked selective scan (CK=128 chunks of CL=8 -> 2048 blocks A/C)
    scan_partial<<<dim3(DI / 256, CK, NB), 256, 0, stream>>>(
        xcb, xdbl, dtb, A_log, hpart, sdtb);
    scan_combine<<<NB * DI * DS / 256, 256, 0, stream>>>(A_log, sdtb, hpart, hentry);
    scan_final<<<dim3(DI / 256, CK, NB), 256, 0, stream>>>(
        xzb, xcb, xdbl, dtb, A_log, D_par, hentry, yb);

    // 6. m partials = y @ W_out  (split-K=4, bf16 partial stores, no atomics)
    gemm_bf16<3, 1><<<dim3(8, 16, 4), 256, 0, stream>>>(
        yb, W_outT, mpart, NTOK, DM, DI, DM, nullptr);

    // 7. out = x + LN(sum of partials)
    ln_add<<<NTOK, 256, 0, stream>>>(x, mpart, gamma, beta, out);
}